// Round 5
// baseline (788.982 us; speedup 1.0000x reference)
//
#include <hip/hip_runtime.h>
#include <hip/hip_bf16.h>
#include <math.h>

#define H_HEADS 8
constexpr float LN_EPS = 1e-5f;

using short8 = __attribute__((ext_vector_type(8))) short;
using f32x4  = __attribute__((ext_vector_type(4))) float;

__device__ __forceinline__ ushort f2bf(float v){
  __hip_bfloat16 h = __float2bfloat16(v);
  return *reinterpret_cast<ushort*>(&h);
}
__device__ __forceinline__ float bf2f(ushort u){
  return __uint_as_float(((unsigned)u) << 16);
}

// ---------- LayerNorm (ddof=1), f32 in -> bf16 out, one wave per row ----------
__global__ void ln_kernel(const float* __restrict__ x, const float* __restrict__ w,
                          const float* __restrict__ b, ushort* __restrict__ out, int nrows){
  int wid = threadIdx.x >> 6, lane = threadIdx.x & 63;
  int r = blockIdx.x * (blockDim.x >> 6) + wid;
  if (r >= nrows) return;
  float2 v = ((const float2*)(x + (size_t)r*128))[lane];
  float s = v.x + v.y;
  #pragma unroll
  for (int o = 32; o; o >>= 1) s += __shfl_xor(s, o);
  float mu = s * (1.0f/128.0f);
  float d0 = v.x - mu, d1 = v.y - mu;
  float ss = d0*d0 + d1*d1;
  #pragma unroll
  for (int o = 32; o; o >>= 1) ss += __shfl_xor(ss, o);
  float sd = sqrtf(ss * (1.0f/127.0f));
  float inv = 1.0f / (sd + LN_EPS);
  float2 wv = ((const float2*)w)[lane];
  float2 bv = ((const float2*)b)[lane];
  ushort2 o2 = { f2bf(d0*inv*wv.x + bv.x), f2bf(d1*inv*wv.y + bv.y) };
  ((ushort2*)(out + (size_t)r*128))[lane] = o2;
}

// ---------- weight f32 -> bf16 conversion (all 6 in one launch) ----------
struct CvtArgs { const float* s[6]; ushort* d[6]; int cnt[6]; };
__global__ void cvt6_kernel(CvtArgs a){
  int w = blockIdx.y;
  int i = blockIdx.x*blockDim.x + threadIdx.x;
  if (i < a.cnt[w]) a.d[w][i] = f2bf(a.s[w][i]);
}

// ---------- bf16 MFMA GEMM: out[M][Nout] = A[M][K] @ W[Nout][K]^T + bias ----------
template<int NT, int RELU, int RESID, int OUT_BF16>
__global__ __launch_bounds__(256) void mfma_gemm(
    const ushort* __restrict__ A, const ushort* __restrict__ W,
    const float* __restrict__ bias, const float* __restrict__ resid,
    void* __restrict__ out, int M, int K, int Nout){
  int wid = threadIdx.x >> 6, lane = threadIdx.x & 63;
  int mb = blockIdx.x * 64 + wid * 16;
  if (mb >= M) return;
  int cb = blockIdx.y * (NT*16);
  int lrow = lane & 15, kgrp = lane >> 4;
  int row = mb + lrow;
  bool rowok = row < M;
  const ushort* arow = A + (size_t)(rowok ? row : (M-1)) * K + kgrp*8;

  f32x4 acc[NT] = {};
  for (int kt = 0; kt < K; kt += 32){
    short8 af = {};
    if (rowok) af = *(const short8*)(arow + kt);
    #pragma unroll
    for (int nt = 0; nt < NT; ++nt){
      int c = cb + nt*16 + lrow;
      short8 bf = *(const short8*)(W + (size_t)c * K + kt + kgrp*8);
      acc[nt] = __builtin_amdgcn_mfma_f32_16x16x32_bf16(af, bf, acc[nt], 0, 0, 0);
    }
  }

  int r0 = mb + kgrp*4;
  #pragma unroll
  for (int nt = 0; nt < NT; ++nt){
    int c = cb + nt*16 + lrow;
    float bsum = bias[c];
    #pragma unroll
    for (int i = 0; i < 4; ++i){
      int r = r0 + i;
      if (r >= M) continue;
      float v = acc[nt][i] + bsum;
      if (RELU)  v = fmaxf(v, 0.0f);
      if (RESID) v += resid[(size_t)r*Nout + c];
      if (OUT_BF16) ((ushort*)out)[(size_t)r*Nout + c] = f2bf(v);
      else          ((float*)out)[(size_t)r*Nout + c] = v;
    }
  }
}

// ---------- CSR builds ----------
__global__ void hist2_kernel(const int* __restrict__ ei, int* __restrict__ cntR,
                             int* __restrict__ cntC, int E){
  int e = blockIdx.x*blockDim.x + threadIdx.x;
  if (e >= E) return;
  int2 rc = ((const int2*)ei)[e];
  atomicAdd(&cntR[rc.x], 1);
  atomicAdd(&cntC[rc.y], 1);
}

// single-block exclusive scan over n counters -> ptr[0..n], cursor copy
__global__ __launch_bounds__(1024) void scan_kernel(const int* __restrict__ cnt,
                                                    int* __restrict__ ptr,
                                                    int* __restrict__ cursor, int n){
  __shared__ int sums[1024];
  int t = threadIdx.x;
  int chunk = (n + 1023) / 1024;
  int lo = t*chunk, hi = min(lo+chunk, n);
  int s = 0;
  for (int i = lo; i < hi; ++i) s += cnt[i];
  sums[t] = s;
  __syncthreads();
  #pragma unroll
  for (int off = 1; off < 1024; off <<= 1){
    int v = (t >= off) ? sums[t-off] : 0;
    __syncthreads();
    sums[t] += v;
    __syncthreads();
  }
  int base = (t == 0) ? 0 : sums[t-1];
  for (int i = lo; i < hi; ++i){
    ptr[i] = base;
    cursor[i] = base;
    base += cnt[i];
  }
  if (t == 1023) ptr[n] = base;
}

// row-CSR fill: rcol[pos] = col of edge, pose[e] = pos
__global__ void fill_r_kernel(const int* __restrict__ ei, int* __restrict__ curR,
                              int* __restrict__ rcol, int* __restrict__ pose, int E){
  int e = blockIdx.x*blockDim.x + threadIdx.x;
  if (e >= E) return;
  int2 rc = ((const int2*)ei)[e];
  int pos = atomicAdd(&curR[rc.x], 1);
  rcol[pos] = rc.y;
  pose[e] = pos;
}

// col-CSR fill: cdat[pos] = {row of edge, row-CSR position}
__global__ void fill_c_kernel(const int* __restrict__ ei, int* __restrict__ curC,
                              const int* __restrict__ pose, int2* __restrict__ cdat, int E){
  int e = blockIdx.x*blockDim.x + threadIdx.x;
  if (e >= E) return;
  int2 rc = ((const int2*)ei)[e];
  int pos = atomicAdd(&curC[rc.y], 1);
  cdat[pos] = make_int2(rc.x, pose[e]);
}

// ---------- fused segmented softmax over row-CSR ----------
// one wave per source node r: scores -> max -> exp -> sum -> alpha (in sbuf, row-CSR order)
// lane = el*8 + h : el = edge slot (8 per iter), h = head
__global__ void row_softmax_kernel(const ushort* __restrict__ qb, const ushort* __restrict__ kb,
                                   const int* __restrict__ rptr, const int* __restrict__ rcol,
                                   float* __restrict__ sbuf, int n){
  int wid = threadIdx.x >> 6, lane = threadIdx.x & 63;
  int r = blockIdx.x * (blockDim.x >> 6) + wid;
  if (r >= n) return;
  int lo = rptr[r], hi = rptr[r+1];
  if (lo >= hi) return;
  int h = lane & 7, el = lane >> 3;

  // k[r][h*16 .. h*16+15] in f32 regs
  float kf[16];
  {
    const short8* kp = (const short8*)(kb + (size_t)r*128 + h*16);
    short8 k0 = kp[0], k1 = kp[1];
    #pragma unroll
    for (int i = 0; i < 8; ++i){
      kf[i]   = bf2f((ushort)k0[i]);
      kf[8+i] = bf2f((ushort)k1[i]);
    }
  }

  float m = -INFINITY;
  for (int j = lo + el; j < hi; j += 8){
    int c = rcol[j];
    const short8* qp = (const short8*)(qb + (size_t)c*128 + h*16);
    short8 q0 = qp[0], q1 = qp[1];
    float s = 0.f;
    #pragma unroll
    for (int i = 0; i < 8; ++i){
      s += bf2f((ushort)q0[i]) * kf[i];
      s += bf2f((ushort)q1[i]) * kf[8+i];
    }
    s *= 0.25f;   // 1/sqrt(16)
    sbuf[(size_t)j*8 + h] = s;
    m = fmaxf(m, s);
  }
  m = fmaxf(m, __shfl_xor(m, 8));
  m = fmaxf(m, __shfl_xor(m, 16));
  m = fmaxf(m, __shfl_xor(m, 32));

  float d = 0.f;
  for (int j = lo + el; j < hi; j += 8){
    float ex = __expf(sbuf[(size_t)j*8 + h] - m);
    sbuf[(size_t)j*8 + h] = ex;
    d += ex;
  }
  d += __shfl_xor(d, 8);
  d += __shfl_xor(d, 16);
  d += __shfl_xor(d, 32);
  float inv = 1.0f / d;

  for (int j = lo + el; j < hi; j += 8)
    sbuf[(size_t)j*8 + h] *= inv;
}

// ---------- gather aggregation over col-CSR -> bf16 agg ----------
__global__ void agg_kernel(const ushort* __restrict__ vb, const float* __restrict__ alpha,
                           const int* __restrict__ cptr, const int2* __restrict__ cdat,
                           ushort* __restrict__ aggb, int n){
  int wid = threadIdx.x >> 6, lane = threadIdx.x & 63;
  int node = blockIdx.x * (blockDim.x >> 6) + wid;
  if (node >= n) return;
  int lo = cptr[node], hi = cptr[node+1];
  int h = lane >> 3;
  float2 acc = {0.f, 0.f};
  for (int j = lo; j < hi; ++j){
    int2 rp = cdat[j];
    float a = alpha[(size_t)rp.y*8 + h];
    ushort2 vv = ((const ushort2*)(vb + (size_t)rp.x*128))[lane];
    acc.x = fmaf(a, bf2f(vv.x), acc.x);
    acc.y = fmaf(a, bf2f(vv.y), acc.y);
  }
  ushort2 o2 = { f2bf(acc.x), f2bf(acc.y) };
  ((ushort2*)(aggb + (size_t)node*128))[lane] = o2;
}

extern "C" void kernel_launch(void* const* d_in, const int* in_sizes, int n_in,
                              void* d_out, int out_size, void* d_ws, size_t ws_size,
                              hipStream_t stream){
  const float* feats = (const float*)d_in[0];
  const int*   ei    = (const int*)  d_in[1];
  const float* Wq = (const float*)d_in[2];
  const float* bq = (const float*)d_in[3];
  const float* Wk = (const float*)d_in[4];
  const float* bk = (const float*)d_in[5];
  const float* Wv = (const float*)d_in[6];
  const float* bv = (const float*)d_in[7];
  const float* Wo = (const float*)d_in[8];
  const float* bo = (const float*)d_in[9];
  const float* ln1w = (const float*)d_in[10];
  const float* ln1b = (const float*)d_in[11];
  const float* ln2w = (const float*)d_in[12];
  const float* ln2b = (const float*)d_in[13];
  const float* W1 = (const float*)d_in[14];
  const float* b1 = (const float*)d_in[15];
  const float* W2 = (const float*)d_in[16];
  const float* b2 = (const float*)d_in[17];
  float* outp = (float*)d_out;

  int n = in_sizes[0] / 128;      // 50000 nodes
  int E = in_sizes[1] / 2;        // 800000 edges

  const size_t ND  = (size_t)n * 128;        // 6.4M elems
  const size_t ND2 = ND / 2;                 // f32 units for an ND bf16 buffer
  const size_t EH  = (size_t)E * H_HEADS;    // 6.4M

  // workspace (f32 units):
  //  x2b(ND2) | qb(ND2) | kb(ND2) | vb(ND2) | sbuf(EH) | aggb(ND2)
  //  | cdat(2E) | rcol(E) | pose(E) | rptr(n+4) | cptr(n+4)
  //  | cntR(n) | cntC(n) | curR(n) | curC(n) | wbuf
  // h1 (n*512 bf16 = 4*ND2 units) aliases qb..sbuf in the FFN phase.
  float* ws = (float*)d_ws;
  ushort* x2b  = (ushort*)ws;
  ushort* qb   = (ushort*)(ws + ND2);
  ushort* kb   = (ushort*)(ws + 2*ND2);
  ushort* vb   = (ushort*)(ws + 3*ND2);
  float*  sbuf = ws + 4*ND2;
  ushort* aggb = (ushort*)(ws + 4*ND2 + EH);
  int2* cdat   = (int2*)(ws + 5*ND2 + EH);
  int* rcol    = (int*)(cdat + E);
  int* pose    = rcol + E;
  int* rptr    = pose + E;
  int* cptr    = rptr + (n + 4);
  int* cntR    = cptr + (n + 4);
  int* cntC    = cntR + n;
  int* curR    = cntC + n;
  int* curC    = curR + n;
  ushort* wbuf = (ushort*)(curC + n);
  ushort* Wqb = wbuf;
  ushort* Wkb = Wqb + 16384;
  ushort* Wvb = Wkb + 16384;
  ushort* Wob = Wvb + 16384;
  ushort* W1b = Wob + 16384;
  ushort* W2b = W1b + 65536;
  ushort* h1  = qb;

  (void)hipMemsetAsync(cntR, 0, 2*n*sizeof(int), stream);  // cntR + cntC adjacent

  // weight conversion (independent)
  CvtArgs ca;
  ca.s[0]=Wq; ca.s[1]=Wk; ca.s[2]=Wv; ca.s[3]=Wo; ca.s[4]=W1; ca.s[5]=W2;
  ca.d[0]=Wqb; ca.d[1]=Wkb; ca.d[2]=Wvb; ca.d[3]=Wob; ca.d[4]=W1b; ca.d[5]=W2b;
  ca.cnt[0]=ca.cnt[1]=ca.cnt[2]=ca.cnt[3]=16384; ca.cnt[4]=ca.cnt[5]=65536;
  cvt6_kernel<<<dim3(65536/256, 6), 256, 0, stream>>>(ca);

  // CSR builds (depend only on ei)
  int ebE = (E + 255)/256;
  hist2_kernel<<<ebE, 256, 0, stream>>>(ei, cntR, cntC, E);
  scan_kernel<<<1, 1024, 0, stream>>>(cntR, rptr, curR, n);
  scan_kernel<<<1, 1024, 0, stream>>>(cntC, cptr, curC, n);
  fill_r_kernel<<<ebE, 256, 0, stream>>>(ei, curR, rcol, pose, E);
  fill_c_kernel<<<ebE, 256, 0, stream>>>(ei, curC, pose, cdat, E);

  // LN1 -> bf16
  ln_kernel<<<(n+3)/4, 256, 0, stream>>>(feats, ln1w, ln1b, x2b, n);

  // QKV projections (bf16 MFMA, bf16 out)
  int gm = (n + 63)/64;
  mfma_gemm<8,0,0,1><<<dim3(gm,1), 256, 0, stream>>>(x2b, Wqb, bq, nullptr, qb, n, 128, 128);
  mfma_gemm<8,0,0,1><<<dim3(gm,1), 256, 0, stream>>>(x2b, Wkb, bk, nullptr, kb, n, 128, 128);
  mfma_gemm<8,0,0,1><<<dim3(gm,1), 256, 0, stream>>>(x2b, Wvb, bv, nullptr, vb, n, 128, 128);

  // fused segmented softmax (scores + max + exp + sum + alpha)
  row_softmax_kernel<<<(n+3)/4, 256, 0, stream>>>(qb, kb, rptr, rcol, sbuf, n);

  // gather aggregation -> bf16
  agg_kernel<<<(n+3)/4, 256, 0, stream>>>(vb, sbuf, cptr, cdat, aggb, n);

  // attention out projection + residual -> d_out (f32)
  mfma_gemm<8,0,1,0><<<dim3(gm,1), 256, 0, stream>>>(aggb, Wob, bo, feats, outp, n, 128, 128);

  // LN2 -> bf16
  ln_kernel<<<(n+3)/4, 256, 0, stream>>>(outp, ln2w, ln2b, x2b, n);

  // FFN
  mfma_gemm<8,1,0,1><<<dim3(gm,4), 256, 0, stream>>>(x2b, W1b, b1, nullptr, h1,  n, 128, 512);
  mfma_gemm<8,1,1,0><<<dim3(gm,1), 256, 0, stream>>>(h1,  W2b, b2, outp,    outp, n, 512, 128);
}

// Round 6
// 583.282 us; speedup vs baseline: 1.3527x; 1.3527x over previous
//
#include <hip/hip_runtime.h>
#include <hip/hip_bf16.h>
#include <math.h>

#define H_HEADS 8
constexpr float LN_EPS = 1e-5f;

using short8 = __attribute__((ext_vector_type(8))) short;
using f32x4  = __attribute__((ext_vector_type(4))) float;

__device__ __forceinline__ ushort f2bf(float v){
  __hip_bfloat16 h = __float2bfloat16(v);
  return *reinterpret_cast<ushort*>(&h);
}
__device__ __forceinline__ float bf2f(ushort u){
  return __uint_as_float(((unsigned)u) << 16);
}

// ---------- LayerNorm (ddof=1), f32 in -> bf16 out, one wave per row ----------
__global__ void ln_kernel(const float* __restrict__ x, const float* __restrict__ w,
                          const float* __restrict__ b, ushort* __restrict__ out, int nrows){
  int wid = threadIdx.x >> 6, lane = threadIdx.x & 63;
  int r = blockIdx.x * (blockDim.x >> 6) + wid;
  if (r >= nrows) return;
  float2 v = ((const float2*)(x + (size_t)r*128))[lane];
  float s = v.x + v.y;
  #pragma unroll
  for (int o = 32; o; o >>= 1) s += __shfl_xor(s, o);
  float mu = s * (1.0f/128.0f);
  float d0 = v.x - mu, d1 = v.y - mu;
  float ss = d0*d0 + d1*d1;
  #pragma unroll
  for (int o = 32; o; o >>= 1) ss += __shfl_xor(ss, o);
  float sd = sqrtf(ss * (1.0f/127.0f));
  float inv = 1.0f / (sd + LN_EPS);
  float2 wv = ((const float2*)w)[lane];
  float2 bv = ((const float2*)b)[lane];
  ushort2 o2 = { f2bf(d0*inv*wv.x + bv.x), f2bf(d1*inv*wv.y + bv.y) };
  ((ushort2*)(out + (size_t)r*128))[lane] = o2;
}

// ---------- weight f32 -> bf16 conversion (all 6 in one launch) ----------
struct CvtArgs { const float* s[6]; ushort* d[6]; int cnt[6]; };
__global__ void cvt6_kernel(CvtArgs a){
  int w = blockIdx.y;
  int i = blockIdx.x*blockDim.x + threadIdx.x;
  if (i < a.cnt[w]) a.d[w][i] = f2bf(a.s[w][i]);
}

// ---------- bf16 MFMA GEMM: out[M][Nout] = A[M][K] @ W[Nout][K]^T + bias ----------
template<int NT, int RELU, int RESID, int OUT_BF16>
__global__ __launch_bounds__(256) void mfma_gemm(
    const ushort* __restrict__ A, const ushort* __restrict__ W,
    const float* __restrict__ bias, const float* __restrict__ resid,
    void* __restrict__ out, int M, int K, int Nout){
  int wid = threadIdx.x >> 6, lane = threadIdx.x & 63;
  int mb = blockIdx.x * 64 + wid * 16;
  if (mb >= M) return;
  int cb = blockIdx.y * (NT*16);
  int lrow = lane & 15, kgrp = lane >> 4;
  int row = mb + lrow;
  bool rowok = row < M;
  const ushort* arow = A + (size_t)(rowok ? row : (M-1)) * K + kgrp*8;

  f32x4 acc[NT] = {};
  for (int kt = 0; kt < K; kt += 32){
    short8 af = {};
    if (rowok) af = *(const short8*)(arow + kt);
    #pragma unroll
    for (int nt = 0; nt < NT; ++nt){
      int c = cb + nt*16 + lrow;
      short8 bf = *(const short8*)(W + (size_t)c * K + kt + kgrp*8);
      acc[nt] = __builtin_amdgcn_mfma_f32_16x16x32_bf16(af, bf, acc[nt], 0, 0, 0);
    }
  }

  int r0 = mb + kgrp*4;
  #pragma unroll
  for (int nt = 0; nt < NT; ++nt){
    int c = cb + nt*16 + lrow;
    float bsum = bias[c];
    #pragma unroll
    for (int i = 0; i < 4; ++i){
      int r = r0 + i;
      if (r >= M) continue;
      float v = acc[nt][i] + bsum;
      if (RELU)  v = fmaxf(v, 0.0f);
      if (RESID) v += resid[(size_t)r*Nout + c];
      if (OUT_BF16) ((ushort*)out)[(size_t)r*Nout + c] = f2bf(v);
      else          ((float*)out)[(size_t)r*Nout + c] = v;
    }
  }
}

// ---------- CSR builds ----------
__global__ void hist2_kernel(const int* __restrict__ ei, int* __restrict__ cntR,
                             int* __restrict__ cntC, int E){
  int e = blockIdx.x*blockDim.x + threadIdx.x;
  if (e >= E) return;
  int2 rc = ((const int2*)ei)[e];
  atomicAdd(&cntR[rc.x], 1);
  atomicAdd(&cntC[rc.y], 1);
}

// ---------- parallel 3-phase exclusive scan (both arrays via gridDim.y=2) ----------
// phase 1: per-block (1024 elems) sums
__global__ __launch_bounds__(256) void scan_reduce(const int* __restrict__ cnt0,
                                                   int* __restrict__ partial, int n, int nb){
  const int* cnt = cnt0 + (size_t)blockIdx.y * n;
  int t = threadIdx.x;
  int base = blockIdx.x*1024 + t*4;
  int s = 0;
  #pragma unroll
  for (int j = 0; j < 4; ++j){ int i = base+j; if (i < n) s += cnt[i]; }
  __shared__ int sm[256];
  sm[t] = s; __syncthreads();
  for (int off = 128; off; off >>= 1){
    if (t < off) sm[t] += sm[t+off];
    __syncthreads();
  }
  if (t == 0) partial[blockIdx.y*nb + blockIdx.x] = sm[0];
}

// phase 2: exclusive-scan the partials (nb <= 256), write ptr[n] = total
__global__ __launch_bounds__(256) void scan_mid(int* __restrict__ partial, int nb,
                                                int* __restrict__ rptr, int* __restrict__ cptr, int n){
  int y = blockIdx.y;
  int* p = partial + y*nb;
  int t = threadIdx.x;
  __shared__ int sm[256];
  sm[t] = (t < nb) ? p[t] : 0;
  __syncthreads();
  for (int off = 1; off < 256; off <<= 1){
    int v = (t >= off) ? sm[t-off] : 0;
    __syncthreads();
    sm[t] += v;
    __syncthreads();
  }
  if (t < nb) p[t] = (t == 0) ? 0 : sm[t-1];
  if (t == 0) (y ? cptr : rptr)[n] = sm[255];
}

// phase 3: block-local exclusive scan + base, write ptr & cursor
__global__ __launch_bounds__(256) void scan_scatter(const int* __restrict__ cnt0,
                                                    const int* __restrict__ partial,
                                                    int* __restrict__ rptr, int* __restrict__ cptr,
                                                    int* __restrict__ curR, int* __restrict__ curC,
                                                    int n, int nb){
  int y = blockIdx.y;
  const int* cnt = cnt0 + (size_t)y * n;
  int* ptr = y ? cptr : rptr;
  int* cur = y ? curC : curR;
  int t = threadIdx.x;
  int base = blockIdx.x*1024 + t*4;
  int v[4]; int s = 0;
  #pragma unroll
  for (int j = 0; j < 4; ++j){ int i = base+j; v[j] = (i<n)?cnt[i]:0; s += v[j]; }
  __shared__ int sm[256];
  sm[t] = s; __syncthreads();
  for (int off = 1; off < 256; off <<= 1){
    int x = (t >= off) ? sm[t-off] : 0;
    __syncthreads();
    sm[t] += x;
    __syncthreads();
  }
  int pre = partial[y*nb + blockIdx.x] + ((t==0)?0:sm[t-1]);
  #pragma unroll
  for (int j = 0; j < 4; ++j){
    int i = base+j;
    if (i < n){ ptr[i] = pre; cur[i] = pre; pre += v[j]; }
  }
}

// row-CSR fill: rcol[pos] = col of edge, pose[e] = pos
__global__ void fill_r_kernel(const int* __restrict__ ei, int* __restrict__ curR,
                              int* __restrict__ rcol, int* __restrict__ pose, int E){
  int e = blockIdx.x*blockDim.x + threadIdx.x;
  if (e >= E) return;
  int2 rc = ((const int2*)ei)[e];
  int pos = atomicAdd(&curR[rc.x], 1);
  rcol[pos] = rc.y;
  pose[e] = pos;
}

// col-CSR fill: cdat[pos] = {row of edge, row-CSR position}
__global__ void fill_c_kernel(const int* __restrict__ ei, int* __restrict__ curC,
                              const int* __restrict__ pose, int2* __restrict__ cdat, int E){
  int e = blockIdx.x*blockDim.x + threadIdx.x;
  if (e >= E) return;
  int2 rc = ((const int2*)ei)[e];
  int pos = atomicAdd(&curC[rc.y], 1);
  cdat[pos] = make_int2(rc.x, pose[e]);
}

// ---------- fused segmented softmax over row-CSR ----------
__global__ void row_softmax_kernel(const ushort* __restrict__ qb, const ushort* __restrict__ kb,
                                   const int* __restrict__ rptr, const int* __restrict__ rcol,
                                   float* __restrict__ sbuf, int n){
  int wid = threadIdx.x >> 6, lane = threadIdx.x & 63;
  int r = blockIdx.x * (blockDim.x >> 6) + wid;
  if (r >= n) return;
  int lo = rptr[r], hi = rptr[r+1];
  if (lo >= hi) return;
  int h = lane & 7, el = lane >> 3;

  float kf[16];
  {
    const short8* kp = (const short8*)(kb + (size_t)r*128 + h*16);
    short8 k0 = kp[0], k1 = kp[1];
    #pragma unroll
    for (int i = 0; i < 8; ++i){
      kf[i]   = bf2f((ushort)k0[i]);
      kf[8+i] = bf2f((ushort)k1[i]);
    }
  }

  float m = -INFINITY;
  for (int j = lo + el; j < hi; j += 8){
    int c = rcol[j];
    const short8* qp = (const short8*)(qb + (size_t)c*128 + h*16);
    short8 q0 = qp[0], q1 = qp[1];
    float s = 0.f;
    #pragma unroll
    for (int i = 0; i < 8; ++i){
      s += bf2f((ushort)q0[i]) * kf[i];
      s += bf2f((ushort)q1[i]) * kf[8+i];
    }
    s *= 0.25f;
    sbuf[(size_t)j*8 + h] = s;
    m = fmaxf(m, s);
  }
  m = fmaxf(m, __shfl_xor(m, 8));
  m = fmaxf(m, __shfl_xor(m, 16));
  m = fmaxf(m, __shfl_xor(m, 32));

  float d = 0.f;
  for (int j = lo + el; j < hi; j += 8){
    float ex = __expf(sbuf[(size_t)j*8 + h] - m);
    sbuf[(size_t)j*8 + h] = ex;
    d += ex;
  }
  d += __shfl_xor(d, 8);
  d += __shfl_xor(d, 16);
  d += __shfl_xor(d, 32);
  float inv = 1.0f / d;

  for (int j = lo + el; j < hi; j += 8)
    sbuf[(size_t)j*8 + h] *= inv;
}

// ---------- gather aggregation over col-CSR -> bf16 agg ----------
__global__ void agg_kernel(const ushort* __restrict__ vb, const float* __restrict__ alpha,
                           const int* __restrict__ cptr, const int2* __restrict__ cdat,
                           ushort* __restrict__ aggb, int n){
  int wid = threadIdx.x >> 6, lane = threadIdx.x & 63;
  int node = blockIdx.x * (blockDim.x >> 6) + wid;
  if (node >= n) return;
  int lo = cptr[node], hi = cptr[node+1];
  int h = lane >> 3;
  float2 acc = {0.f, 0.f};
  for (int j = lo; j < hi; ++j){
    int2 rp = cdat[j];
    float a = alpha[(size_t)rp.y*8 + h];
    ushort2 vv = ((const ushort2*)(vb + (size_t)rp.x*128))[lane];
    acc.x = fmaf(a, bf2f(vv.x), acc.x);
    acc.y = fmaf(a, bf2f(vv.y), acc.y);
  }
  ushort2 o2 = { f2bf(acc.x), f2bf(acc.y) };
  ((ushort2*)(aggb + (size_t)node*128))[lane] = o2;
}

extern "C" void kernel_launch(void* const* d_in, const int* in_sizes, int n_in,
                              void* d_out, int out_size, void* d_ws, size_t ws_size,
                              hipStream_t stream){
  const float* feats = (const float*)d_in[0];
  const int*   ei    = (const int*)  d_in[1];
  const float* Wq = (const float*)d_in[2];
  const float* bq = (const float*)d_in[3];
  const float* Wk = (const float*)d_in[4];
  const float* bk = (const float*)d_in[5];
  const float* Wv = (const float*)d_in[6];
  const float* bv = (const float*)d_in[7];
  const float* Wo = (const float*)d_in[8];
  const float* bo = (const float*)d_in[9];
  const float* ln1w = (const float*)d_in[10];
  const float* ln1b = (const float*)d_in[11];
  const float* ln2w = (const float*)d_in[12];
  const float* ln2b = (const float*)d_in[13];
  const float* W1 = (const float*)d_in[14];
  const float* b1 = (const float*)d_in[15];
  const float* W2 = (const float*)d_in[16];
  const float* b2 = (const float*)d_in[17];
  float* outp = (float*)d_out;

  int n = in_sizes[0] / 128;      // 50000 nodes
  int E = in_sizes[1] / 2;        // 800000 edges

  const size_t ND  = (size_t)n * 128;
  const size_t ND2 = ND / 2;
  const size_t EH  = (size_t)E * H_HEADS;

  float* ws = (float*)d_ws;
  ushort* x2b  = (ushort*)ws;
  ushort* qb   = (ushort*)(ws + ND2);
  ushort* kb   = (ushort*)(ws + 2*ND2);
  ushort* vb   = (ushort*)(ws + 3*ND2);
  float*  sbuf = ws + 4*ND2;
  ushort* aggb = (ushort*)(ws + 4*ND2 + EH);
  int2* cdat   = (int2*)(ws + 5*ND2 + EH);
  int* rcol    = (int*)(cdat + E);
  int* pose    = rcol + E;
  int* rptr    = pose + E;
  int* cptr    = rptr + (n + 4);
  int* cntR    = cptr + (n + 4);
  int* cntC    = cntR + n;
  int* curR    = cntC + n;
  int* curC    = curR + n;
  int* partial = curC + n;                  // 2*nb ints (nb <= 256)
  ushort* wbuf = (ushort*)(partial + 512);
  ushort* Wqb = wbuf;
  ushort* Wkb = Wqb + 16384;
  ushort* Wvb = Wkb + 16384;
  ushort* Wob = Wvb + 16384;
  ushort* W1b = Wob + 16384;
  ushort* W2b = W1b + 65536;
  ushort* h1  = qb;

  (void)hipMemsetAsync(cntR, 0, 2*n*sizeof(int), stream);

  // weight conversion (independent)
  CvtArgs ca;
  ca.s[0]=Wq; ca.s[1]=Wk; ca.s[2]=Wv; ca.s[3]=Wo; ca.s[4]=W1; ca.s[5]=W2;
  ca.d[0]=Wqb; ca.d[1]=Wkb; ca.d[2]=Wvb; ca.d[3]=Wob; ca.d[4]=W1b; ca.d[5]=W2b;
  ca.cnt[0]=ca.cnt[1]=ca.cnt[2]=ca.cnt[3]=16384; ca.cnt[4]=ca.cnt[5]=65536;
  cvt6_kernel<<<dim3(65536/256, 6), 256, 0, stream>>>(ca);

  // CSR builds
  int ebE = (E + 255)/256;
  int nb = (n + 1023)/1024;
  hist2_kernel<<<ebE, 256, 0, stream>>>(ei, cntR, cntC, E);
  scan_reduce <<<dim3(nb,2), 256, 0, stream>>>(cntR, partial, n, nb);
  scan_mid    <<<dim3(1,2),  256, 0, stream>>>(partial, nb, rptr, cptr, n);
  scan_scatter<<<dim3(nb,2), 256, 0, stream>>>(cntR, partial, rptr, cptr, curR, curC, n, nb);
  fill_r_kernel<<<ebE, 256, 0, stream>>>(ei, curR, rcol, pose, E);
  fill_c_kernel<<<ebE, 256, 0, stream>>>(ei, curC, pose, cdat, E);

  // LN1 -> bf16
  ln_kernel<<<(n+3)/4, 256, 0, stream>>>(feats, ln1w, ln1b, x2b, n);

  // QKV projections (bf16 MFMA, bf16 out)
  int gm = (n + 63)/64;
  mfma_gemm<8,0,0,1><<<dim3(gm,1), 256, 0, stream>>>(x2b, Wqb, bq, nullptr, qb, n, 128, 128);
  mfma_gemm<8,0,0,1><<<dim3(gm,1), 256, 0, stream>>>(x2b, Wkb, bk, nullptr, kb, n, 128, 128);
  mfma_gemm<8,0,0,1><<<dim3(gm,1), 256, 0, stream>>>(x2b, Wvb, bv, nullptr, vb, n, 128, 128);

  // fused segmented softmax
  row_softmax_kernel<<<(n+3)/4, 256, 0, stream>>>(qb, kb, rptr, rcol, sbuf, n);

  // gather aggregation -> bf16
  agg_kernel<<<(n+3)/4, 256, 0, stream>>>(vb, sbuf, cptr, cdat, aggb, n);

  // attention out projection + residual -> d_out (f32)
  mfma_gemm<8,0,1,0><<<dim3(gm,1), 256, 0, stream>>>(aggb, Wob, bo, feats, outp, n, 128, 128);

  // LN2 -> bf16
  ln_kernel<<<(n+3)/4, 256, 0, stream>>>(outp, ln2w, ln2b, x2b, n);

  // FFN
  mfma_gemm<8,1,0,1><<<dim3(gm,4), 256, 0, stream>>>(x2b, W1b, b1, nullptr, h1,  n, 128, 512);
  mfma_gemm<8,1,1,0><<<dim3(gm,1), 256, 0, stream>>>(h1,  W2b, b2, outp,    outp, n, 512, 128);
}

// Round 7
// 535.216 us; speedup vs baseline: 1.4741x; 1.0898x over previous
//
#include <hip/hip_runtime.h>
#include <hip/hip_bf16.h>
#include <math.h>

#define H_HEADS 8
constexpr float LN_EPS = 1e-5f;

using short8 = __attribute__((ext_vector_type(8))) short;
using f32x4  = __attribute__((ext_vector_type(4))) float;

__device__ __forceinline__ ushort f2bf(float v){
  __hip_bfloat16 h = __float2bfloat16(v);
  return *reinterpret_cast<ushort*>(&h);
}
__device__ __forceinline__ float bf2f(ushort u){
  return __uint_as_float(((unsigned)u) << 16);
}

// ---------- LayerNorm (ddof=1), f32 in -> bf16 out, one wave per row ----------
__global__ void ln_kernel(const float* __restrict__ x, const float* __restrict__ w,
                          const float* __restrict__ b, ushort* __restrict__ out, int nrows){
  int wid = threadIdx.x >> 6, lane = threadIdx.x & 63;
  int r = blockIdx.x * (blockDim.x >> 6) + wid;
  if (r >= nrows) return;
  float2 v = ((const float2*)(x + (size_t)r*128))[lane];
  float s = v.x + v.y;
  #pragma unroll
  for (int o = 32; o; o >>= 1) s += __shfl_xor(s, o);
  float mu = s * (1.0f/128.0f);
  float d0 = v.x - mu, d1 = v.y - mu;
  float ss = d0*d0 + d1*d1;
  #pragma unroll
  for (int o = 32; o; o >>= 1) ss += __shfl_xor(ss, o);
  float sd = sqrtf(ss * (1.0f/127.0f));
  float inv = 1.0f / (sd + LN_EPS);
  float2 wv = ((const float2*)w)[lane];
  float2 bv = ((const float2*)b)[lane];
  ushort2 o2 = { f2bf(d0*inv*wv.x + bv.x), f2bf(d1*inv*wv.y + bv.y) };
  ((ushort2*)(out + (size_t)r*128))[lane] = o2;
}

// ---------- weight f32 -> bf16 conversion (all 6 in one launch) ----------
struct CvtArgs { const float* s[6]; ushort* d[6]; int cnt[6]; };
__global__ void cvt6_kernel(CvtArgs a){
  int w = blockIdx.y;
  int i = blockIdx.x*blockDim.x + threadIdx.x;
  if (i < a.cnt[w]) a.d[w][i] = f2bf(a.s[w][i]);
}

// ---------- bf16 MFMA GEMM: out[M][Nout] = A[M][K] @ W[Nout][K]^T + bias ----------
template<int NT, int RELU, int RESID, int OUT_BF16>
__global__ __launch_bounds__(256) void mfma_gemm(
    const ushort* __restrict__ A, const ushort* __restrict__ W,
    const float* __restrict__ bias, const float* __restrict__ resid,
    void* __restrict__ out, int M, int K, int Nout){
  int wid = threadIdx.x >> 6, lane = threadIdx.x & 63;
  int mb = blockIdx.x * 64 + wid * 16;
  if (mb >= M) return;
  int cb = blockIdx.y * (NT*16);
  int lrow = lane & 15, kgrp = lane >> 4;
  int row = mb + lrow;
  bool rowok = row < M;
  const ushort* arow = A + (size_t)(rowok ? row : (M-1)) * K + kgrp*8;

  f32x4 acc[NT] = {};
  for (int kt = 0; kt < K; kt += 32){
    short8 af = {};
    if (rowok) af = *(const short8*)(arow + kt);
    #pragma unroll
    for (int nt = 0; nt < NT; ++nt){
      int c = cb + nt*16 + lrow;
      short8 bf = *(const short8*)(W + (size_t)c * K + kt + kgrp*8);
      acc[nt] = __builtin_amdgcn_mfma_f32_16x16x32_bf16(af, bf, acc[nt], 0, 0, 0);
    }
  }

  int r0 = mb + kgrp*4;
  #pragma unroll
  for (int nt = 0; nt < NT; ++nt){
    int c = cb + nt*16 + lrow;
    float bsum = bias[c];
    #pragma unroll
    for (int i = 0; i < 4; ++i){
      int r = r0 + i;
      if (r >= M) continue;
      float v = acc[nt][i] + bsum;
      if (RELU)  v = fmaxf(v, 0.0f);
      if (RESID) v += resid[(size_t)r*Nout + c];
      if (OUT_BF16) ((ushort*)out)[(size_t)r*Nout + c] = f2bf(v);
      else          ((float*)out)[(size_t)r*Nout + c] = v;
    }
  }
}

// ---------- fused QKV GEMM: blockIdx.y selects {Wq,Wk,Wv} (contiguous) ----------
__global__ __launch_bounds__(256) void qkv_gemm(
    const ushort* __restrict__ A, const ushort* __restrict__ Wcat,
    const float* __restrict__ bq, const float* __restrict__ bk, const float* __restrict__ bv,
    ushort* __restrict__ qb, ushort* __restrict__ kb, ushort* __restrict__ vb, int M){
  const int K = 128;
  int y = blockIdx.y;
  const ushort* W = Wcat + (size_t)y * 16384;
  const float* bias = (y==0) ? bq : (y==1) ? bk : bv;
  ushort* out = (y==0) ? qb : (y==1) ? kb : vb;

  int wid = threadIdx.x >> 6, lane = threadIdx.x & 63;
  int mb = blockIdx.x * 64 + wid * 16;
  if (mb >= M) return;
  int lrow = lane & 15, kgrp = lane >> 4;
  int row = mb + lrow;
  bool rowok = row < M;
  const ushort* arow = A + (size_t)(rowok ? row : (M-1)) * K + kgrp*8;

  f32x4 acc[8] = {};
  #pragma unroll
  for (int kt = 0; kt < K; kt += 32){
    short8 af = {};
    if (rowok) af = *(const short8*)(arow + kt);
    #pragma unroll
    for (int nt = 0; nt < 8; ++nt){
      int c = nt*16 + lrow;
      short8 bf = *(const short8*)(W + (size_t)c * K + kt + kgrp*8);
      acc[nt] = __builtin_amdgcn_mfma_f32_16x16x32_bf16(af, bf, acc[nt], 0, 0, 0);
    }
  }
  int r0 = mb + kgrp*4;
  #pragma unroll
  for (int nt = 0; nt < 8; ++nt){
    int c = nt*16 + lrow;
    float bsum = bias[c];
    #pragma unroll
    for (int i = 0; i < 4; ++i){
      int r = r0 + i;
      if (r >= M) continue;
      out[(size_t)r*128 + c] = f2bf(acc[nt][i] + bsum);
    }
  }
}

// ---------- CSR builds ----------
__global__ void hist2_kernel(const int* __restrict__ ei, int* __restrict__ cntR,
                             int* __restrict__ cntC, int E){
  int e = blockIdx.x*blockDim.x + threadIdx.x;
  if (e >= E) return;
  int2 rc = ((const int2*)ei)[e];
  atomicAdd(&cntR[rc.x], 1);
  atomicAdd(&cntC[rc.y], 1);
}

// ---------- parallel 3-phase exclusive scan (both arrays via gridDim.y=2) ----------
__global__ __launch_bounds__(256) void scan_reduce(const int* __restrict__ cnt0,
                                                   int* __restrict__ partial, int n, int nb){
  const int* cnt = cnt0 + (size_t)blockIdx.y * n;
  int t = threadIdx.x;
  int base = blockIdx.x*1024 + t*4;
  int s = 0;
  #pragma unroll
  for (int j = 0; j < 4; ++j){ int i = base+j; if (i < n) s += cnt[i]; }
  __shared__ int sm[256];
  sm[t] = s; __syncthreads();
  for (int off = 128; off; off >>= 1){
    if (t < off) sm[t] += sm[t+off];
    __syncthreads();
  }
  if (t == 0) partial[blockIdx.y*nb + blockIdx.x] = sm[0];
}

__global__ __launch_bounds__(256) void scan_mid(int* __restrict__ partial, int nb,
                                                int* __restrict__ rptr, int* __restrict__ cptr, int n){
  int y = blockIdx.y;
  int* p = partial + y*nb;
  int t = threadIdx.x;
  __shared__ int sm[256];
  sm[t] = (t < nb) ? p[t] : 0;
  __syncthreads();
  for (int off = 1; off < 256; off <<= 1){
    int v = (t >= off) ? sm[t-off] : 0;
    __syncthreads();
    sm[t] += v;
    __syncthreads();
  }
  if (t < nb) p[t] = (t == 0) ? 0 : sm[t-1];
  if (t == 0) (y ? cptr : rptr)[n] = sm[255];
}

__global__ __launch_bounds__(256) void scan_scatter(const int* __restrict__ cnt0,
                                                    const int* __restrict__ partial,
                                                    int* __restrict__ rptr, int* __restrict__ cptr,
                                                    int* __restrict__ curR, int* __restrict__ curC,
                                                    int n, int nb){
  int y = blockIdx.y;
  const int* cnt = cnt0 + (size_t)y * n;
  int* ptr = y ? cptr : rptr;
  int* cur = y ? curC : curR;
  int t = threadIdx.x;
  int base = blockIdx.x*1024 + t*4;
  int v[4]; int s = 0;
  #pragma unroll
  for (int j = 0; j < 4; ++j){ int i = base+j; v[j] = (i<n)?cnt[i]:0; s += v[j]; }
  __shared__ int sm[256];
  sm[t] = s; __syncthreads();
  for (int off = 1; off < 256; off <<= 1){
    int x = (t >= off) ? sm[t-off] : 0;
    __syncthreads();
    sm[t] += x;
    __syncthreads();
  }
  int pre = partial[y*nb + blockIdx.x] + ((t==0)?0:sm[t-1]);
  #pragma unroll
  for (int j = 0; j < 4; ++j){
    int i = base+j;
    if (i < n){ ptr[i] = pre; cur[i] = pre; pre += v[j]; }
  }
}

// row-CSR fill: rcol[pos] = col of edge, pose[e] = pos
__global__ void fill_r_kernel(const int* __restrict__ ei, int* __restrict__ curR,
                              int* __restrict__ rcol, int* __restrict__ pose, int E){
  int e = blockIdx.x*blockDim.x + threadIdx.x;
  if (e >= E) return;
  int2 rc = ((const int2*)ei)[e];
  int pos = atomicAdd(&curR[rc.x], 1);
  rcol[pos] = rc.y;
  pose[e] = pos;
}

// col-CSR fill: crow[pos] = row; cposr[row-CSR pos] = col-CSR pos
__global__ void fill_c_kernel(const int* __restrict__ ei, int* __restrict__ curC,
                              const int* __restrict__ pose, int* __restrict__ crow,
                              int* __restrict__ cposr, int E){
  int e = blockIdx.x*blockDim.x + threadIdx.x;
  if (e >= E) return;
  int2 rc = ((const int2*)ei)[e];
  int pos = atomicAdd(&curC[rc.y], 1);
  crow[pos] = rc.x;
  cposr[pose[e]] = pos;
}

// ---------- fused segmented softmax over row-CSR (online m,d; alpha -> col-CSR order) ----------
// lane = el*8 + h : el = edge slot (8 per iter), h = head
__global__ void row_softmax_kernel(const ushort* __restrict__ qb, const ushort* __restrict__ kb,
                                   const int* __restrict__ rptr, const int* __restrict__ rcol,
                                   const int* __restrict__ cposr,
                                   float* __restrict__ sbuf, float* __restrict__ cbuf, int n){
  int wid = threadIdx.x >> 6, lane = threadIdx.x & 63;
  int r = blockIdx.x * (blockDim.x >> 6) + wid;
  if (r >= n) return;
  int lo = rptr[r], hi = rptr[r+1];
  if (lo >= hi) return;
  int h = lane & 7, el = lane >> 3;

  float kf[16];
  {
    const short8* kp = (const short8*)(kb + (size_t)r*128 + h*16);
    short8 k0 = kp[0], k1 = kp[1];
    #pragma unroll
    for (int i = 0; i < 8; ++i){
      kf[i]   = bf2f((ushort)k0[i]);
      kf[8+i] = bf2f((ushort)k1[i]);
    }
  }

  float m = -1e30f, d = 0.f;
  for (int j = lo + el; j < hi; j += 8){
    int c = rcol[j];
    const short8* qp = (const short8*)(qb + (size_t)c*128 + h*16);
    short8 q0 = qp[0], q1 = qp[1];
    float s = 0.f;
    #pragma unroll
    for (int i = 0; i < 8; ++i){
      s += bf2f((ushort)q0[i]) * kf[i];
      s += bf2f((ushort)q1[i]) * kf[8+i];
    }
    s *= 0.25f;
    sbuf[(size_t)j*8 + h] = s;
    float nm = fmaxf(m, s);
    d = d*__expf(m - nm) + __expf(s - nm);
    m = nm;
  }
  #pragma unroll
  for (int o = 8; o < 64; o <<= 1){
    float om = __shfl_xor(m, o);
    float od = __shfl_xor(d, o);
    float nm = fmaxf(m, om);
    d = d*__expf(m - nm) + od*__expf(om - nm);
    m = nm;
  }
  float invd = 1.0f / d;

  for (int j = lo + el; j < hi; j += 8){
    float s = sbuf[(size_t)j*8 + h];
    float a = __expf(s - m) * invd;
    cbuf[(size_t)cposr[j]*8 + h] = a;     // scatter to col-CSR order
  }
}

// ---------- gather aggregation over col-CSR -> bf16 agg ----------
// two 32-lane halves process alternate edges; 4 dims/lane; alpha+crow streamed.
__global__ void agg_kernel(const ushort* __restrict__ vb, const float* __restrict__ cbuf,
                           const int* __restrict__ cptr, const int* __restrict__ crow,
                           ushort* __restrict__ aggb, int n){
  int wid = threadIdx.x >> 6, lane = threadIdx.x & 63;
  int node = blockIdx.x * (blockDim.x >> 6) + wid;
  if (node >= n) return;
  int lo = cptr[node], hi = cptr[node+1];
  int half = lane >> 5, l32 = lane & 31;
  int h = l32 >> 2;
  float4 acc = {0.f, 0.f, 0.f, 0.f};
  for (int j = lo + half; j < hi; j += 2){
    float a = cbuf[(size_t)j*8 + h];
    int row = crow[j];
    ushort4 vv = *(const ushort4*)(vb + (size_t)row*128 + l32*4);
    acc.x = fmaf(a, bf2f(vv.x), acc.x);
    acc.y = fmaf(a, bf2f(vv.y), acc.y);
    acc.z = fmaf(a, bf2f(vv.z), acc.z);
    acc.w = fmaf(a, bf2f(vv.w), acc.w);
  }
  acc.x += __shfl_xor(acc.x, 32);
  acc.y += __shfl_xor(acc.y, 32);
  acc.z += __shfl_xor(acc.z, 32);
  acc.w += __shfl_xor(acc.w, 32);
  if (half == 0){
    ushort4 o = { f2bf(acc.x), f2bf(acc.y), f2bf(acc.z), f2bf(acc.w) };
    *(ushort4*)(aggb + (size_t)node*128 + l32*4) = o;
  }
}

extern "C" void kernel_launch(void* const* d_in, const int* in_sizes, int n_in,
                              void* d_out, int out_size, void* d_ws, size_t ws_size,
                              hipStream_t stream){
  const float* feats = (const float*)d_in[0];
  const int*   ei    = (const int*)  d_in[1];
  const float* Wq = (const float*)d_in[2];
  const float* bq = (const float*)d_in[3];
  const float* Wk = (const float*)d_in[4];
  const float* bk = (const float*)d_in[5];
  const float* Wv = (const float*)d_in[6];
  const float* bv = (const float*)d_in[7];
  const float* Wo = (const float*)d_in[8];
  const float* bo = (const float*)d_in[9];
  const float* ln1w = (const float*)d_in[10];
  const float* ln1b = (const float*)d_in[11];
  const float* ln2w = (const float*)d_in[12];
  const float* ln2b = (const float*)d_in[13];
  const float* W1 = (const float*)d_in[14];
  const float* b1 = (const float*)d_in[15];
  const float* W2 = (const float*)d_in[16];
  const float* b2 = (const float*)d_in[17];
  float* outp = (float*)d_out;

  int n = in_sizes[0] / 128;      // 50000 nodes
  int E = in_sizes[1] / 2;        // 800000 edges

  const size_t ND  = (size_t)n * 128;
  const size_t ND2 = ND / 2;
  const size_t EH  = (size_t)E * H_HEADS;

  float* ws = (float*)d_ws;
  ushort* x2b  = (ushort*)ws;                      // ND bf16
  ushort* qb   = (ushort*)(ws + ND2);
  ushort* kb   = (ushort*)(ws + 2*ND2);
  ushort* vb   = (ushort*)(ws + 3*ND2);
  float*  sbuf = ws + 4*ND2;                       // EH f32 (scores, row order)
  float*  cbuf = ws + 4*ND2 + EH;                  // EH f32 (alpha, col order)
  ushort* aggb = (ushort*)(ws + 4*ND2 + 2*EH);     // ND bf16
  int* crow    = (int*)(ws + 5*ND2 + 2*EH);
  int* cposr   = crow + E;
  int* rcol    = cposr + E;
  int* pose    = rcol + E;
  int* rptr    = pose + E;
  int* cptr    = rptr + (n + 4);
  int* cntR    = cptr + (n + 4);
  int* cntC    = cntR + n;
  int* curR    = cntC + n;
  int* curC    = curR + n;
  int* partial = curC + n;                         // 2*nb ints (nb <= 256)
  ushort* wbuf = (ushort*)(partial + 512);
  ushort* Wqb = wbuf;                              // Wq,Wk,Wv contiguous for qkv_gemm
  ushort* Wkb = Wqb + 16384;
  ushort* Wvb = Wkb + 16384;
  ushort* Wob = Wvb + 16384;
  ushort* W1b = Wob + 16384;
  ushort* W2b = W1b + 65536;
  ushort* h1  = qb;                                // n*512 bf16, aliases qb..sbuf

  (void)hipMemsetAsync(cntR, 0, 2*n*sizeof(int), stream);

  // weight conversion (independent)
  CvtArgs ca;
  ca.s[0]=Wq; ca.s[1]=Wk; ca.s[2]=Wv; ca.s[3]=Wo; ca.s[4]=W1; ca.s[5]=W2;
  ca.d[0]=Wqb; ca.d[1]=Wkb; ca.d[2]=Wvb; ca.d[3]=Wob; ca.d[4]=W1b; ca.d[5]=W2b;
  ca.cnt[0]=ca.cnt[1]=ca.cnt[2]=ca.cnt[3]=16384; ca.cnt[4]=ca.cnt[5]=65536;
  cvt6_kernel<<<dim3(65536/256, 6), 256, 0, stream>>>(ca);

  // CSR builds
  int ebE = (E + 255)/256;
  int nb = (n + 1023)/1024;
  hist2_kernel<<<ebE, 256, 0, stream>>>(ei, cntR, cntC, E);
  scan_reduce <<<dim3(nb,2), 256, 0, stream>>>(cntR, partial, n, nb);
  scan_mid    <<<dim3(1,2),  256, 0, stream>>>(partial, nb, rptr, cptr, n);
  scan_scatter<<<dim3(nb,2), 256, 0, stream>>>(cntR, partial, rptr, cptr, curR, curC, n, nb);
  fill_r_kernel<<<ebE, 256, 0, stream>>>(ei, curR, rcol, pose, E);
  fill_c_kernel<<<ebE, 256, 0, stream>>>(ei, curC, pose, crow, cposr, E);

  // LN1 -> bf16
  ln_kernel<<<(n+3)/4, 256, 0, stream>>>(feats, ln1w, ln1b, x2b, n);

  // fused QKV projections (bf16 MFMA, bf16 out)
  int gm = (n + 63)/64;
  qkv_gemm<<<dim3(gm,3), 256, 0, stream>>>(x2b, Wqb, bq, bk, bv, qb, kb, vb, n);

  // fused segmented softmax (online m,d), alpha scattered to col-CSR order
  row_softmax_kernel<<<(n+3)/4, 256, 0, stream>>>(qb, kb, rptr, rcol, cposr, sbuf, cbuf, n);

  // gather aggregation (streamed alpha, 2 edges in flight) -> bf16
  agg_kernel<<<(n+3)/4, 256, 0, stream>>>(vb, cbuf, cptr, crow, aggb, n);

  // attention out projection + residual -> d_out (f32)
  mfma_gemm<8,0,1,0><<<dim3(gm,1), 256, 0, stream>>>(aggb, Wob, bo, feats, outp, n, 128, 128);

  // LN2 -> bf16
  ln_kernel<<<(n+3)/4, 256, 0, stream>>>(outp, ln2w, ln2b, x2b, n);

  // FFN
  mfma_gemm<8,1,0,1><<<dim3(gm,4), 256, 0, stream>>>(x2b, W1b, b1, nullptr, h1,  n, 128, 512);
  mfma_gemm<8,1,1,0><<<dim3(gm,1), 256, 0, stream>>>(h1,  W2b, b2, outp,    outp, n, 512, 128);
}

// Round 8
// 533.853 us; speedup vs baseline: 1.4779x; 1.0026x over previous
//
#include <hip/hip_runtime.h>
#include <hip/hip_bf16.h>
#include <math.h>

#define H_HEADS 8
constexpr float LN_EPS = 1e-5f;

using short8 = __attribute__((ext_vector_type(8))) short;
using f32x4  = __attribute__((ext_vector_type(4))) float;

__device__ __forceinline__ ushort f2bf(float v){
  __hip_bfloat16 h = __float2bfloat16(v);
  return *reinterpret_cast<ushort*>(&h);
}
__device__ __forceinline__ float bf2f(ushort u){
  return __uint_as_float(((unsigned)u) << 16);
}

// ---------- LayerNorm (ddof=1), f32 in -> bf16 out, one wave per row ----------
__global__ void ln_kernel(const float* __restrict__ x, const float* __restrict__ w,
                          const float* __restrict__ b, ushort* __restrict__ out, int nrows){
  int wid = threadIdx.x >> 6, lane = threadIdx.x & 63;
  int r = blockIdx.x * (blockDim.x >> 6) + wid;
  if (r >= nrows) return;
  float2 v = ((const float2*)(x + (size_t)r*128))[lane];
  float s = v.x + v.y;
  #pragma unroll
  for (int o = 32; o; o >>= 1) s += __shfl_xor(s, o);
  float mu = s * (1.0f/128.0f);
  float d0 = v.x - mu, d1 = v.y - mu;
  float ss = d0*d0 + d1*d1;
  #pragma unroll
  for (int o = 32; o; o >>= 1) ss += __shfl_xor(ss, o);
  float sd = sqrtf(ss * (1.0f/127.0f));
  float inv = 1.0f / (sd + LN_EPS);
  float2 wv = ((const float2*)w)[lane];
  float2 bv = ((const float2*)b)[lane];
  ushort2 o2 = { f2bf(d0*inv*wv.x + bv.x), f2bf(d1*inv*wv.y + bv.y) };
  ((ushort2*)(out + (size_t)r*128))[lane] = o2;
}

// ---------- weight f32 -> bf16 conversion (all 6 in one launch) ----------
struct CvtArgs { const float* s[6]; ushort* d[6]; int cnt[6]; };
__global__ void cvt6_kernel(CvtArgs a){
  int w = blockIdx.y;
  int i = blockIdx.x*blockDim.x + threadIdx.x;
  if (i < a.cnt[w]) a.d[w][i] = f2bf(a.s[w][i]);
}

// ---------- bf16 MFMA GEMM, compile-time K, 2-deep register pipeline ----------
// out[M][Nout] = A[M][K] @ W[Nout][K]^T + bias (+relu)(+resid)
template<int K, int NT, int RELU, int RESID, int OUT_BF16>
__global__ __launch_bounds__(256) void mfma_gemm(
    const ushort* __restrict__ A, const ushort* __restrict__ W,
    const float* __restrict__ bias, const float* __restrict__ resid,
    void* __restrict__ out, int M, int Nout){
  constexpr int NK = K/32;
  int wid = threadIdx.x >> 6, lane = threadIdx.x & 63;
  int mb = blockIdx.x * 64 + wid * 16;
  if (mb >= M) return;
  int cb = blockIdx.y * (NT*16);
  int lrow = lane & 15, kgrp = lane >> 4;
  int row = mb + lrow;
  bool rowok = row < M;
  const ushort* arow = A + (size_t)(rowok ? row : (M-1)) * K + kgrp*8;
  const ushort* wrow = W + (size_t)(cb + lrow) * K + kgrp*8;

  f32x4 acc[NT] = {};
  short8 af[2]; short8 bf[2][NT];

  // prologue: kt = 0
  af[0] = rowok ? *(const short8*)(arow) : short8{};
  #pragma unroll
  for (int nt = 0; nt < NT; ++nt)
    bf[0][nt] = *(const short8*)(wrow + (size_t)nt*16*K);

  #pragma unroll
  for (int kk = 0; kk < NK; ++kk){
    int cur = kk & 1, nxt = cur ^ 1;
    if (kk + 1 < NK){
      int kt = (kk+1)*32;
      af[nxt] = rowok ? *(const short8*)(arow + kt) : short8{};
      #pragma unroll
      for (int nt = 0; nt < NT; ++nt)
        bf[nxt][nt] = *(const short8*)(wrow + (size_t)nt*16*K + kt);
    }
    #pragma unroll
    for (int nt = 0; nt < NT; ++nt)
      acc[nt] = __builtin_amdgcn_mfma_f32_16x16x32_bf16(af[cur], bf[cur][nt], acc[nt], 0, 0, 0);
  }

  int r0 = mb + kgrp*4;
  #pragma unroll
  for (int nt = 0; nt < NT; ++nt){
    int c = cb + nt*16 + lrow;
    float bsum = bias[c];
    #pragma unroll
    for (int i = 0; i < 4; ++i){
      int r = r0 + i;
      if (r >= M) continue;
      float v = acc[nt][i] + bsum;
      if (RELU)  v = fmaxf(v, 0.0f);
      if (RESID) v += resid[(size_t)r*Nout + c];
      if (OUT_BF16) ((ushort*)out)[(size_t)r*Nout + c] = f2bf(v);
      else          ((float*)out)[(size_t)r*Nout + c] = v;
    }
  }
}

// ---------- fused QKV GEMM: blockIdx.y selects {Wq,Wk,Wv} (contiguous) ----------
__global__ __launch_bounds__(256) void qkv_gemm(
    const ushort* __restrict__ A, const ushort* __restrict__ Wcat,
    const float* __restrict__ bq, const float* __restrict__ bk, const float* __restrict__ bv,
    ushort* __restrict__ qb, ushort* __restrict__ kb, ushort* __restrict__ vb, int M){
  const int K = 128;
  int y = blockIdx.y;
  const ushort* W = Wcat + (size_t)y * 16384;
  const float* bias = (y==0) ? bq : (y==1) ? bk : bv;
  ushort* out = (y==0) ? qb : (y==1) ? kb : vb;

  int wid = threadIdx.x >> 6, lane = threadIdx.x & 63;
  int mb = blockIdx.x * 64 + wid * 16;
  if (mb >= M) return;
  int lrow = lane & 15, kgrp = lane >> 4;
  int row = mb + lrow;
  bool rowok = row < M;
  const ushort* arow = A + (size_t)(rowok ? row : (M-1)) * K + kgrp*8;
  const ushort* wrow = W + (size_t)lrow * K + kgrp*8;

  f32x4 acc[8] = {};
  short8 af[2]; short8 bf[2][8];
  af[0] = rowok ? *(const short8*)(arow) : short8{};
  #pragma unroll
  for (int nt = 0; nt < 8; ++nt)
    bf[0][nt] = *(const short8*)(wrow + (size_t)nt*16*K);

  #pragma unroll
  for (int kk = 0; kk < 4; ++kk){
    int cur = kk & 1, nxt = cur ^ 1;
    if (kk + 1 < 4){
      int kt = (kk+1)*32;
      af[nxt] = rowok ? *(const short8*)(arow + kt) : short8{};
      #pragma unroll
      for (int nt = 0; nt < 8; ++nt)
        bf[nxt][nt] = *(const short8*)(wrow + (size_t)nt*16*K + kt);
    }
    #pragma unroll
    for (int nt = 0; nt < 8; ++nt)
      acc[nt] = __builtin_amdgcn_mfma_f32_16x16x32_bf16(af[cur], bf[cur][nt], acc[nt], 0, 0, 0);
  }
  int r0 = mb + kgrp*4;
  #pragma unroll
  for (int nt = 0; nt < 8; ++nt){
    int c = nt*16 + lrow;
    float bsum = bias[c];
    #pragma unroll
    for (int i = 0; i < 4; ++i){
      int r = r0 + i;
      if (r >= M) continue;
      out[(size_t)r*128 + c] = f2bf(acc[nt][i] + bsum);
    }
  }
}

// ---------- CSR builds ----------
__global__ void hist2_kernel(const int* __restrict__ ei, int* __restrict__ cntR,
                             int* __restrict__ cntC, int E){
  int e = blockIdx.x*blockDim.x + threadIdx.x;
  if (e >= E) return;
  int2 rc = ((const int2*)ei)[e];
  atomicAdd(&cntR[rc.x], 1);
  atomicAdd(&cntC[rc.y], 1);
}

// ---------- parallel 3-phase exclusive scan (both arrays via gridDim.y=2) ----------
__global__ __launch_bounds__(256) void scan_reduce(const int* __restrict__ cnt0,
                                                   int* __restrict__ partial, int n, int nb){
  const int* cnt = cnt0 + (size_t)blockIdx.y * n;
  int t = threadIdx.x;
  int base = blockIdx.x*1024 + t*4;
  int s = 0;
  #pragma unroll
  for (int j = 0; j < 4; ++j){ int i = base+j; if (i < n) s += cnt[i]; }
  __shared__ int sm[256];
  sm[t] = s; __syncthreads();
  for (int off = 128; off; off >>= 1){
    if (t < off) sm[t] += sm[t+off];
    __syncthreads();
  }
  if (t == 0) partial[blockIdx.y*nb + blockIdx.x] = sm[0];
}

__global__ __launch_bounds__(256) void scan_mid(int* __restrict__ partial, int nb,
                                                int* __restrict__ rptr, int* __restrict__ cptr, int n){
  int y = blockIdx.y;
  int* p = partial + y*nb;
  int t = threadIdx.x;
  __shared__ int sm[256];
  sm[t] = (t < nb) ? p[t] : 0;
  __syncthreads();
  for (int off = 1; off < 256; off <<= 1){
    int v = (t >= off) ? sm[t-off] : 0;
    __syncthreads();
    sm[t] += v;
    __syncthreads();
  }
  if (t < nb) p[t] = (t == 0) ? 0 : sm[t-1];
  if (t == 0) (y ? cptr : rptr)[n] = sm[255];
}

__global__ __launch_bounds__(256) void scan_scatter(const int* __restrict__ cnt0,
                                                    const int* __restrict__ partial,
                                                    int* __restrict__ rptr, int* __restrict__ cptr,
                                                    int* __restrict__ curR, int* __restrict__ curC,
                                                    int n, int nb){
  int y = blockIdx.y;
  const int* cnt = cnt0 + (size_t)y * n;
  int* ptr = y ? cptr : rptr;
  int* cur = y ? curC : curR;
  int t = threadIdx.x;
  int base = blockIdx.x*1024 + t*4;
  int v[4]; int s = 0;
  #pragma unroll
  for (int j = 0; j < 4; ++j){ int i = base+j; v[j] = (i<n)?cnt[i]:0; s += v[j]; }
  __shared__ int sm[256];
  sm[t] = s; __syncthreads();
  for (int off = 1; off < 256; off <<= 1){
    int x = (t >= off) ? sm[t-off] : 0;
    __syncthreads();
    sm[t] += x;
    __syncthreads();
  }
  int pre = partial[y*nb + blockIdx.x] + ((t==0)?0:sm[t-1]);
  #pragma unroll
  for (int j = 0; j < 4; ++j){
    int i = base+j;
    if (i < n){ ptr[i] = pre; cur[i] = pre; pre += v[j]; }
  }
}

// row-CSR fill: rcol[pos] = col of edge, pose[e] = pos
__global__ void fill_r_kernel(const int* __restrict__ ei, int* __restrict__ curR,
                              int* __restrict__ rcol, int* __restrict__ pose, int E){
  int e = blockIdx.x*blockDim.x + threadIdx.x;
  if (e >= E) return;
  int2 rc = ((const int2*)ei)[e];
  int pos = atomicAdd(&curR[rc.x], 1);
  rcol[pos] = rc.y;
  pose[e] = pos;
}

// col-CSR fill: crow[pos] = row; cposr[row-CSR pos] = col-CSR pos
__global__ void fill_c_kernel(const int* __restrict__ ei, int* __restrict__ curC,
                              const int* __restrict__ pose, int* __restrict__ crow,
                              int* __restrict__ cposr, int E){
  int e = blockIdx.x*blockDim.x + threadIdx.x;
  if (e >= E) return;
  int2 rc = ((const int2*)ei)[e];
  int pos = atomicAdd(&curC[rc.y], 1);
  crow[pos] = rc.x;
  cposr[pose[e]] = pos;
}

// ---------- fused segmented softmax over row-CSR (online m,d; alpha -> col-CSR order) ----------
__global__ void row_softmax_kernel(const ushort* __restrict__ qb, const ushort* __restrict__ kb,
                                   const int* __restrict__ rptr, const int* __restrict__ rcol,
                                   const int* __restrict__ cposr,
                                   float* __restrict__ sbuf, float* __restrict__ cbuf, int n){
  int wid = threadIdx.x >> 6, lane = threadIdx.x & 63;
  int r = blockIdx.x * (blockDim.x >> 6) + wid;
  if (r >= n) return;
  int lo = rptr[r], hi = rptr[r+1];
  if (lo >= hi) return;
  int h = lane & 7, el = lane >> 3;

  float kf[16];
  {
    const short8* kp = (const short8*)(kb + (size_t)r*128 + h*16);
    short8 k0 = kp[0], k1 = kp[1];
    #pragma unroll
    for (int i = 0; i < 8; ++i){
      kf[i]   = bf2f((ushort)k0[i]);
      kf[8+i] = bf2f((ushort)k1[i]);
    }
  }

  float m = -1e30f, d = 0.f;
  for (int j = lo + el; j < hi; j += 8){
    int c = rcol[j];
    const short8* qp = (const short8*)(qb + (size_t)c*128 + h*16);
    short8 q0 = qp[0], q1 = qp[1];
    float s = 0.f;
    #pragma unroll
    for (int i = 0; i < 8; ++i){
      s += bf2f((ushort)q0[i]) * kf[i];
      s += bf2f((ushort)q1[i]) * kf[8+i];
    }
    s *= 0.25f;
    sbuf[(size_t)j*8 + h] = s;
    float nm = fmaxf(m, s);
    d = d*__expf(m - nm) + __expf(s - nm);
    m = nm;
  }
  #pragma unroll
  for (int o = 8; o < 64; o <<= 1){
    float om = __shfl_xor(m, o);
    float od = __shfl_xor(d, o);
    float nm = fmaxf(m, om);
    d = d*__expf(m - nm) + od*__expf(om - nm);
    m = nm;
  }
  float invd = 1.0f / d;

  for (int j = lo + el; j < hi; j += 8){
    float s = sbuf[(size_t)j*8 + h];
    float a = __expf(s - m) * invd;
    cbuf[(size_t)cposr[j]*8 + h] = a;     // scatter to col-CSR order
  }
}

// ---------- gather aggregation over col-CSR -> bf16 agg ----------
__global__ void agg_kernel(const ushort* __restrict__ vb, const float* __restrict__ cbuf,
                           const int* __restrict__ cptr, const int* __restrict__ crow,
                           ushort* __restrict__ aggb, int n){
  int wid = threadIdx.x >> 6, lane = threadIdx.x & 63;
  int node = blockIdx.x * (blockDim.x >> 6) + wid;
  if (node >= n) return;
  int lo = cptr[node], hi = cptr[node+1];
  int half = lane >> 5, l32 = lane & 31;
  int h = l32 >> 2;
  float4 acc = {0.f, 0.f, 0.f, 0.f};
  for (int j = lo + half; j < hi; j += 2){
    float a = cbuf[(size_t)j*8 + h];
    int row = crow[j];
    ushort4 vv = *(const ushort4*)(vb + (size_t)row*128 + l32*4);
    acc.x = fmaf(a, bf2f(vv.x), acc.x);
    acc.y = fmaf(a, bf2f(vv.y), acc.y);
    acc.z = fmaf(a, bf2f(vv.z), acc.z);
    acc.w = fmaf(a, bf2f(vv.w), acc.w);
  }
  acc.x += __shfl_xor(acc.x, 32);
  acc.y += __shfl_xor(acc.y, 32);
  acc.z += __shfl_xor(acc.z, 32);
  acc.w += __shfl_xor(acc.w, 32);
  if (half == 0){
    ushort4 o = { f2bf(acc.x), f2bf(acc.y), f2bf(acc.z), f2bf(acc.w) };
    *(ushort4*)(aggb + (size_t)node*128 + l32*4) = o;
  }
}

extern "C" void kernel_launch(void* const* d_in, const int* in_sizes, int n_in,
                              void* d_out, int out_size, void* d_ws, size_t ws_size,
                              hipStream_t stream){
  const float* feats = (const float*)d_in[0];
  const int*   ei    = (const int*)  d_in[1];
  const float* Wq = (const float*)d_in[2];
  const float* bq = (const float*)d_in[3];
  const float* Wk = (const float*)d_in[4];
  const float* bk = (const float*)d_in[5];
  const float* Wv = (const float*)d_in[6];
  const float* bv = (const float*)d_in[7];
  const float* Wo = (const float*)d_in[8];
  const float* bo = (const float*)d_in[9];
  const float* ln1w = (const float*)d_in[10];
  const float* ln1b = (const float*)d_in[11];
  const float* ln2w = (const float*)d_in[12];
  const float* ln2b = (const float*)d_in[13];
  const float* W1 = (const float*)d_in[14];
  const float* b1 = (const float*)d_in[15];
  const float* W2 = (const float*)d_in[16];
  const float* b2 = (const float*)d_in[17];
  float* outp = (float*)d_out;

  int n = in_sizes[0] / 128;      // 50000 nodes
  int E = in_sizes[1] / 2;        // 800000 edges

  const size_t ND  = (size_t)n * 128;
  const size_t ND2 = ND / 2;
  const size_t EH  = (size_t)E * H_HEADS;

  float* ws = (float*)d_ws;
  ushort* x2b  = (ushort*)ws;                      // ND bf16
  ushort* qb   = (ushort*)(ws + ND2);
  ushort* kb   = (ushort*)(ws + 2*ND2);
  ushort* vb   = (ushort*)(ws + 3*ND2);
  float*  sbuf = ws + 4*ND2;                       // EH f32 (scores, row order)
  float*  cbuf = ws + 4*ND2 + EH;                  // EH f32 (alpha, col order)
  ushort* aggb = (ushort*)(ws + 4*ND2 + 2*EH);     // ND bf16
  int* crow    = (int*)(ws + 5*ND2 + 2*EH);
  int* cposr   = crow + E;
  int* rcol    = cposr + E;
  int* pose    = rcol + E;
  int* rptr    = pose + E;
  int* cptr    = rptr + (n + 4);
  int* cntR    = cptr + (n + 4);
  int* cntC    = cntR + n;
  int* curR    = cntC + n;
  int* curC    = curR + n;
  int* partial = curC + n;                         // 2*nb ints (nb <= 256)
  ushort* wbuf = (ushort*)(partial + 512);
  ushort* Wqb = wbuf;                              // Wq,Wk,Wv contiguous for qkv_gemm
  ushort* Wkb = Wqb + 16384;
  ushort* Wvb = Wkb + 16384;
  ushort* Wob = Wvb + 16384;
  ushort* W1b = Wob + 16384;
  ushort* W2b = W1b + 65536;
  ushort* h1  = qb;                                // n*512 bf16, aliases qb..sbuf

  (void)hipMemsetAsync(cntR, 0, 2*n*sizeof(int), stream);

  // weight conversion (independent)
  CvtArgs ca;
  ca.s[0]=Wq; ca.s[1]=Wk; ca.s[2]=Wv; ca.s[3]=Wo; ca.s[4]=W1; ca.s[5]=W2;
  ca.d[0]=Wqb; ca.d[1]=Wkb; ca.d[2]=Wvb; ca.d[3]=Wob; ca.d[4]=W1b; ca.d[5]=W2b;
  ca.cnt[0]=ca.cnt[1]=ca.cnt[2]=ca.cnt[3]=16384; ca.cnt[4]=ca.cnt[5]=65536;
  cvt6_kernel<<<dim3(65536/256, 6), 256, 0, stream>>>(ca);

  // CSR builds
  int ebE = (E + 255)/256;
  int nb = (n + 1023)/1024;
  hist2_kernel<<<ebE, 256, 0, stream>>>(ei, cntR, cntC, E);
  scan_reduce <<<dim3(nb,2), 256, 0, stream>>>(cntR, partial, n, nb);
  scan_mid    <<<dim3(1,2),  256, 0, stream>>>(partial, nb, rptr, cptr, n);
  scan_scatter<<<dim3(nb,2), 256, 0, stream>>>(cntR, partial, rptr, cptr, curR, curC, n, nb);
  fill_r_kernel<<<ebE, 256, 0, stream>>>(ei, curR, rcol, pose, E);
  fill_c_kernel<<<ebE, 256, 0, stream>>>(ei, curC, pose, crow, cposr, E);

  // LN1 -> bf16
  ln_kernel<<<(n+3)/4, 256, 0, stream>>>(feats, ln1w, ln1b, x2b, n);

  // fused QKV projections (bf16 MFMA, bf16 out)
  int gm = (n + 63)/64;
  qkv_gemm<<<dim3(gm,3), 256, 0, stream>>>(x2b, Wqb, bq, bk, bv, qb, kb, vb, n);

  // fused segmented softmax (online m,d), alpha scattered to col-CSR order
  row_softmax_kernel<<<(n+3)/4, 256, 0, stream>>>(qb, kb, rptr, rcol, cposr, sbuf, cbuf, n);

  // gather aggregation (streamed alpha, 2 edges in flight) -> bf16
  agg_kernel<<<(n+3)/4, 256, 0, stream>>>(vb, cbuf, cptr, crow, aggb, n);

  // attention out projection + residual -> d_out (f32)
  mfma_gemm<128,8,0,1,0><<<dim3(gm,1), 256, 0, stream>>>(aggb, Wob, bo, feats, outp, n, 128);

  // LN2 -> bf16
  ln_kernel<<<(n+3)/4, 256, 0, stream>>>(outp, ln2w, ln2b, x2b, n);

  // FFN
  mfma_gemm<128,8,1,0,1><<<dim3(gm,4), 256, 0, stream>>>(x2b, W1b, b1, nullptr, h1,  n, 512);
  mfma_gemm<512,8,1,1,0><<<dim3(gm,1), 256, 0, stream>>>(h1,  W2b, b2, outp,    outp, n, 128);
}

// Round 9
// 409.015 us; speedup vs baseline: 1.9290x; 1.3052x over previous
//
#include <hip/hip_runtime.h>
#include <hip/hip_bf16.h>
#include <math.h>

#define H_HEADS 8
constexpr float LN_EPS = 1e-5f;

using short8 = __attribute__((ext_vector_type(8))) short;
using f32x4  = __attribute__((ext_vector_type(4))) float;

__device__ __forceinline__ ushort f2bf(float v){
  __hip_bfloat16 h = __float2bfloat16(v);
  return *reinterpret_cast<ushort*>(&h);
}
__device__ __forceinline__ float bf2f(ushort u){
  return __uint_as_float(((unsigned)u) << 16);
}

// async global->LDS, 16B per lane; dest = wave-uniform base + lane*16
__device__ __forceinline__ void stage16(const ushort* g, ushort* l){
  __builtin_amdgcn_global_load_lds((const __attribute__((address_space(1))) unsigned*)g,
                                   (__attribute__((address_space(3))) unsigned*)l,
                                   16, 0, 0);
}

// ---------- LayerNorm (ddof=1), f32 in -> bf16 out, one wave per row ----------
__global__ void ln_kernel(const float* __restrict__ x, const float* __restrict__ w,
                          const float* __restrict__ b, ushort* __restrict__ out, int nrows){
  int wid = threadIdx.x >> 6, lane = threadIdx.x & 63;
  int r = blockIdx.x * (blockDim.x >> 6) + wid;
  if (r >= nrows) return;
  float2 v = ((const float2*)(x + (size_t)r*128))[lane];
  float s = v.x + v.y;
  #pragma unroll
  for (int o = 32; o; o >>= 1) s += __shfl_xor(s, o);
  float mu = s * (1.0f/128.0f);
  float d0 = v.x - mu, d1 = v.y - mu;
  float ss = d0*d0 + d1*d1;
  #pragma unroll
  for (int o = 32; o; o >>= 1) ss += __shfl_xor(ss, o);
  float sd = sqrtf(ss * (1.0f/127.0f));
  float inv = 1.0f / (sd + LN_EPS);
  float2 wv = ((const float2*)w)[lane];
  float2 bv = ((const float2*)b)[lane];
  ushort2 o2 = { f2bf(d0*inv*wv.x + bv.x), f2bf(d1*inv*wv.y + bv.y) };
  ((ushort2*)(out + (size_t)r*128))[lane] = o2;
}

// ---------- weight f32 -> bf16 conversion (all 6 in one launch) ----------
struct CvtArgs { const float* s[6]; ushort* d[6]; int cnt[6]; };
__global__ void cvt6_kernel(CvtArgs a){
  int w = blockIdx.y;
  int i = blockIdx.x*blockDim.x + threadIdx.x;
  if (i < a.cnt[w]) a.d[w][i] = f2bf(a.s[w][i]);
}

// ---------- LDS-staged bf16 MFMA GEMM ----------
// Block: 4 waves x 16 rows = 64 rows, 128 cols (cb). W chunk (128 cols x 128 k,
// 32 KB) staged via global_load_lds with XOR-swizzled 16B granules
// (slot = g ^ (col&7), applied on BOTH stage-source and ds_read — rule 21).
// A-chunk fully prefetched to regs (4 x dwordx4), double-buffered across chunks.
template<int K, int RELU, int RESID, int OUT_BF16>
__device__ __forceinline__ void gemm_lds_body(
    const ushort* __restrict__ A, const ushort* __restrict__ W,
    const float* __restrict__ bias, const float* __restrict__ resid,
    void* __restrict__ out, int M, int Nout, int cb, ushort* Wl){
  constexpr int NCH = K / 128;
  int t = threadIdx.x;
  int wid = t >> 6, lane = t & 63;
  int mb = blockIdx.x * 64 + wid * 16;
  int lrow = lane & 15, kgrp = lane >> 4;
  int row = mb + lrow;
  bool rowok = row < M;
  const ushort* arow = A + (size_t)(rowok ? row : (M-1)) * K + kgrp*8;

  f32x4 acc[8] = {};
  short8 af[2][4];

  // stage chunk 0 (8 passes x 1KB/wave) + prefetch A chunk 0
  #pragma unroll
  for (int p = 0; p < 8; ++p){
    int L = p*256 + t;
    int colp = L >> 4, sp = L & 15;
    stage16(W + (size_t)colp*K + ((sp ^ (colp & 7)) << 3),
            (ushort*)((char*)Wl + ((size_t)(p*256 + (t & ~63)))*16));
  }
  #pragma unroll
  for (int kk = 0; kk < 4; ++kk)
    af[0][kk] = *(const short8*)(arow + kk*32);

  #pragma unroll
  for (int ci = 0; ci < NCH; ++ci){
    __syncthreads();                       // LDS chunk + A regs ready
    int cur = ci & 1;
    if (ci + 1 < NCH){                     // prefetch next A chunk under compute
      #pragma unroll
      for (int kk = 0; kk < 4; ++kk)
        af[cur^1][kk] = *(const short8*)(arow + (ci+1)*128 + kk*32);
    }
    #pragma unroll
    for (int kk = 0; kk < 4; ++kk){
      #pragma unroll
      for (int nt = 0; nt < 8; ++nt){
        int colc = nt*16 + lrow;
        int g = kk*4 + kgrp;
        short8 bfv = *(const short8*)((const char*)Wl + colc*256 + ((g ^ (colc & 7))*16));
        acc[nt] = __builtin_amdgcn_mfma_f32_16x16x32_bf16(af[cur][kk], bfv, acc[nt], 0, 0, 0);
      }
    }
    if (ci + 1 < NCH){
      __syncthreads();                     // readers done; restage LDS
      const ushort* Wc = W + (ci+1)*128;
      #pragma unroll
      for (int p = 0; p < 8; ++p){
        int L = p*256 + t;
        int colp = L >> 4, sp = L & 15;
        stage16(Wc + (size_t)colp*K + ((sp ^ (colp & 7)) << 3),
                (ushort*)((char*)Wl + ((size_t)(p*256 + (t & ~63)))*16));
      }
    }
  }

  int r0 = mb + kgrp*4;
  #pragma unroll
  for (int nt = 0; nt < 8; ++nt){
    int c = cb + nt*16 + lrow;
    float bsum = bias[c];
    #pragma unroll
    for (int i = 0; i < 4; ++i){
      int r = r0 + i;
      if (r >= M) continue;
      float v = acc[nt][i] + bsum;
      if (RELU)  v = fmaxf(v, 0.0f);
      if (RESID) v += resid[(size_t)r*Nout + c];
      if (OUT_BF16) ((ushort*)out)[(size_t)r*Nout + c] = f2bf(v);
      else          ((float*)out)[(size_t)r*Nout + c] = v;
    }
  }
}

template<int K, int RELU, int RESID, int OUT_BF16>
__global__ __launch_bounds__(256) void gemm_lds(
    const ushort* __restrict__ A, const ushort* __restrict__ Wfull,
    const float* __restrict__ bias, const float* __restrict__ resid,
    void* __restrict__ out, int M, int Nout){
  __shared__ __align__(16) ushort Wl[16384];   // 32 KB
  int cb = blockIdx.y * 128;
  gemm_lds_body<K,RELU,RESID,OUT_BF16>(A, Wfull + (size_t)cb*K, bias, resid, out, M, Nout, cb, Wl);
}

__global__ __launch_bounds__(256) void qkv_lds(
    const ushort* __restrict__ A, const ushort* __restrict__ Wcat,
    const float* __restrict__ bq, const float* __restrict__ bk, const float* __restrict__ bv,
    ushort* __restrict__ qb, ushort* __restrict__ kb, ushort* __restrict__ vb, int M){
  __shared__ __align__(16) ushort Wl[16384];
  int y = blockIdx.y;
  const float* bias = (y==0) ? bq : (y==1) ? bk : bv;
  ushort* out = (y==0) ? qb : (y==1) ? kb : vb;
  gemm_lds_body<128,0,0,1>(A, Wcat + (size_t)y*16384, bias, nullptr, out, M, 128, 0, Wl);
}

// ---------- CSR builds ----------
__global__ void hist2_kernel(const int* __restrict__ ei, int* __restrict__ cntR,
                             int* __restrict__ cntC, int E){
  int e = blockIdx.x*blockDim.x + threadIdx.x;
  if (e >= E) return;
  int2 rc = ((const int2*)ei)[e];
  atomicAdd(&cntR[rc.x], 1);
  atomicAdd(&cntC[rc.y], 1);
}

// ---------- parallel 3-phase exclusive scan (both arrays via gridDim.y=2) ----------
__global__ __launch_bounds__(256) void scan_reduce(const int* __restrict__ cnt0,
                                                   int* __restrict__ partial, int n, int nb){
  const int* cnt = cnt0 + (size_t)blockIdx.y * n;
  int t = threadIdx.x;
  int base = blockIdx.x*1024 + t*4;
  int s = 0;
  #pragma unroll
  for (int j = 0; j < 4; ++j){ int i = base+j; if (i < n) s += cnt[i]; }
  __shared__ int sm[256];
  sm[t] = s; __syncthreads();
  for (int off = 128; off; off >>= 1){
    if (t < off) sm[t] += sm[t+off];
    __syncthreads();
  }
  if (t == 0) partial[blockIdx.y*nb + blockIdx.x] = sm[0];
}

__global__ __launch_bounds__(256) void scan_mid(int* __restrict__ partial, int nb,
                                                int* __restrict__ rptr, int* __restrict__ cptr, int n){
  int y = blockIdx.y;
  int* p = partial + y*nb;
  int t = threadIdx.x;
  __shared__ int sm[256];
  sm[t] = (t < nb) ? p[t] : 0;
  __syncthreads();
  for (int off = 1; off < 256; off <<= 1){
    int v = (t >= off) ? sm[t-off] : 0;
    __syncthreads();
    sm[t] += v;
    __syncthreads();
  }
  if (t < nb) p[t] = (t == 0) ? 0 : sm[t-1];
  if (t == 0) (y ? cptr : rptr)[n] = sm[255];
}

__global__ __launch_bounds__(256) void scan_scatter(const int* __restrict__ cnt0,
                                                    const int* __restrict__ partial,
                                                    int* __restrict__ rptr, int* __restrict__ cptr,
                                                    int* __restrict__ curR, int* __restrict__ curC,
                                                    int n, int nb){
  int y = blockIdx.y;
  const int* cnt = cnt0 + (size_t)y * n;
  int* ptr = y ? cptr : rptr;
  int* cur = y ? curC : curR;
  int t = threadIdx.x;
  int base = blockIdx.x*1024 + t*4;
  int v[4]; int s = 0;
  #pragma unroll
  for (int j = 0; j < 4; ++j){ int i = base+j; v[j] = (i<n)?cnt[i]:0; s += v[j]; }
  __shared__ int sm[256];
  sm[t] = s; __syncthreads();
  for (int off = 1; off < 256; off <<= 1){
    int x = (t >= off) ? sm[t-off] : 0;
    __syncthreads();
    sm[t] += x;
    __syncthreads();
  }
  int pre = partial[y*nb + blockIdx.x] + ((t==0)?0:sm[t-1]);
  #pragma unroll
  for (int j = 0; j < 4; ++j){
    int i = base+j;
    if (i < n){ ptr[i] = pre; cur[i] = pre; pre += v[j]; }
  }
}

// row-CSR fill: rcol[pos] = col of edge, pose[e] = pos
__global__ void fill_r_kernel(const int* __restrict__ ei, int* __restrict__ curR,
                              int* __restrict__ rcol, int* __restrict__ pose, int E){
  int e = blockIdx.x*blockDim.x + threadIdx.x;
  if (e >= E) return;
  int2 rc = ((const int2*)ei)[e];
  int pos = atomicAdd(&curR[rc.x], 1);
  rcol[pos] = rc.y;
  pose[e] = pos;
}

// col-CSR fill: crow[pos] = row; cposr[row-CSR pos] = col-CSR pos
__global__ void fill_c_kernel(const int* __restrict__ ei, int* __restrict__ curC,
                              const int* __restrict__ pose, int* __restrict__ crow,
                              int* __restrict__ cposr, int E){
  int e = blockIdx.x*blockDim.x + threadIdx.x;
  if (e >= E) return;
  int2 rc = ((const int2*)ei)[e];
  int pos = atomicAdd(&curC[rc.y], 1);
  crow[pos] = rc.x;
  cposr[pose[e]] = pos;
}

// ---------- fused segmented softmax over row-CSR (online m,d; alpha -> col-CSR order) ----------
__global__ void row_softmax_kernel(const ushort* __restrict__ qb, const ushort* __restrict__ kb,
                                   const int* __restrict__ rptr, const int* __restrict__ rcol,
                                   const int* __restrict__ cposr,
                                   float* __restrict__ sbuf, float* __restrict__ cbuf, int n){
  int wid = threadIdx.x >> 6, lane = threadIdx.x & 63;
  int r = blockIdx.x * (blockDim.x >> 6) + wid;
  if (r >= n) return;
  int lo = rptr[r], hi = rptr[r+1];
  if (lo >= hi) return;
  int h = lane & 7, el = lane >> 3;

  float kf[16];
  {
    const short8* kp = (const short8*)(kb + (size_t)r*128 + h*16);
    short8 k0 = kp[0], k1 = kp[1];
    #pragma unroll
    for (int i = 0; i < 8; ++i){
      kf[i]   = bf2f((ushort)k0[i]);
      kf[8+i] = bf2f((ushort)k1[i]);
    }
  }

  float m = -1e30f, d = 0.f;
  for (int j = lo + el; j < hi; j += 8){
    int c = rcol[j];
    const short8* qp = (const short8*)(qb + (size_t)c*128 + h*16);
    short8 q0 = qp[0], q1 = qp[1];
    float s = 0.f;
    #pragma unroll
    for (int i = 0; i < 8; ++i){
      s += bf2f((ushort)q0[i]) * kf[i];
      s += bf2f((ushort)q1[i]) * kf[8+i];
    }
    s *= 0.25f;
    sbuf[(size_t)j*8 + h] = s;
    float nm = fmaxf(m, s);
    d = d*__expf(m - nm) + __expf(s - nm);
    m = nm;
  }
  #pragma unroll
  for (int o = 8; o < 64; o <<= 1){
    float om = __shfl_xor(m, o);
    float od = __shfl_xor(d, o);
    float nm = fmaxf(m, om);
    d = d*__expf(m - nm) + od*__expf(om - nm);
    m = nm;
  }
  float invd = 1.0f / d;

  for (int j = lo + el; j < hi; j += 8){
    float s = sbuf[(size_t)j*8 + h];
    float a = __expf(s - m) * invd;
    cbuf[(size_t)cposr[j]*8 + h] = a;     // scatter to col-CSR order
  }
}

// ---------- gather aggregation over col-CSR -> bf16 agg ----------
__global__ void agg_kernel(const ushort* __restrict__ vb, const float* __restrict__ cbuf,
                           const int* __restrict__ cptr, const int* __restrict__ crow,
                           ushort* __restrict__ aggb, int n){
  int wid = threadIdx.x >> 6, lane = threadIdx.x & 63;
  int node = blockIdx.x * (blockDim.x >> 6) + wid;
  if (node >= n) return;
  int lo = cptr[node], hi = cptr[node+1];
  int half = lane >> 5, l32 = lane & 31;
  int h = l32 >> 2;
  float4 acc = {0.f, 0.f, 0.f, 0.f};
  for (int j = lo + half; j < hi; j += 2){
    float a = cbuf[(size_t)j*8 + h];
    int row = crow[j];
    ushort4 vv = *(const ushort4*)(vb + (size_t)row*128 + l32*4);
    acc.x = fmaf(a, bf2f(vv.x), acc.x);
    acc.y = fmaf(a, bf2f(vv.y), acc.y);
    acc.z = fmaf(a, bf2f(vv.z), acc.z);
    acc.w = fmaf(a, bf2f(vv.w), acc.w);
  }
  acc.x += __shfl_xor(acc.x, 32);
  acc.y += __shfl_xor(acc.y, 32);
  acc.z += __shfl_xor(acc.z, 32);
  acc.w += __shfl_xor(acc.w, 32);
  if (half == 0){
    ushort4 o = { f2bf(acc.x), f2bf(acc.y), f2bf(acc.z), f2bf(acc.w) };
    *(ushort4*)(aggb + (size_t)node*128 + l32*4) = o;
  }
}

extern "C" void kernel_launch(void* const* d_in, const int* in_sizes, int n_in,
                              void* d_out, int out_size, void* d_ws, size_t ws_size,
                              hipStream_t stream){
  const float* feats = (const float*)d_in[0];
  const int*   ei    = (const int*)  d_in[1];
  const float* Wq = (const float*)d_in[2];
  const float* bq = (const float*)d_in[3];
  const float* Wk = (const float*)d_in[4];
  const float* bk = (const float*)d_in[5];
  const float* Wv = (const float*)d_in[6];
  const float* bv = (const float*)d_in[7];
  const float* Wo = (const float*)d_in[8];
  const float* bo = (const float*)d_in[9];
  const float* ln1w = (const float*)d_in[10];
  const float* ln1b = (const float*)d_in[11];
  const float* ln2w = (const float*)d_in[12];
  const float* ln2b = (const float*)d_in[13];
  const float* W1 = (const float*)d_in[14];
  const float* b1 = (const float*)d_in[15];
  const float* W2 = (const float*)d_in[16];
  const float* b2 = (const float*)d_in[17];
  float* outp = (float*)d_out;

  int n = in_sizes[0] / 128;      // 50000 nodes
  int E = in_sizes[1] / 2;        // 800000 edges

  const size_t ND  = (size_t)n * 128;
  const size_t ND2 = ND / 2;
  const size_t EH  = (size_t)E * H_HEADS;

  float* ws = (float*)d_ws;
  ushort* x2b  = (ushort*)ws;                      // ND bf16
  ushort* qb   = (ushort*)(ws + ND2);
  ushort* kb   = (ushort*)(ws + 2*ND2);
  ushort* vb   = (ushort*)(ws + 3*ND2);
  float*  sbuf = ws + 4*ND2;                       // EH f32 (scores, row order)
  float*  cbuf = ws + 4*ND2 + EH;                  // EH f32 (alpha, col order)
  ushort* aggb = (ushort*)(ws + 4*ND2 + 2*EH);     // ND bf16
  int* crow    = (int*)(ws + 5*ND2 + 2*EH);
  int* cposr   = crow + E;
  int* rcol    = cposr + E;
  int* pose    = rcol + E;
  int* rptr    = pose + E;
  int* cptr    = rptr + (n + 4);
  int* cntR    = cptr + (n + 4);
  int* cntC    = cntR + n;
  int* curR    = cntC + n;
  int* curC    = curR + n;
  int* partial = curC + n;                         // 2*nb ints (nb <= 256)
  ushort* wbuf = (ushort*)(partial + 512);
  ushort* Wqb = wbuf;                              // Wq,Wk,Wv contiguous for qkv
  ushort* Wkb = Wqb + 16384;
  ushort* Wvb = Wkb + 16384;
  ushort* Wob = Wvb + 16384;
  ushort* W1b = Wob + 16384;
  ushort* W2b = W1b + 65536;
  ushort* h1  = qb;                                // n*512 bf16, aliases qb..sbuf

  (void)hipMemsetAsync(cntR, 0, 2*n*sizeof(int), stream);

  // weight conversion (independent)
  CvtArgs ca;
  ca.s[0]=Wq; ca.s[1]=Wk; ca.s[2]=Wv; ca.s[3]=Wo; ca.s[4]=W1; ca.s[5]=W2;
  ca.d[0]=Wqb; ca.d[1]=Wkb; ca.d[2]=Wvb; ca.d[3]=Wob; ca.d[4]=W1b; ca.d[5]=W2b;
  ca.cnt[0]=ca.cnt[1]=ca.cnt[2]=ca.cnt[3]=16384; ca.cnt[4]=ca.cnt[5]=65536;
  cvt6_kernel<<<dim3(65536/256, 6), 256, 0, stream>>>(ca);

  // CSR builds
  int ebE = (E + 255)/256;
  int nb = (n + 1023)/1024;
  hist2_kernel<<<ebE, 256, 0, stream>>>(ei, cntR, cntC, E);
  scan_reduce <<<dim3(nb,2), 256, 0, stream>>>(cntR, partial, n, nb);
  scan_mid    <<<dim3(1,2),  256, 0, stream>>>(partial, nb, rptr, cptr, n);
  scan_scatter<<<dim3(nb,2), 256, 0, stream>>>(cntR, partial, rptr, cptr, curR, curC, n, nb);
  fill_r_kernel<<<ebE, 256, 0, stream>>>(ei, curR, rcol, pose, E);
  fill_c_kernel<<<ebE, 256, 0, stream>>>(ei, curC, pose, crow, cposr, E);

  // LN1 -> bf16
  ln_kernel<<<(n+3)/4, 256, 0, stream>>>(feats, ln1w, ln1b, x2b, n);

  // fused QKV projections (LDS-staged bf16 MFMA, bf16 out)
  int gm = (n + 63)/64;
  qkv_lds<<<dim3(gm,3), 256, 0, stream>>>(x2b, Wqb, bq, bk, bv, qb, kb, vb, n);

  // fused segmented softmax (online m,d), alpha scattered to col-CSR order
  row_softmax_kernel<<<(n+3)/4, 256, 0, stream>>>(qb, kb, rptr, rcol, cposr, sbuf, cbuf, n);

  // gather aggregation (streamed alpha, 2 edges in flight) -> bf16
  agg_kernel<<<(n+3)/4, 256, 0, stream>>>(vb, cbuf, cptr, crow, aggb, n);

  // attention out projection + residual -> d_out (f32)
  gemm_lds<128,0,1,0><<<dim3(gm,1), 256, 0, stream>>>(aggb, Wob, bo, feats, outp, n, 128);

  // LN2 -> bf16
  ln_kernel<<<(n+3)/4, 256, 0, stream>>>(outp, ln2w, ln2b, x2b, n);

  // FFN
  gemm_lds<128,1,0,1><<<dim3(gm,4), 256, 0, stream>>>(x2b, W1b, b1, nullptr, h1,  n, 512);
  gemm_lds<512,1,1,0><<<dim3(gm,1), 256, 0, stream>>>(h1,  W2b, b2, outp,    outp, n, 128);
}

// Round 10
// 374.715 us; speedup vs baseline: 2.1056x; 1.0915x over previous
//
#include <hip/hip_runtime.h>
#include <hip/hip_bf16.h>
#include <math.h>

#define H_HEADS 8
constexpr float LN_EPS = 1e-5f;
constexpr int NBCH = 64;          // CSR build chunks (chunk <= 65535 for u16 counters)

using short8 = __attribute__((ext_vector_type(8))) short;
using f32x4  = __attribute__((ext_vector_type(4))) float;

__device__ __forceinline__ ushort f2bf(float v){
  __hip_bfloat16 h = __float2bfloat16(v);
  return *reinterpret_cast<ushort*>(&h);
}
__device__ __forceinline__ float bf2f(ushort u){
  return __uint_as_float(((unsigned)u) << 16);
}

// async global->LDS, 16B per lane; dest = wave-uniform base + lane*16
__device__ __forceinline__ void stage16(const ushort* g, ushort* l){
  __builtin_amdgcn_global_load_lds((const __attribute__((address_space(1))) unsigned*)g,
                                   (__attribute__((address_space(3))) unsigned*)l,
                                   16, 0, 0);
}

// ---------- LayerNorm (ddof=1), f32 in -> bf16 out, one wave per row ----------
__global__ void ln_kernel(const float* __restrict__ x, const float* __restrict__ w,
                          const float* __restrict__ b, ushort* __restrict__ out, int nrows){
  int wid = threadIdx.x >> 6, lane = threadIdx.x & 63;
  int r = blockIdx.x * (blockDim.x >> 6) + wid;
  if (r >= nrows) return;
  float2 v = ((const float2*)(x + (size_t)r*128))[lane];
  float s = v.x + v.y;
  #pragma unroll
  for (int o = 32; o; o >>= 1) s += __shfl_xor(s, o);
  float mu = s * (1.0f/128.0f);
  float d0 = v.x - mu, d1 = v.y - mu;
  float ss = d0*d0 + d1*d1;
  #pragma unroll
  for (int o = 32; o; o >>= 1) ss += __shfl_xor(ss, o);
  float sd = sqrtf(ss * (1.0f/127.0f));
  float inv = 1.0f / (sd + LN_EPS);
  float2 wv = ((const float2*)w)[lane];
  float2 bv = ((const float2*)b)[lane];
  ushort2 o2 = { f2bf(d0*inv*wv.x + bv.x), f2bf(d1*inv*wv.y + bv.y) };
  ((ushort2*)(out + (size_t)r*128))[lane] = o2;
}

// ---------- weight f32 -> bf16 conversion (all 6 in one launch) ----------
struct CvtArgs { const float* s[6]; ushort* d[6]; int cnt[6]; };
__global__ void cvt6_kernel(CvtArgs a){
  int w = blockIdx.y;
  int i = blockIdx.x*blockDim.x + threadIdx.x;
  if (i < a.cnt[w]) a.d[w][i] = f2bf(a.s[w][i]);
}

// ---------- LDS-staged bf16 MFMA GEMM ----------
template<int K, int RELU, int RESID, int OUT_BF16>
__device__ __forceinline__ void gemm_lds_body(
    const ushort* __restrict__ A, const ushort* __restrict__ W,
    const float* __restrict__ bias, const float* __restrict__ resid,
    void* __restrict__ out, int M, int Nout, int cb, ushort* Wl){
  constexpr int NCH = K / 128;
  int t = threadIdx.x;
  int wid = t >> 6, lane = t & 63;
  int mb = blockIdx.x * 64 + wid * 16;
  int lrow = lane & 15, kgrp = lane >> 4;
  int row = mb + lrow;
  bool rowok = row < M;
  const ushort* arow = A + (size_t)(rowok ? row : (M-1)) * K + kgrp*8;

  f32x4 acc[8] = {};
  short8 af[2][4];

  #pragma unroll
  for (int p = 0; p < 8; ++p){
    int L = p*256 + t;
    int colp = L >> 4, sp = L & 15;
    stage16(W + (size_t)colp*K + ((sp ^ (colp & 7)) << 3),
            (ushort*)((char*)Wl + ((size_t)(p*256 + (t & ~63)))*16));
  }
  #pragma unroll
  for (int kk = 0; kk < 4; ++kk)
    af[0][kk] = *(const short8*)(arow + kk*32);

  #pragma unroll
  for (int ci = 0; ci < NCH; ++ci){
    __syncthreads();
    int cur = ci & 1;
    if (ci + 1 < NCH){
      #pragma unroll
      for (int kk = 0; kk < 4; ++kk)
        af[cur^1][kk] = *(const short8*)(arow + (ci+1)*128 + kk*32);
    }
    #pragma unroll
    for (int kk = 0; kk < 4; ++kk){
      #pragma unroll
      for (int nt = 0; nt < 8; ++nt){
        int colc = nt*16 + lrow;
        int g = kk*4 + kgrp;
        short8 bfv = *(const short8*)((const char*)Wl + colc*256 + ((g ^ (colc & 7))*16));
        acc[nt] = __builtin_amdgcn_mfma_f32_16x16x32_bf16(af[cur][kk], bfv, acc[nt], 0, 0, 0);
      }
    }
    if (ci + 1 < NCH){
      __syncthreads();
      const ushort* Wc = W + (ci+1)*128;
      #pragma unroll
      for (int p = 0; p < 8; ++p){
        int L = p*256 + t;
        int colp = L >> 4, sp = L & 15;
        stage16(Wc + (size_t)colp*K + ((sp ^ (colp & 7)) << 3),
                (ushort*)((char*)Wl + ((size_t)(p*256 + (t & ~63)))*16));
      }
    }
  }

  int r0 = mb + kgrp*4;
  #pragma unroll
  for (int nt = 0; nt < 8; ++nt){
    int c = cb + nt*16 + lrow;
    float bsum = bias[c];
    #pragma unroll
    for (int i = 0; i < 4; ++i){
      int r = r0 + i;
      if (r >= M) continue;
      float v = acc[nt][i] + bsum;
      if (RELU)  v = fmaxf(v, 0.0f);
      if (RESID) v += resid[(size_t)r*Nout + c];
      if (OUT_BF16) ((ushort*)out)[(size_t)r*Nout + c] = f2bf(v);
      else          ((float*)out)[(size_t)r*Nout + c] = v;
    }
  }
}

template<int K, int RELU, int RESID, int OUT_BF16>
__global__ __launch_bounds__(256) void gemm_lds(
    const ushort* __restrict__ A, const ushort* __restrict__ Wfull,
    const float* __restrict__ bias, const float* __restrict__ resid,
    void* __restrict__ out, int M, int Nout){
  __shared__ __align__(16) ushort Wl[16384];
  int cb = blockIdx.y * 128;
  gemm_lds_body<K,RELU,RESID,OUT_BF16>(A, Wfull + (size_t)cb*K, bias, resid, out, M, Nout, cb, Wl);
}

__global__ __launch_bounds__(256) void qkv_lds(
    const ushort* __restrict__ A, const ushort* __restrict__ Wcat,
    const float* __restrict__ bq, const float* __restrict__ bk, const float* __restrict__ bv,
    ushort* __restrict__ qb, ushort* __restrict__ kb, ushort* __restrict__ vb, int M){
  __shared__ __align__(16) ushort Wl[16384];
  int y = blockIdx.y;
  const float* bias = (y==0) ? bq : (y==1) ? bk : bv;
  ushort* out = (y==0) ? qb : (y==1) ? kb : vb;
  gemm_lds_body<128,0,0,1>(A, Wcat + (size_t)y*16384, bias, nullptr, out, M, 128, 0, Wl);
}

// ---------- CSR build, atomic-free (chunked LDS histograms, counting sort) ----------
// packed u16 LDS histogram over all bins (needs n <= 50176: 100KB LDS)
__global__ __launch_bounds__(256) void hist_lds(const int* __restrict__ ei,
    unsigned* __restrict__ copies, int E, int nw, int chunk){
  __shared__ unsigned hh[25088];
  int y = blockIdx.y, b = blockIdx.x, t = threadIdx.x;
  for (int i = t; i < nw; i += 256) hh[i] = 0;
  __syncthreads();
  int lo = b*chunk, hi = min(lo + chunk, E);
  for (int e = lo + t; e < hi; e += 256){
    int2 rc = ((const int2*)ei)[e];
    int bin = y ? rc.y : rc.x;
    atomicAdd(&hh[bin>>1], 1u << ((bin & 1)*16));
  }
  __syncthreads();
  unsigned* dst = copies + ((size_t)y*NBCH + b)*nw;
  for (int i = t; i < nw; i += 256) dst[i] = hh[i];
}

// fold copies: cnt[y][bin] total + per-chunk exclusive offsets choff[y][b][bin]
__global__ __launch_bounds__(256) void scan_fold(const unsigned* __restrict__ copies,
    int* __restrict__ cnt2, int* __restrict__ choff, int n, int nw){
  int y = blockIdx.y;
  int bin = blockIdx.x*256 + threadIdx.x;
  if (bin >= n) return;
  const unsigned* cp = copies + (size_t)y*NBCH*nw + (bin >> 1);
  int sh = (bin & 1)*16;
  int run = 0;
  for (int b = 0; b < NBCH; ++b){
    int c = (int)((cp[(size_t)b*nw] >> sh) & 0xffffu);
    choff[((size_t)y*NBCH + b)*n + bin] = run;
    run += c;
  }
  cnt2[(size_t)y*n + bin] = run;
}

// ---------- parallel 3-phase exclusive scan over cnt2 (both arrays, gridDim.y=2) ----------
__global__ __launch_bounds__(256) void scan_reduce(const int* __restrict__ cnt0,
                                                   int* __restrict__ partial, int n, int nb){
  const int* cnt = cnt0 + (size_t)blockIdx.y * n;
  int t = threadIdx.x;
  int base = blockIdx.x*1024 + t*4;
  int s = 0;
  #pragma unroll
  for (int j = 0; j < 4; ++j){ int i = base+j; if (i < n) s += cnt[i]; }
  __shared__ int sm[256];
  sm[t] = s; __syncthreads();
  for (int off = 128; off; off >>= 1){
    if (t < off) sm[t] += sm[t+off];
    __syncthreads();
  }
  if (t == 0) partial[blockIdx.y*nb + blockIdx.x] = sm[0];
}

__global__ __launch_bounds__(256) void scan_mid(int* __restrict__ partial, int nb,
                                                int* __restrict__ rptr, int* __restrict__ cptr, int n){
  int y = blockIdx.y;
  int* p = partial + y*nb;
  int t = threadIdx.x;
  __shared__ int sm[256];
  sm[t] = (t < nb) ? p[t] : 0;
  __syncthreads();
  for (int off = 1; off < 256; off <<= 1){
    int v = (t >= off) ? sm[t-off] : 0;
    __syncthreads();
    sm[t] += v;
    __syncthreads();
  }
  if (t < nb) p[t] = (t == 0) ? 0 : sm[t-1];
  if (t == 0) (y ? cptr : rptr)[n] = sm[255];
}

__global__ __launch_bounds__(256) void scan_scatter(const int* __restrict__ cnt0,
                                                    const int* __restrict__ partial,
                                                    int* __restrict__ rptr, int* __restrict__ cptr,
                                                    int n, int nb){
  int y = blockIdx.y;
  const int* cnt = cnt0 + (size_t)y * n;
  int* ptr = y ? cptr : rptr;
  int t = threadIdx.x;
  int base = blockIdx.x*1024 + t*4;
  int v[4]; int s = 0;
  #pragma unroll
  for (int j = 0; j < 4; ++j){ int i = base+j; v[j] = (i<n)?cnt[i]:0; s += v[j]; }
  __shared__ int sm[256];
  sm[t] = s; __syncthreads();
  for (int off = 1; off < 256; off <<= 1){
    int x = (t >= off) ? sm[t-off] : 0;
    __syncthreads();
    sm[t] += x;
    __syncthreads();
  }
  int pre = partial[y*nb + blockIdx.x] + ((t==0)?0:sm[t-1]);
  #pragma unroll
  for (int j = 0; j < 4; ++j){
    int i = base+j;
    if (i < n){ ptr[i] = pre; pre += v[j]; }
  }
}

// fill via in-chunk LDS rank (returning packed-u16 LDS atomic), no global atomics
__global__ __launch_bounds__(256) void fill_r_lds(const int* __restrict__ ei,
    const int* __restrict__ rptr, const int* __restrict__ choffR,
    int* __restrict__ rcol, int* __restrict__ pose, int E, int n, int nw, int chunk){
  __shared__ unsigned hh[25088];
  int b = blockIdx.x, t = threadIdx.x;
  for (int i = t; i < nw; i += 256) hh[i] = 0;
  __syncthreads();
  const int* chb = choffR + (size_t)b*n;
  int lo = b*chunk, hi = min(lo + chunk, E);
  for (int e = lo + t; e < hi; e += 256){
    int2 rc = ((const int2*)ei)[e];
    int bin = rc.x, sh = (bin & 1)*16;
    unsigned old = atomicAdd(&hh[bin>>1], 1u << sh);
    int rank = (int)((old >> sh) & 0xffffu);
    int pos = rptr[bin] + chb[bin] + rank;
    rcol[pos] = rc.y;
    pose[e] = pos;
  }
}

__global__ __launch_bounds__(256) void fill_c_lds(const int* __restrict__ ei,
    const int* __restrict__ cptr, const int* __restrict__ choffC,
    const int* __restrict__ pose, int* __restrict__ crow, int* __restrict__ cposr,
    int E, int n, int nw, int chunk){
  __shared__ unsigned hh[25088];
  int b = blockIdx.x, t = threadIdx.x;
  for (int i = t; i < nw; i += 256) hh[i] = 0;
  __syncthreads();
  const int* chb = choffC + (size_t)b*n;
  int lo = b*chunk, hi = min(lo + chunk, E);
  for (int e = lo + t; e < hi; e += 256){
    int2 rc = ((const int2*)ei)[e];
    int bin = rc.y, sh = (bin & 1)*16;
    unsigned old = atomicAdd(&hh[bin>>1], 1u << sh);
    int rank = (int)((old >> sh) & 0xffffu);
    int pos = cptr[bin] + chb[bin] + rank;
    crow[pos] = rc.x;
    cposr[pose[e]] = pos;
  }
}

// ---------- fused segmented softmax over row-CSR (online m,d; alpha -> col-CSR order) ----------
__global__ void row_softmax_kernel(const ushort* __restrict__ qb, const ushort* __restrict__ kb,
                                   const int* __restrict__ rptr, const int* __restrict__ rcol,
                                   const int* __restrict__ cposr,
                                   float* __restrict__ sbuf, float* __restrict__ cbuf, int n){
  int wid = threadIdx.x >> 6, lane = threadIdx.x & 63;
  int r = blockIdx.x * (blockDim.x >> 6) + wid;
  if (r >= n) return;
  int lo = rptr[r], hi = rptr[r+1];
  if (lo >= hi) return;
  int h = lane & 7, el = lane >> 3;

  float kf[16];
  {
    const short8* kp = (const short8*)(kb + (size_t)r*128 + h*16);
    short8 k0 = kp[0], k1 = kp[1];
    #pragma unroll
    for (int i = 0; i < 8; ++i){
      kf[i]   = bf2f((ushort)k0[i]);
      kf[8+i] = bf2f((ushort)k1[i]);
    }
  }

  float m = -1e30f, d = 0.f;
  for (int j = lo + el; j < hi; j += 8){
    int c = rcol[j];
    const short8* qp = (const short8*)(qb + (size_t)c*128 + h*16);
    short8 q0 = qp[0], q1 = qp[1];
    float s = 0.f;
    #pragma unroll
    for (int i = 0; i < 8; ++i){
      s += bf2f((ushort)q0[i]) * kf[i];
      s += bf2f((ushort)q1[i]) * kf[8+i];
    }
    s *= 0.25f;
    sbuf[(size_t)j*8 + h] = s;
    float nm = fmaxf(m, s);
    d = d*__expf(m - nm) + __expf(s - nm);
    m = nm;
  }
  #pragma unroll
  for (int o = 8; o < 64; o <<= 1){
    float om = __shfl_xor(m, o);
    float od = __shfl_xor(d, o);
    float nm = fmaxf(m, om);
    d = d*__expf(m - nm) + od*__expf(om - nm);
    m = nm;
  }
  float invd = 1.0f / d;

  for (int j = lo + el; j < hi; j += 8){
    float s = sbuf[(size_t)j*8 + h];
    float a = __expf(s - m) * invd;
    cbuf[(size_t)cposr[j]*8 + h] = a;     // scatter to col-CSR order
  }
}

// ---------- gather aggregation over col-CSR -> bf16 agg ----------
__global__ void agg_kernel(const ushort* __restrict__ vb, const float* __restrict__ cbuf,
                           const int* __restrict__ cptr, const int* __restrict__ crow,
                           ushort* __restrict__ aggb, int n){
  int wid = threadIdx.x >> 6, lane = threadIdx.x & 63;
  int node = blockIdx.x * (blockDim.x >> 6) + wid;
  if (node >= n) return;
  int lo = cptr[node], hi = cptr[node+1];
  int half = lane >> 5, l32 = lane & 31;
  int h = l32 >> 2;
  float4 acc = {0.f, 0.f, 0.f, 0.f};
  for (int j = lo + half; j < hi; j += 2){
    float a = cbuf[(size_t)j*8 + h];
    int row = crow[j];
    ushort4 vv = *(const ushort4*)(vb + (size_t)row*128 + l32*4);
    acc.x = fmaf(a, bf2f(vv.x), acc.x);
    acc.y = fmaf(a, bf2f(vv.y), acc.y);
    acc.z = fmaf(a, bf2f(vv.z), acc.z);
    acc.w = fmaf(a, bf2f(vv.w), acc.w);
  }
  acc.x += __shfl_xor(acc.x, 32);
  acc.y += __shfl_xor(acc.y, 32);
  acc.z += __shfl_xor(acc.z, 32);
  acc.w += __shfl_xor(acc.w, 32);
  if (half == 0){
    ushort4 o = { f2bf(acc.x), f2bf(acc.y), f2bf(acc.z), f2bf(acc.w) };
    *(ushort4*)(aggb + (size_t)node*128 + l32*4) = o;
  }
}

extern "C" void kernel_launch(void* const* d_in, const int* in_sizes, int n_in,
                              void* d_out, int out_size, void* d_ws, size_t ws_size,
                              hipStream_t stream){
  const float* feats = (const float*)d_in[0];
  const int*   ei    = (const int*)  d_in[1];
  const float* Wq = (const float*)d_in[2];
  const float* bq = (const float*)d_in[3];
  const float* Wk = (const float*)d_in[4];
  const float* bk = (const float*)d_in[5];
  const float* Wv = (const float*)d_in[6];
  const float* bv = (const float*)d_in[7];
  const float* Wo = (const float*)d_in[8];
  const float* bo = (const float*)d_in[9];
  const float* ln1w = (const float*)d_in[10];
  const float* ln1b = (const float*)d_in[11];
  const float* ln2w = (const float*)d_in[12];
  const float* ln2b = (const float*)d_in[13];
  const float* W1 = (const float*)d_in[14];
  const float* b1 = (const float*)d_in[15];
  const float* W2 = (const float*)d_in[16];
  const float* b2 = (const float*)d_in[17];
  float* outp = (float*)d_out;

  int n = in_sizes[0] / 128;      // 50000 nodes
  int E = in_sizes[1] / 2;        // 800000 edges
  int nw = (n + 1) >> 1;          // packed u16 words per histogram
  int chunk = (E + NBCH - 1) / NBCH;

  const size_t ND  = (size_t)n * 128;
  const size_t ND2 = ND / 2;
  const size_t EH  = (size_t)E * H_HEADS;

  float* ws = (float*)d_ws;
  ushort* x2b  = (ushort*)ws;                      // ND bf16
  ushort* qb   = (ushort*)(ws + ND2);
  ushort* kb   = (ushort*)(ws + 2*ND2);
  ushort* vb   = (ushort*)(ws + 3*ND2);
  float*  sbuf = ws + 4*ND2;                       // EH f32 (scores, row order)
  float*  cbuf = ws + 4*ND2 + EH;                  // EH f32 (alpha, col order)
  ushort* aggb = (ushort*)(ws + 4*ND2 + 2*EH);     // ND bf16
  int* crow    = (int*)(ws + 5*ND2 + 2*EH);
  int* cposr   = crow + E;
  int* rcol    = cposr + E;
  int* pose    = rcol + E;
  int* rptr    = pose + E;
  int* cptr    = rptr + (n + 4);
  int* cnt2    = cptr + (n + 4);                   // [2][n]
  int* choff   = cnt2 + 2*n;                       // [2][NBCH][n]
  unsigned* copies = (unsigned*)(choff + (size_t)2*NBCH*n);  // [2][NBCH][nw]
  int* partial = (int*)(copies + (size_t)2*NBCH*nw);         // 2*nb ints
  ushort* wbuf = (ushort*)(partial + 512);
  ushort* Wqb = wbuf;                              // Wq,Wk,Wv contiguous for qkv
  ushort* Wkb = Wqb + 16384;
  ushort* Wvb = Wkb + 16384;
  ushort* Wob = Wvb + 16384;
  ushort* W1b = Wob + 16384;
  ushort* W2b = W1b + 65536;
  ushort* h1  = qb;                                // n*512 bf16, aliases qb..sbuf

  // weight conversion (independent)
  CvtArgs ca;
  ca.s[0]=Wq; ca.s[1]=Wk; ca.s[2]=Wv; ca.s[3]=Wo; ca.s[4]=W1; ca.s[5]=W2;
  ca.d[0]=Wqb; ca.d[1]=Wkb; ca.d[2]=Wvb; ca.d[3]=Wob; ca.d[4]=W1b; ca.d[5]=W2b;
  ca.cnt[0]=ca.cnt[1]=ca.cnt[2]=ca.cnt[3]=16384; ca.cnt[4]=ca.cnt[5]=65536;
  cvt6_kernel<<<dim3(65536/256, 6), 256, 0, stream>>>(ca);

  // atomic-free CSR build
  int nb = (n + 1023)/1024;
  hist_lds  <<<dim3(NBCH,2), 256, 0, stream>>>(ei, copies, E, nw, chunk);
  scan_fold <<<dim3((n+255)/256,2), 256, 0, stream>>>(copies, cnt2, choff, n, nw);
  scan_reduce <<<dim3(nb,2), 256, 0, stream>>>(cnt2, partial, n, nb);
  scan_mid    <<<dim3(1,2),  256, 0, stream>>>(partial, nb, rptr, cptr, n);
  scan_scatter<<<dim3(nb,2), 256, 0, stream>>>(cnt2, partial, rptr, cptr, n, nb);
  fill_r_lds<<<NBCH, 256, 0, stream>>>(ei, rptr, choff,                 rcol, pose, E, n, nw, chunk);
  fill_c_lds<<<NBCH, 256, 0, stream>>>(ei, cptr, choff + (size_t)NBCH*n, pose, crow, cposr, E, n, nw, chunk);

  // LN1 -> bf16
  ln_kernel<<<(n+3)/4, 256, 0, stream>>>(feats, ln1w, ln1b, x2b, n);

  // fused QKV projections (LDS-staged bf16 MFMA, bf16 out)
  int gm = (n + 63)/64;
  qkv_lds<<<dim3(gm,3), 256, 0, stream>>>(x2b, Wqb, bq, bk, bv, qb, kb, vb, n);

  // fused segmented softmax (online m,d), alpha scattered to col-CSR order
  row_softmax_kernel<<<(n+3)/4, 256, 0, stream>>>(qb, kb, rptr, rcol, cposr, sbuf, cbuf, n);

  // gather aggregation (streamed alpha, 2 edges in flight) -> bf16
  agg_kernel<<<(n+3)/4, 256, 0, stream>>>(vb, cbuf, cptr, crow, aggb, n);

  // attention out projection + residual -> d_out (f32)
  gemm_lds<128,0,1,0><<<dim3(gm,1), 256, 0, stream>>>(aggb, Wob, bo, feats, outp, n, 128);

  // LN2 -> bf16
  ln_kernel<<<(n+3)/4, 256, 0, stream>>>(outp, ln2w, ln2b, x2b, n);

  // FFN
  gemm_lds<128,1,0,1><<<dim3(gm,4), 256, 0, stream>>>(x2b, W1b, b1, nullptr, h1,  n, 512);
  gemm_lds<512,1,1,0><<<dim3(gm,1), 256, 0, stream>>>(h1,  W2b, b2, outp,    outp, n, 128);
}

// Round 11
// 336.497 us; speedup vs baseline: 2.3447x; 1.1136x over previous
//
#include <hip/hip_runtime.h>
#include <hip/hip_bf16.h>
#include <math.h>

#define H_HEADS 8
constexpr float LN_EPS = 1e-5f;
constexpr int NBCH = 64;          // CSR build chunks (chunk <= 65535 for u16 counters)
constexpr int NSEG = 4;           // bin segments per chunk (LDS = ~n/NSEG/2 words)

using short8 = __attribute__((ext_vector_type(8))) short;
using f32x4  = __attribute__((ext_vector_type(4))) float;

__device__ __forceinline__ ushort f2bf(float v){
  __hip_bfloat16 h = __float2bfloat16(v);
  return *reinterpret_cast<ushort*>(&h);
}
__device__ __forceinline__ float bf2f(ushort u){
  return __uint_as_float(((unsigned)u) << 16);
}

// async global->LDS, 16B per lane; dest = wave-uniform base + lane*16
__device__ __forceinline__ void stage16(const ushort* g, ushort* l){
  __builtin_amdgcn_global_load_lds((const __attribute__((address_space(1))) unsigned*)g,
                                   (__attribute__((address_space(3))) unsigned*)l,
                                   16, 0, 0);
}

// ---------- LayerNorm (ddof=1), f32 in -> bf16 out, one wave per row ----------
__global__ void ln_kernel(const float* __restrict__ x, const float* __restrict__ w,
                          const float* __restrict__ b, ushort* __restrict__ out, int nrows){
  int wid = threadIdx.x >> 6, lane = threadIdx.x & 63;
  int r = blockIdx.x * (blockDim.x >> 6) + wid;
  if (r >= nrows) return;
  float2 v = ((const float2*)(x + (size_t)r*128))[lane];
  float s = v.x + v.y;
  #pragma unroll
  for (int o = 32; o; o >>= 1) s += __shfl_xor(s, o);
  float mu = s * (1.0f/128.0f);
  float d0 = v.x - mu, d1 = v.y - mu;
  float ss = d0*d0 + d1*d1;
  #pragma unroll
  for (int o = 32; o; o >>= 1) ss += __shfl_xor(ss, o);
  float sd = sqrtf(ss * (1.0f/127.0f));
  float inv = 1.0f / (sd + LN_EPS);
  float2 wv = ((const float2*)w)[lane];
  float2 bv = ((const float2*)b)[lane];
  ushort2 o2 = { f2bf(d0*inv*wv.x + bv.x), f2bf(d1*inv*wv.y + bv.y) };
  ((ushort2*)(out + (size_t)r*128))[lane] = o2;
}

// ---------- weight f32 -> bf16 conversion (all 6 in one launch) ----------
struct CvtArgs { const float* s[6]; ushort* d[6]; int cnt[6]; };
__global__ void cvt6_kernel(CvtArgs a){
  int w = blockIdx.y;
  int i = blockIdx.x*blockDim.x + threadIdx.x;
  if (i < a.cnt[w]) a.d[w][i] = f2bf(a.s[w][i]);
}

// ---------- LDS-staged bf16 MFMA GEMM ----------
template<int K, int RELU, int RESID, int OUT_BF16>
__device__ __forceinline__ void gemm_lds_body(
    const ushort* __restrict__ A, const ushort* __restrict__ W,
    const float* __restrict__ bias, const float* __restrict__ resid,
    void* __restrict__ out, int M, int Nout, int cb, ushort* Wl){
  constexpr int NCH = K / 128;
  int t = threadIdx.x;
  int wid = t >> 6, lane = t & 63;
  int mb = blockIdx.x * 64 + wid * 16;
  int lrow = lane & 15, kgrp = lane >> 4;
  int row = mb + lrow;
  bool rowok = row < M;
  const ushort* arow = A + (size_t)(rowok ? row : (M-1)) * K + kgrp*8;

  f32x4 acc[8] = {};
  short8 af[2][4];

  #pragma unroll
  for (int p = 0; p < 8; ++p){
    int L = p*256 + t;
    int colp = L >> 4, sp = L & 15;
    stage16(W + (size_t)colp*K + ((sp ^ (colp & 7)) << 3),
            (ushort*)((char*)Wl + ((size_t)(p*256 + (t & ~63)))*16));
  }
  #pragma unroll
  for (int kk = 0; kk < 4; ++kk)
    af[0][kk] = *(const short8*)(arow + kk*32);

  #pragma unroll
  for (int ci = 0; ci < NCH; ++ci){
    __syncthreads();
    int cur = ci & 1;
    if (ci + 1 < NCH){
      #pragma unroll
      for (int kk = 0; kk < 4; ++kk)
        af[cur^1][kk] = *(const short8*)(arow + (ci+1)*128 + kk*32);
    }
    #pragma unroll
    for (int kk = 0; kk < 4; ++kk){
      #pragma unroll
      for (int nt = 0; nt < 8; ++nt){
        int colc = nt*16 + lrow;
        int g = kk*4 + kgrp;
        short8 bfv = *(const short8*)((const char*)Wl + colc*256 + ((g ^ (colc & 7))*16));
        acc[nt] = __builtin_amdgcn_mfma_f32_16x16x32_bf16(af[cur][kk], bfv, acc[nt], 0, 0, 0);
      }
    }
    if (ci + 1 < NCH){
      __syncthreads();
      const ushort* Wc = W + (ci+1)*128;
      #pragma unroll
      for (int p = 0; p < 8; ++p){
        int L = p*256 + t;
        int colp = L >> 4, sp = L & 15;
        stage16(Wc + (size_t)colp*K + ((sp ^ (colp & 7)) << 3),
                (ushort*)((char*)Wl + ((size_t)(p*256 + (t & ~63)))*16));
      }
    }
  }

  int r0 = mb + kgrp*4;
  #pragma unroll
  for (int nt = 0; nt < 8; ++nt){
    int c = cb + nt*16 + lrow;
    float bsum = bias[c];
    #pragma unroll
    for (int i = 0; i < 4; ++i){
      int r = r0 + i;
      if (r >= M) continue;
      float v = acc[nt][i] + bsum;
      if (RELU)  v = fmaxf(v, 0.0f);
      if (RESID) v += resid[(size_t)r*Nout + c];
      if (OUT_BF16) ((ushort*)out)[(size_t)r*Nout + c] = f2bf(v);
      else          ((float*)out)[(size_t)r*Nout + c] = v;
    }
  }
}

template<int K, int RELU, int RESID, int OUT_BF16>
__global__ __launch_bounds__(256) void gemm_lds(
    const ushort* __restrict__ A, const ushort* __restrict__ Wfull,
    const float* __restrict__ bias, const float* __restrict__ resid,
    void* __restrict__ out, int M, int Nout){
  __shared__ __align__(16) ushort Wl[16384];
  int cb = blockIdx.y * 128;
  gemm_lds_body<K,RELU,RESID,OUT_BF16>(A, Wfull + (size_t)cb*K, bias, resid, out, M, Nout, cb, Wl);
}

__global__ __launch_bounds__(256) void qkv_lds(
    const ushort* __restrict__ A, const ushort* __restrict__ Wcat,
    const float* __restrict__ bq, const float* __restrict__ bk, const float* __restrict__ bv,
    ushort* __restrict__ qb, ushort* __restrict__ kb, ushort* __restrict__ vb, int M){
  __shared__ __align__(16) ushort Wl[16384];
  int y = blockIdx.y;
  const float* bias = (y==0) ? bq : (y==1) ? bk : bv;
  ushort* out = (y==0) ? qb : (y==1) ? kb : vb;
  gemm_lds_body<128,0,0,1>(A, Wcat + (size_t)y*16384, bias, nullptr, out, M, 128, 0, Wl);
}

// ---------- CSR build, atomic-free, bin-segmented (chunk x segment grid) ----------
// packed u16 LDS histogram over ONE bin segment (~n/NSEG bins, <=32KB LDS)
// block (b, s, y): chunk b, segment s, y = 0:row / 1:col
__global__ __launch_bounds__(256) void hist_seg(const int* __restrict__ ei,
    unsigned* __restrict__ copies, int E, int n, int nw, int chunk, int nsb){
  __shared__ unsigned hh[8192];
  int b = blockIdx.x, s = blockIdx.y, y = blockIdx.z, t = threadIdx.x;
  int bin0 = s * nsb;
  int bin1 = min(bin0 + nsb, n);
  int words = (bin1 - bin0 + 1) >> 1;
  for (int i = t; i < words; i += 256) hh[i] = 0;
  __syncthreads();
  int lo = b*chunk, hi = min(lo + chunk, E);
  for (int e = lo + t; e < hi; e += 256){
    int2 rc = ((const int2*)ei)[e];
    int bin = y ? rc.y : rc.x;
    if (bin >= bin0 && bin < bin1)
      atomicAdd(&hh[(bin - bin0) >> 1], 1u << ((bin & 1)*16));
  }
  __syncthreads();
  unsigned* dst = copies + ((size_t)y*NBCH + b)*nw + (bin0 >> 1);
  for (int i = t; i < words; i += 256) dst[i] = hh[i];
}

// fold copies: cnt[y][bin] total + per-chunk exclusive offsets choff[y][b][bin]
__global__ __launch_bounds__(256) void scan_fold(const unsigned* __restrict__ copies,
    int* __restrict__ cnt2, int* __restrict__ choff, int n, int nw){
  int y = blockIdx.y;
  int bin = blockIdx.x*256 + threadIdx.x;
  if (bin >= n) return;
  const unsigned* cp = copies + (size_t)y*NBCH*nw + (bin >> 1);
  int sh = (bin & 1)*16;
  int run = 0;
  for (int b = 0; b < NBCH; ++b){
    int c = (int)((cp[(size_t)b*nw] >> sh) & 0xffffu);
    choff[((size_t)y*NBCH + b)*n + bin] = run;
    run += c;
  }
  cnt2[(size_t)y*n + bin] = run;
}

// ---------- parallel 3-phase exclusive scan over cnt2 (both arrays, gridDim.y=2) ----------
__global__ __launch_bounds__(256) void scan_reduce(const int* __restrict__ cnt0,
                                                   int* __restrict__ partial, int n, int nb){
  const int* cnt = cnt0 + (size_t)blockIdx.y * n;
  int t = threadIdx.x;
  int base = blockIdx.x*1024 + t*4;
  int s = 0;
  #pragma unroll
  for (int j = 0; j < 4; ++j){ int i = base+j; if (i < n) s += cnt[i]; }
  __shared__ int sm[256];
  sm[t] = s; __syncthreads();
  for (int off = 128; off; off >>= 1){
    if (t < off) sm[t] += sm[t+off];
    __syncthreads();
  }
  if (t == 0) partial[blockIdx.y*nb + blockIdx.x] = sm[0];
}

__global__ __launch_bounds__(256) void scan_mid(int* __restrict__ partial, int nb,
                                                int* __restrict__ rptr, int* __restrict__ cptr, int n){
  int y = blockIdx.y;
  int* p = partial + y*nb;
  int t = threadIdx.x;
  __shared__ int sm[256];
  sm[t] = (t < nb) ? p[t] : 0;
  __syncthreads();
  for (int off = 1; off < 256; off <<= 1){
    int v = (t >= off) ? sm[t-off] : 0;
    __syncthreads();
    sm[t] += v;
    __syncthreads();
  }
  if (t < nb) p[t] = (t == 0) ? 0 : sm[t-1];
  if (t == 0) (y ? cptr : rptr)[n] = sm[255];
}

__global__ __launch_bounds__(256) void scan_scatter(const int* __restrict__ cnt0,
                                                    const int* __restrict__ partial,
                                                    int* __restrict__ rptr, int* __restrict__ cptr,
                                                    int n, int nb){
  int y = blockIdx.y;
  const int* cnt = cnt0 + (size_t)y * n;
  int* ptr = y ? cptr : rptr;
  int t = threadIdx.x;
  int base = blockIdx.x*1024 + t*4;
  int v[4]; int s = 0;
  #pragma unroll
  for (int j = 0; j < 4; ++j){ int i = base+j; v[j] = (i<n)?cnt[i]:0; s += v[j]; }
  __shared__ int sm[256];
  sm[t] = s; __syncthreads();
  for (int off = 1; off < 256; off <<= 1){
    int x = (t >= off) ? sm[t-off] : 0;
    __syncthreads();
    sm[t] += x;
    __syncthreads();
  }
  int pre = partial[y*nb + blockIdx.x] + ((t==0)?0:sm[t-1]);
  #pragma unroll
  for (int j = 0; j < 4; ++j){
    int i = base+j;
    if (i < n){ ptr[i] = pre; pre += v[j]; }
  }
}

// fill via in-chunk LDS rank within bin segment; no global atomics
__global__ __launch_bounds__(256) void fill_r_seg(const int* __restrict__ ei,
    const int* __restrict__ rptr, const int* __restrict__ choffR,
    int* __restrict__ rcol, int* __restrict__ pose, int E, int n, int chunk, int nsb){
  __shared__ unsigned hh[8192];
  int b = blockIdx.x, s = blockIdx.y, t = threadIdx.x;
  int bin0 = s * nsb;
  int bin1 = min(bin0 + nsb, n);
  int words = (bin1 - bin0 + 1) >> 1;
  for (int i = t; i < words; i += 256) hh[i] = 0;
  __syncthreads();
  const int* chb = choffR + (size_t)b*n;
  int lo = b*chunk, hi = min(lo + chunk, E);
  for (int e = lo + t; e < hi; e += 256){
    int2 rc = ((const int2*)ei)[e];
    int bin = rc.x;
    if (bin < bin0 || bin >= bin1) continue;
    int sh = (bin & 1)*16;
    unsigned old = atomicAdd(&hh[(bin - bin0) >> 1], 1u << sh);
    int rank = (int)((old >> sh) & 0xffffu);
    int pos = rptr[bin] + chb[bin] + rank;
    rcol[pos] = rc.y;
    pose[e] = pos;
  }
}

__global__ __launch_bounds__(256) void fill_c_seg(const int* __restrict__ ei,
    const int* __restrict__ cptr, const int* __restrict__ choffC,
    const int* __restrict__ pose, int* __restrict__ crow, int* __restrict__ cposr,
    int E, int n, int chunk, int nsb){
  __shared__ unsigned hh[8192];
  int b = blockIdx.x, s = blockIdx.y, t = threadIdx.x;
  int bin0 = s * nsb;
  int bin1 = min(bin0 + nsb, n);
  int words = (bin1 - bin0 + 1) >> 1;
  for (int i = t; i < words; i += 256) hh[i] = 0;
  __syncthreads();
  const int* chb = choffC + (size_t)b*n;
  int lo = b*chunk, hi = min(lo + chunk, E);
  for (int e = lo + t; e < hi; e += 256){
    int2 rc = ((const int2*)ei)[e];
    int bin = rc.y;
    if (bin < bin0 || bin >= bin1) continue;
    int sh = (bin & 1)*16;
    unsigned old = atomicAdd(&hh[(bin - bin0) >> 1], 1u << sh);
    int rank = (int)((old >> sh) & 0xffffu);
    int pos = cptr[bin] + chb[bin] + rank;
    crow[pos] = rc.x;
    cposr[pose[e]] = pos;
  }
}

// ---------- fused segmented softmax over row-CSR (online m,d; alpha -> col-CSR order) ----------
__global__ void row_softmax_kernel(const ushort* __restrict__ qb, const ushort* __restrict__ kb,
                                   const int* __restrict__ rptr, const int* __restrict__ rcol,
                                   const int* __restrict__ cposr,
                                   float* __restrict__ sbuf, float* __restrict__ cbuf, int n){
  int wid = threadIdx.x >> 6, lane = threadIdx.x & 63;
  int r = blockIdx.x * (blockDim.x >> 6) + wid;
  if (r >= n) return;
  int lo = rptr[r], hi = rptr[r+1];
  if (lo >= hi) return;
  int h = lane & 7, el = lane >> 3;

  float kf[16];
  {
    const short8* kp = (const short8*)(kb + (size_t)r*128 + h*16);
    short8 k0 = kp[0], k1 = kp[1];
    #pragma unroll
    for (int i = 0; i < 8; ++i){
      kf[i]   = bf2f((ushort)k0[i]);
      kf[8+i] = bf2f((ushort)k1[i]);
    }
  }

  float m = -1e30f, d = 0.f;
  for (int j = lo + el; j < hi; j += 8){
    int c = rcol[j];
    const short8* qp = (const short8*)(qb + (size_t)c*128 + h*16);
    short8 q0 = qp[0], q1 = qp[1];
    float s = 0.f;
    #pragma unroll
    for (int i = 0; i < 8; ++i){
      s += bf2f((ushort)q0[i]) * kf[i];
      s += bf2f((ushort)q1[i]) * kf[8+i];
    }
    s *= 0.25f;
    sbuf[(size_t)j*8 + h] = s;
    float nm = fmaxf(m, s);
    d = d*__expf(m - nm) + __expf(s - nm);
    m = nm;
  }
  #pragma unroll
  for (int o = 8; o < 64; o <<= 1){
    float om = __shfl_xor(m, o);
    float od = __shfl_xor(d, o);
    float nm = fmaxf(m, om);
    d = d*__expf(m - nm) + od*__expf(om - nm);
    m = nm;
  }
  float invd = 1.0f / d;

  for (int j = lo + el; j < hi; j += 8){
    float s = sbuf[(size_t)j*8 + h];
    float a = __expf(s - m) * invd;
    cbuf[(size_t)cposr[j]*8 + h] = a;     // scatter to col-CSR order
  }
}

// ---------- gather aggregation over col-CSR -> bf16 agg ----------
__global__ void agg_kernel(const ushort* __restrict__ vb, const float* __restrict__ cbuf,
                           const int* __restrict__ cptr, const int* __restrict__ crow,
                           ushort* __restrict__ aggb, int n){
  int wid = threadIdx.x >> 6, lane = threadIdx.x & 63;
  int node = blockIdx.x * (blockDim.x >> 6) + wid;
  if (node >= n) return;
  int lo = cptr[node], hi = cptr[node+1];
  int half = lane >> 5, l32 = lane & 31;
  int h = l32 >> 2;
  float4 acc = {0.f, 0.f, 0.f, 0.f};
  for (int j = lo + half; j < hi; j += 2){
    float a = cbuf[(size_t)j*8 + h];
    int row = crow[j];
    ushort4 vv = *(const ushort4*)(vb + (size_t)row*128 + l32*4);
    acc.x = fmaf(a, bf2f(vv.x), acc.x);
    acc.y = fmaf(a, bf2f(vv.y), acc.y);
    acc.z = fmaf(a, bf2f(vv.z), acc.z);
    acc.w = fmaf(a, bf2f(vv.w), acc.w);
  }
  acc.x += __shfl_xor(acc.x, 32);
  acc.y += __shfl_xor(acc.y, 32);
  acc.z += __shfl_xor(acc.z, 32);
  acc.w += __shfl_xor(acc.w, 32);
  if (half == 0){
    ushort4 o = { f2bf(acc.x), f2bf(acc.y), f2bf(acc.z), f2bf(acc.w) };
    *(ushort4*)(aggb + (size_t)node*128 + l32*4) = o;
  }
}

extern "C" void kernel_launch(void* const* d_in, const int* in_sizes, int n_in,
                              void* d_out, int out_size, void* d_ws, size_t ws_size,
                              hipStream_t stream){
  const float* feats = (const float*)d_in[0];
  const int*   ei    = (const int*)  d_in[1];
  const float* Wq = (const float*)d_in[2];
  const float* bq = (const float*)d_in[3];
  const float* Wk = (const float*)d_in[4];
  const float* bk = (const float*)d_in[5];
  const float* Wv = (const float*)d_in[6];
  const float* bv = (const float*)d_in[7];
  const float* Wo = (const float*)d_in[8];
  const float* bo = (const float*)d_in[9];
  const float* ln1w = (const float*)d_in[10];
  const float* ln1b = (const float*)d_in[11];
  const float* ln2w = (const float*)d_in[12];
  const float* ln2b = (const float*)d_in[13];
  const float* W1 = (const float*)d_in[14];
  const float* b1 = (const float*)d_in[15];
  const float* W2 = (const float*)d_in[16];
  const float* b2 = (const float*)d_in[17];
  float* outp = (float*)d_out;

  int n = in_sizes[0] / 128;      // 50000 nodes
  int E = in_sizes[1] / 2;        // 800000 edges
  int nw = (n + 1) >> 1;          // packed u16 words per full histogram
  int chunk = (E + NBCH - 1) / NBCH;
  int nsb = (((n + NSEG - 1) / NSEG) + 1) & ~1;   // bins per segment (even)

  const size_t ND  = (size_t)n * 128;
  const size_t ND2 = ND / 2;
  const size_t EH  = (size_t)E * H_HEADS;

  float* ws = (float*)d_ws;
  ushort* x2b  = (ushort*)ws;                      // ND bf16
  ushort* qb   = (ushort*)(ws + ND2);
  ushort* kb   = (ushort*)(ws + 2*ND2);
  ushort* vb   = (ushort*)(ws + 3*ND2);
  float*  sbuf = ws + 4*ND2;                       // EH f32 (scores, row order)
  float*  cbuf = ws + 4*ND2 + EH;                  // EH f32 (alpha, col order)
  ushort* aggb = (ushort*)(ws + 4*ND2 + 2*EH);     // ND bf16
  int* crow    = (int*)(ws + 5*ND2 + 2*EH);
  int* cposr   = crow + E;
  int* rcol    = cposr + E;
  int* pose    = rcol + E;
  int* rptr    = pose + E;
  int* cptr    = rptr + (n + 4);
  int* cnt2    = cptr + (n + 4);                   // [2][n]
  int* choff   = cnt2 + 2*n;                       // [2][NBCH][n]
  unsigned* copies = (unsigned*)(choff + (size_t)2*NBCH*n);  // [2][NBCH][nw]
  int* partial = (int*)(copies + (size_t)2*NBCH*nw);         // 2*nb ints
  ushort* wbuf = (ushort*)(partial + 512);
  ushort* Wqb = wbuf;                              // Wq,Wk,Wv contiguous for qkv
  ushort* Wkb = Wqb + 16384;
  ushort* Wvb = Wkb + 16384;
  ushort* Wob = Wvb + 16384;
  ushort* W1b = Wob + 16384;
  ushort* W2b = W1b + 65536;
  ushort* h1  = qb;                                // n*512 bf16, aliases qb..sbuf

  // weight conversion (independent)
  CvtArgs ca;
  ca.s[0]=Wq; ca.s[1]=Wk; ca.s[2]=Wv; ca.s[3]=Wo; ca.s[4]=W1; ca.s[5]=W2;
  ca.d[0]=Wqb; ca.d[1]=Wkb; ca.d[2]=Wvb; ca.d[3]=Wob; ca.d[4]=W1b; ca.d[5]=W2b;
  ca.cnt[0]=ca.cnt[1]=ca.cnt[2]=ca.cnt[3]=16384; ca.cnt[4]=ca.cnt[5]=65536;
  cvt6_kernel<<<dim3(65536/256, 6), 256, 0, stream>>>(ca);

  // atomic-free CSR build (bin-segmented LDS histograms)
  int nb = (n + 1023)/1024;
  hist_seg  <<<dim3(NBCH,NSEG,2), 256, 0, stream>>>(ei, copies, E, n, nw, chunk, nsb);
  scan_fold <<<dim3((n+255)/256,2), 256, 0, stream>>>(copies, cnt2, choff, n, nw);
  scan_reduce <<<dim3(nb,2), 256, 0, stream>>>(cnt2, partial, n, nb);
  scan_mid    <<<dim3(1,2),  256, 0, stream>>>(partial, nb, rptr, cptr, n);
  scan_scatter<<<dim3(nb,2), 256, 0, stream>>>(cnt2, partial, rptr, cptr, n, nb);
  fill_r_seg<<<dim3(NBCH,NSEG), 256, 0, stream>>>(ei, rptr, choff,                  rcol, pose, E, n, chunk, nsb);
  fill_c_seg<<<dim3(NBCH,NSEG), 256, 0, stream>>>(ei, cptr, choff + (size_t)NBCH*n, pose, crow, cposr, E, n, chunk, nsb);

  // LN1 -> bf16
  ln_kernel<<<(n+3)/4, 256, 0, stream>>>(feats, ln1w, ln1b, x2b, n);

  // fused QKV projections (LDS-staged bf16 MFMA, bf16 out)
  int gm = (n + 63)/64;
  qkv_lds<<<dim3(gm,3), 256, 0, stream>>>(x2b, Wqb, bq, bk, bv, qb, kb, vb, n);

  // fused segmented softmax (online m,d), alpha scattered to col-CSR order
  row_softmax_kernel<<<(n+3)/4, 256, 0, stream>>>(qb, kb, rptr, rcol, cposr, sbuf, cbuf, n);

  // gather aggregation (streamed alpha, 2 edges in flight) -> bf16
  agg_kernel<<<(n+3)/4, 256, 0, stream>>>(vb, cbuf, cptr, crow, aggb, n);

  // attention out projection + residual -> d_out (f32)
  gemm_lds<128,0,1,0><<<dim3(gm,1), 256, 0, stream>>>(aggb, Wob, bo, feats, outp, n, 128);

  // LN2 -> bf16
  ln_kernel<<<(n+3)/4, 256, 0, stream>>>(outp, ln2w, ln2b, x2b, n);

  // FFN
  gemm_lds<128,1,0,1><<<dim3(gm,4), 256, 0, stream>>>(x2b, W1b, b1, nullptr, h1,  n, 512);
  gemm_lds<512,1,1,0><<<dim3(gm,1), 256, 0, stream>>>(h1,  W2b, b2, outp,    outp, n, 128);
}

// Round 12
// 315.770 us; speedup vs baseline: 2.4986x; 1.0656x over previous
//
#include <hip/hip_runtime.h>
#include <hip/hip_bf16.h>
#include <math.h>

#define H_HEADS 8
constexpr float LN_EPS = 1e-5f;
constexpr int NBCH = 64;          // CSR build chunks (chunk <= 65535 for u16 counters)
constexpr int NSEG = 4;           // bin segments per chunk (LDS = ~n/NSEG/2 words)

using short8 = __attribute__((ext_vector_type(8))) short;
using f32x4  = __attribute__((ext_vector_type(4))) float;

__device__ __forceinline__ ushort f2bf(float v){
  __hip_bfloat16 h = __float2bfloat16(v);
  return *reinterpret_cast<ushort*>(&h);
}
__device__ __forceinline__ float bf2f(ushort u){
  return __uint_as_float(((unsigned)u) << 16);
}

// async global->LDS, 16B per lane; dest = wave-uniform base + lane*16
__device__ __forceinline__ void stage16(const ushort* g, ushort* l){
  __builtin_amdgcn_global_load_lds((const __attribute__((address_space(1))) unsigned*)g,
                                   (__attribute__((address_space(3))) unsigned*)l,
                                   16, 0, 0);
}

// ---------- LayerNorm (ddof=1), f32 in -> bf16 out, one wave per row ----------
__global__ void ln_kernel(const float* __restrict__ x, const float* __restrict__ w,
                          const float* __restrict__ b, ushort* __restrict__ out, int nrows){
  int wid = threadIdx.x >> 6, lane = threadIdx.x & 63;
  int r = blockIdx.x * (blockDim.x >> 6) + wid;
  if (r >= nrows) return;
  float2 v = ((const float2*)(x + (size_t)r*128))[lane];
  float s = v.x + v.y;
  #pragma unroll
  for (int o = 32; o; o >>= 1) s += __shfl_xor(s, o);
  float mu = s * (1.0f/128.0f);
  float d0 = v.x - mu, d1 = v.y - mu;
  float ss = d0*d0 + d1*d1;
  #pragma unroll
  for (int o = 32; o; o >>= 1) ss += __shfl_xor(ss, o);
  float sd = sqrtf(ss * (1.0f/127.0f));
  float inv = 1.0f / (sd + LN_EPS);
  float2 wv = ((const float2*)w)[lane];
  float2 bv = ((const float2*)b)[lane];
  ushort2 o2 = { f2bf(d0*inv*wv.x + bv.x), f2bf(d1*inv*wv.y + bv.y) };
  ((ushort2*)(out + (size_t)r*128))[lane] = o2;
}

// ---------- weight f32 -> bf16 conversion (all 6 in one launch) ----------
struct CvtArgs { const float* s[6]; ushort* d[6]; int cnt[6]; };
__global__ void cvt6_kernel(CvtArgs a){
  int w = blockIdx.y;
  int i = blockIdx.x*blockDim.x + threadIdx.x;
  if (i < a.cnt[w]) a.d[w][i] = f2bf(a.s[w][i]);
}

// ---------- LDS-staged bf16 MFMA GEMM ----------
template<int K, int RELU, int RESID, int OUT_BF16>
__device__ __forceinline__ void gemm_lds_body(
    const ushort* __restrict__ A, const ushort* __restrict__ W,
    const float* __restrict__ bias, const float* __restrict__ resid,
    void* __restrict__ out, int M, int Nout, int cb, ushort* Wl){
  constexpr int NCH = K / 128;
  int t = threadIdx.x;
  int wid = t >> 6, lane = t & 63;
  int mb = blockIdx.x * 64 + wid * 16;
  int lrow = lane & 15, kgrp = lane >> 4;
  int row = mb + lrow;
  bool rowok = row < M;
  const ushort* arow = A + (size_t)(rowok ? row : (M-1)) * K + kgrp*8;

  f32x4 acc[8] = {};
  short8 af[2][4];

  #pragma unroll
  for (int p = 0; p < 8; ++p){
    int L = p*256 + t;
    int colp = L >> 4, sp = L & 15;
    stage16(W + (size_t)colp*K + ((sp ^ (colp & 7)) << 3),
            (ushort*)((char*)Wl + ((size_t)(p*256 + (t & ~63)))*16));
  }
  #pragma unroll
  for (int kk = 0; kk < 4; ++kk)
    af[0][kk] = *(const short8*)(arow + kk*32);

  #pragma unroll
  for (int ci = 0; ci < NCH; ++ci){
    __syncthreads();
    int cur = ci & 1;
    if (ci + 1 < NCH){
      #pragma unroll
      for (int kk = 0; kk < 4; ++kk)
        af[cur^1][kk] = *(const short8*)(arow + (ci+1)*128 + kk*32);
    }
    #pragma unroll
    for (int kk = 0; kk < 4; ++kk){
      #pragma unroll
      for (int nt = 0; nt < 8; ++nt){
        int colc = nt*16 + lrow;
        int g = kk*4 + kgrp;
        short8 bfv = *(const short8*)((const char*)Wl + colc*256 + ((g ^ (colc & 7))*16));
        acc[nt] = __builtin_amdgcn_mfma_f32_16x16x32_bf16(af[cur][kk], bfv, acc[nt], 0, 0, 0);
      }
    }
    if (ci + 1 < NCH){
      __syncthreads();
      const ushort* Wc = W + (ci+1)*128;
      #pragma unroll
      for (int p = 0; p < 8; ++p){
        int L = p*256 + t;
        int colp = L >> 4, sp = L & 15;
        stage16(Wc + (size_t)colp*K + ((sp ^ (colp & 7)) << 3),
                (ushort*)((char*)Wl + ((size_t)(p*256 + (t & ~63)))*16));
      }
    }
  }

  int r0 = mb + kgrp*4;
  #pragma unroll
  for (int nt = 0; nt < 8; ++nt){
    int c = cb + nt*16 + lrow;
    float bsum = bias[c];
    #pragma unroll
    for (int i = 0; i < 4; ++i){
      int r = r0 + i;
      if (r >= M) continue;
      float v = acc[nt][i] + bsum;
      if (RELU)  v = fmaxf(v, 0.0f);
      if (RESID) v += resid[(size_t)r*Nout + c];
      if (OUT_BF16) ((ushort*)out)[(size_t)r*Nout + c] = f2bf(v);
      else          ((float*)out)[(size_t)r*Nout + c] = v;
    }
  }
}

template<int K, int RELU, int RESID, int OUT_BF16>
__global__ __launch_bounds__(256) void gemm_lds(
    const ushort* __restrict__ A, const ushort* __restrict__ Wfull,
    const float* __restrict__ bias, const float* __restrict__ resid,
    void* __restrict__ out, int M, int Nout){
  __shared__ __align__(16) ushort Wl[16384];
  int cb = blockIdx.y * 128;
  gemm_lds_body<K,RELU,RESID,OUT_BF16>(A, Wfull + (size_t)cb*K, bias, resid, out, M, Nout, cb, Wl);
}

__global__ __launch_bounds__(256) void qkv_lds(
    const ushort* __restrict__ A, const ushort* __restrict__ Wcat,
    const float* __restrict__ bq, const float* __restrict__ bk, const float* __restrict__ bv,
    ushort* __restrict__ qb, ushort* __restrict__ kb, ushort* __restrict__ vb, int M){
  __shared__ __align__(16) ushort Wl[16384];
  int y = blockIdx.y;
  const float* bias = (y==0) ? bq : (y==1) ? bk : bv;
  ushort* out = (y==0) ? qb : (y==1) ? kb : vb;
  gemm_lds_body<128,0,0,1>(A, Wcat + (size_t)y*16384, bias, nullptr, out, M, 128, 0, Wl);
}

// ---------- CSR build, atomic-free, bin-segmented (chunk x segment grid) ----------
__global__ __launch_bounds__(256) void hist_seg(const int* __restrict__ ei,
    unsigned* __restrict__ copies, int E, int n, int nw, int chunk, int nsb){
  __shared__ unsigned hh[8192];
  int b = blockIdx.x, s = blockIdx.y, y = blockIdx.z, t = threadIdx.x;
  int bin0 = s * nsb;
  int bin1 = min(bin0 + nsb, n);
  int words = (bin1 - bin0 + 1) >> 1;
  for (int i = t; i < words; i += 256) hh[i] = 0;
  __syncthreads();
  int lo = b*chunk, hi = min(lo + chunk, E);
  for (int e = lo + t; e < hi; e += 256){
    int2 rc = ((const int2*)ei)[e];
    int bin = y ? rc.y : rc.x;
    if (bin >= bin0 && bin < bin1)
      atomicAdd(&hh[(bin - bin0) >> 1], 1u << ((bin & 1)*16));
  }
  __syncthreads();
  unsigned* dst = copies + ((size_t)y*NBCH + b)*nw + (bin0 >> 1);
  for (int i = t; i < words; i += 256) dst[i] = hh[i];
}

__global__ __launch_bounds__(256) void scan_fold(const unsigned* __restrict__ copies,
    int* __restrict__ cnt2, int* __restrict__ choff, int n, int nw){
  int y = blockIdx.y;
  int bin = blockIdx.x*256 + threadIdx.x;
  if (bin >= n) return;
  const unsigned* cp = copies + (size_t)y*NBCH*nw + (bin >> 1);
  int sh = (bin & 1)*16;
  int run = 0;
  for (int b = 0; b < NBCH; ++b){
    int c = (int)((cp[(size_t)b*nw] >> sh) & 0xffffu);
    choff[((size_t)y*NBCH + b)*n + bin] = run;
    run += c;
  }
  cnt2[(size_t)y*n + bin] = run;
}

// ---------- parallel 3-phase exclusive scan over cnt2 (both arrays, gridDim.y=2) ----------
__global__ __launch_bounds__(256) void scan_reduce(const int* __restrict__ cnt0,
                                                   int* __restrict__ partial, int n, int nb){
  const int* cnt = cnt0 + (size_t)blockIdx.y * n;
  int t = threadIdx.x;
  int base = blockIdx.x*1024 + t*4;
  int s = 0;
  #pragma unroll
  for (int j = 0; j < 4; ++j){ int i = base+j; if (i < n) s += cnt[i]; }
  __shared__ int sm[256];
  sm[t] = s; __syncthreads();
  for (int off = 128; off; off >>= 1){
    if (t < off) sm[t] += sm[t+off];
    __syncthreads();
  }
  if (t == 0) partial[blockIdx.y*nb + blockIdx.x] = sm[0];
}

__global__ __launch_bounds__(256) void scan_mid(int* __restrict__ partial, int nb,
                                                int* __restrict__ rptr, int* __restrict__ cptr, int n){
  int y = blockIdx.y;
  int* p = partial + y*nb;
  int t = threadIdx.x;
  __shared__ int sm[256];
  sm[t] = (t < nb) ? p[t] : 0;
  __syncthreads();
  for (int off = 1; off < 256; off <<= 1){
    int v = (t >= off) ? sm[t-off] : 0;
    __syncthreads();
    sm[t] += v;
    __syncthreads();
  }
  if (t < nb) p[t] = (t == 0) ? 0 : sm[t-1];
  if (t == 0) (y ? cptr : rptr)[n] = sm[255];
}

__global__ __launch_bounds__(256) void scan_scatter(const int* __restrict__ cnt0,
                                                    const int* __restrict__ partial,
                                                    int* __restrict__ rptr, int* __restrict__ cptr,
                                                    int n, int nb){
  int y = blockIdx.y;
  const int* cnt = cnt0 + (size_t)y * n;
  int* ptr = y ? cptr : rptr;
  int t = threadIdx.x;
  int base = blockIdx.x*1024 + t*4;
  int v[4]; int s = 0;
  #pragma unroll
  for (int j = 0; j < 4; ++j){ int i = base+j; v[j] = (i<n)?cnt[i]:0; s += v[j]; }
  __shared__ int sm[256];
  sm[t] = s; __syncthreads();
  for (int off = 1; off < 256; off <<= 1){
    int x = (t >= off) ? sm[t-off] : 0;
    __syncthreads();
    sm[t] += x;
    __syncthreads();
  }
  int pre = partial[y*nb + blockIdx.x] + ((t==0)?0:sm[t-1]);
  #pragma unroll
  for (int j = 0; j < 4; ++j){
    int i = base+j;
    if (i < n){ ptr[i] = pre; pre += v[j]; }
  }
}

// fill via in-chunk LDS rank within bin segment; no global atomics
__global__ __launch_bounds__(256) void fill_r_seg(const int* __restrict__ ei,
    const int* __restrict__ rptr, const int* __restrict__ choffR,
    int* __restrict__ rcol, int* __restrict__ pose, int E, int n, int chunk, int nsb){
  __shared__ unsigned hh[8192];
  int b = blockIdx.x, s = blockIdx.y, t = threadIdx.x;
  int bin0 = s * nsb;
  int bin1 = min(bin0 + nsb, n);
  int words = (bin1 - bin0 + 1) >> 1;
  for (int i = t; i < words; i += 256) hh[i] = 0;
  __syncthreads();
  const int* chb = choffR + (size_t)b*n;
  int lo = b*chunk, hi = min(lo + chunk, E);
  for (int e = lo + t; e < hi; e += 256){
    int2 rc = ((const int2*)ei)[e];
    int bin = rc.x;
    if (bin < bin0 || bin >= bin1) continue;
    int sh = (bin & 1)*16;
    unsigned old = atomicAdd(&hh[(bin - bin0) >> 1], 1u << sh);
    int rank = (int)((old >> sh) & 0xffffu);
    int pos = rptr[bin] + chb[bin] + rank;
    rcol[pos] = rc.y;
    pose[e] = pos;
  }
}

__global__ __launch_bounds__(256) void fill_c_seg(const int* __restrict__ ei,
    const int* __restrict__ cptr, const int* __restrict__ choffC,
    const int* __restrict__ pose, int* __restrict__ crow, int* __restrict__ cposr,
    int E, int n, int chunk, int nsb){
  __shared__ unsigned hh[8192];
  int b = blockIdx.x, s = blockIdx.y, t = threadIdx.x;
  int bin0 = s * nsb;
  int bin1 = min(bin0 + nsb, n);
  int words = (bin1 - bin0 + 1) >> 1;
  for (int i = t; i < words; i += 256) hh[i] = 0;
  __syncthreads();
  const int* chb = choffC + (size_t)b*n;
  int lo = b*chunk, hi = min(lo + chunk, E);
  for (int e = lo + t; e < hi; e += 256){
    int2 rc = ((const int2*)ei)[e];
    int bin = rc.y;
    if (bin < bin0 || bin >= bin1) continue;
    int sh = (bin & 1)*16;
    unsigned old = atomicAdd(&hh[(bin - bin0) >> 1], 1u << sh);
    int rank = (int)((old >> sh) & 0xffffu);
    int pos = cptr[bin] + chb[bin] + rank;
    crow[pos] = rc.x;
    cposr[pose[e]] = pos;
  }
}

// ---------- q.k dot for one head (16 dims), kf kept in regs via full unroll ----------
__device__ __forceinline__ float qdot16(const ushort* __restrict__ qb, int c, int h,
                                        const float kf[16]){
  const short8* qp = (const short8*)(qb + (size_t)c*128 + h*16);
  short8 q0 = qp[0], q1 = qp[1];
  float s = 0.f;
  #pragma unroll
  for (int i = 0; i < 8; ++i){
    s += bf2f((ushort)q0[i]) * kf[i];
    s += bf2f((ushort)q1[i]) * kf[8+i];
  }
  return s * 0.25f;   // 1/sqrt(16)
}

// ---------- fused segmented softmax over row-CSR ----------
// scores kept in an 8-slot REGISTER ring per lane (deg <= 64; Poisson(16) => always).
// deg > 64 falls back to recompute. alpha written bf16 to col-CSR positions.
__global__ void row_softmax_kernel(const ushort* __restrict__ qb, const ushort* __restrict__ kb,
                                   const int* __restrict__ rptr, const int* __restrict__ rcol,
                                   const int* __restrict__ cposr,
                                   ushort* __restrict__ cbuf, int n){
  int wid = threadIdx.x >> 6, lane = threadIdx.x & 63;
  int r = blockIdx.x * (blockDim.x >> 6) + wid;
  if (r >= n) return;
  int lo = rptr[r], hi = rptr[r+1];
  if (lo >= hi) return;
  int h = lane & 7, el = lane >> 3;

  float kf[16];
  {
    const short8* kp = (const short8*)(kb + (size_t)r*128 + h*16);
    short8 k0 = kp[0], k1 = kp[1];
    #pragma unroll
    for (int i = 0; i < 8; ++i){
      kf[i]   = bf2f((ushort)k0[i]);
      kf[8+i] = bf2f((ushort)k1[i]);
    }
  }

  float m = -1e30f, d = 0.f;
  float sreg[8];
  #pragma unroll
  for (int ts = 0; ts < 8; ++ts){
    int j = lo + el + ts*8;
    float s = -1e30f;
    if (j < hi){
      s = qdot16(qb, rcol[j], h, kf);
      float nm = fmaxf(m, s);
      d = d*__expf(m - nm) + __expf(s - nm);
      m = nm;
    }
    sreg[ts] = s;
  }
  // overflow tail (deg > 64): fold into (m,d), recompute later
  for (int j = lo + el + 64; j < hi; j += 8){
    float s = qdot16(qb, rcol[j], h, kf);
    float nm = fmaxf(m, s);
    d = d*__expf(m - nm) + __expf(s - nm);
    m = nm;
  }
  #pragma unroll
  for (int o = 8; o < 64; o <<= 1){
    float om = __shfl_xor(m, o);
    float od = __shfl_xor(d, o);
    float nm = fmaxf(m, om);
    d = d*__expf(m - nm) + od*__expf(om - nm);
    m = nm;
  }
  float invd = 1.0f / d;

  #pragma unroll
  for (int ts = 0; ts < 8; ++ts){
    int j = lo + el + ts*8;
    if (j < hi)
      cbuf[(size_t)cposr[j]*8 + h] = f2bf(__expf(sreg[ts] - m) * invd);
  }
  for (int j = lo + el + 64; j < hi; j += 8){
    float s = qdot16(qb, rcol[j], h, kf);
    cbuf[(size_t)cposr[j]*8 + h] = f2bf(__expf(s - m) * invd);
  }
}

// ---------- gather aggregation over col-CSR -> bf16 agg ----------
// four 16-lane quarters process alternate edges (4 dependent chains in flight);
// each lane covers 8 dims (ushort8); reduce via shfl_xor(16,32).
__global__ void agg_kernel(const ushort* __restrict__ vb, const ushort* __restrict__ cbuf,
                           const int* __restrict__ cptr, const int* __restrict__ crow,
                           ushort* __restrict__ aggb, int n){
  int wid = threadIdx.x >> 6, lane = threadIdx.x & 63;
  int node = blockIdx.x * (blockDim.x >> 6) + wid;
  if (node >= n) return;
  int lo = cptr[node], hi = cptr[node+1];
  int qtr = lane >> 4, l16 = lane & 15;
  int h = l16 >> 1;                      // dims [l16*8, l16*8+8) -> head l16/2
  float acc[8] = {};
  for (int j = lo + qtr; j < hi; j += 4){
    float a = bf2f(cbuf[(size_t)j*8 + h]);
    int row = crow[j];
    short8 vv = *(const short8*)(vb + (size_t)row*128 + l16*8);
    #pragma unroll
    for (int i = 0; i < 8; ++i)
      acc[i] = fmaf(a, bf2f((ushort)vv[i]), acc[i]);
  }
  #pragma unroll
  for (int i = 0; i < 8; ++i){
    acc[i] += __shfl_xor(acc[i], 16);
    acc[i] += __shfl_xor(acc[i], 32);
  }
  if (qtr == 0){
    short8 o8;
    #pragma unroll
    for (int i = 0; i < 8; ++i) o8[i] = (short)f2bf(acc[i]);
    *(short8*)(aggb + (size_t)node*128 + l16*8) = o8;
  }
}

extern "C" void kernel_launch(void* const* d_in, const int* in_sizes, int n_in,
                              void* d_out, int out_size, void* d_ws, size_t ws_size,
                              hipStream_t stream){
  const float* feats = (const float*)d_in[0];
  const int*   ei    = (const int*)  d_in[1];
  const float* Wq = (const float*)d_in[2];
  const float* bq = (const float*)d_in[3];
  const float* Wk = (const float*)d_in[4];
  const float* bk = (const float*)d_in[5];
  const float* Wv = (const float*)d_in[6];
  const float* bv = (const float*)d_in[7];
  const float* Wo = (const float*)d_in[8];
  const float* bo = (const float*)d_in[9];
  const float* ln1w = (const float*)d_in[10];
  const float* ln1b = (const float*)d_in[11];
  const float* ln2w = (const float*)d_in[12];
  const float* ln2b = (const float*)d_in[13];
  const float* W1 = (const float*)d_in[14];
  const float* b1 = (const float*)d_in[15];
  const float* W2 = (const float*)d_in[16];
  const float* b2 = (const float*)d_in[17];
  float* outp = (float*)d_out;

  int n = in_sizes[0] / 128;      // 50000 nodes
  int E = in_sizes[1] / 2;        // 800000 edges
  int nw = (n + 1) >> 1;          // packed u16 words per full histogram
  int chunk = (E + NBCH - 1) / NBCH;
  int nsb = (((n + NSEG - 1) / NSEG) + 1) & ~1;   // bins per segment (even)

  const size_t ND  = (size_t)n * 128;
  const size_t ND2 = ND / 2;
  const size_t EH  = (size_t)E * H_HEADS;

  // workspace (f32 units): x2b | qb | kb | vb | cbuf(bf16, EH/2) | aggb | ints...
  // h1 (n*512 bf16 = 4*ND2 f32 units) aliases qb..cbuf exactly; aggb is beyond it.
  float* ws = (float*)d_ws;
  ushort* x2b  = (ushort*)ws;                      // ND bf16
  ushort* qb   = (ushort*)(ws + ND2);
  ushort* kb   = (ushort*)(ws + 2*ND2);
  ushort* vb   = (ushort*)(ws + 3*ND2);
  ushort* cbuf = (ushort*)(ws + 4*ND2);            // EH bf16 (alpha, col order)
  ushort* aggb = (ushort*)(ws + 4*ND2 + EH/2);     // ND bf16
  int* crow    = (int*)(ws + 5*ND2 + EH/2);
  int* cposr   = crow + E;
  int* rcol    = cposr + E;
  int* pose    = rcol + E;
  int* rptr    = pose + E;
  int* cptr    = rptr + (n + 4);
  int* cnt2    = cptr + (n + 4);                   // [2][n]
  int* choff   = cnt2 + 2*n;                       // [2][NBCH][n]
  unsigned* copies = (unsigned*)(choff + (size_t)2*NBCH*n);  // [2][NBCH][nw]
  int* partial = (int*)(copies + (size_t)2*NBCH*nw);         // 2*nb ints
  ushort* wbuf = (ushort*)(partial + 512);
  ushort* Wqb = wbuf;                              // Wq,Wk,Wv contiguous for qkv
  ushort* Wkb = Wqb + 16384;
  ushort* Wvb = Wkb + 16384;
  ushort* Wob = Wvb + 16384;
  ushort* W1b = Wob + 16384;
  ushort* W2b = W1b + 65536;
  ushort* h1  = qb;                                // n*512 bf16 == qb..cbuf

  // weight conversion (independent)
  CvtArgs ca;
  ca.s[0]=Wq; ca.s[1]=Wk; ca.s[2]=Wv; ca.s[3]=Wo; ca.s[4]=W1; ca.s[5]=W2;
  ca.d[0]=Wqb; ca.d[1]=Wkb; ca.d[2]=Wvb; ca.d[3]=Wob; ca.d[4]=W1b; ca.d[5]=W2b;
  ca.cnt[0]=ca.cnt[1]=ca.cnt[2]=ca.cnt[3]=16384; ca.cnt[4]=ca.cnt[5]=65536;
  cvt6_kernel<<<dim3(65536/256, 6), 256, 0, stream>>>(ca);

  // atomic-free CSR build (bin-segmented LDS histograms)
  int nb = (n + 1023)/1024;
  hist_seg  <<<dim3(NBCH,NSEG,2), 256, 0, stream>>>(ei, copies, E, n, nw, chunk, nsb);
  scan_fold <<<dim3((n+255)/256,2), 256, 0, stream>>>(copies, cnt2, choff, n, nw);
  scan_reduce <<<dim3(nb,2), 256, 0, stream>>>(cnt2, partial, n, nb);
  scan_mid    <<<dim3(1,2),  256, 0, stream>>>(partial, nb, rptr, cptr, n);
  scan_scatter<<<dim3(nb,2), 256, 0, stream>>>(cnt2, partial, rptr, cptr, n, nb);
  fill_r_seg<<<dim3(NBCH,NSEG), 256, 0, stream>>>(ei, rptr, choff,                  rcol, pose, E, n, chunk, nsb);
  fill_c_seg<<<dim3(NBCH,NSEG), 256, 0, stream>>>(ei, cptr, choff + (size_t)NBCH*n, pose, crow, cposr, E, n, chunk, nsb);

  // LN1 -> bf16
  ln_kernel<<<(n+3)/4, 256, 0, stream>>>(feats, ln1w, ln1b, x2b, n);

  // fused QKV projections (LDS-staged bf16 MFMA, bf16 out)
  int gm = (n + 63)/64;
  qkv_lds<<<dim3(gm,3), 256, 0, stream>>>(x2b, Wqb, bq, bk, bv, qb, kb, vb, n);

  // fused segmented softmax (register score ring), alpha bf16 -> col-CSR order
  row_softmax_kernel<<<(n+3)/4, 256, 0, stream>>>(qb, kb, rptr, rcol, cposr, cbuf, n);

  // gather aggregation (4 edges in flight) -> bf16
  agg_kernel<<<(n+3)/4, 256, 0, stream>>>(vb, cbuf, cptr, crow, aggb, n);

  // attention out projection + residual -> d_out (f32)
  gemm_lds<128,0,1,0><<<dim3(gm,1), 256, 0, stream>>>(aggb, Wob, bo, feats, outp, n, 128);

  // LN2 -> bf16
  ln_kernel<<<(n+3)/4, 256, 0, stream>>>(outp, ln2w, ln2b, x2b, n);

  // FFN
  gemm_lds<128,1,0,1><<<dim3(gm,4), 256, 0, stream>>>(x2b, W1b, b1, nullptr, h1,  n, 512);
  gemm_lds<512,1,1,0><<<dim3(gm,1), 256, 0, stream>>>(h1,  W2b, b2, outp,    outp, n, 128);
}

// Round 13
// 314.824 us; speedup vs baseline: 2.5061x; 1.0030x over previous
//
#include <hip/hip_runtime.h>
#include <hip/hip_bf16.h>
#include <math.h>

#define H_HEADS 8
constexpr float LN_EPS = 1e-5f;
constexpr int NBCH = 64;          // CSR build chunks (chunk <= 65535 for u16 counters)
constexpr int NSEG = 4;           // bin segments per chunk

using short8 = __attribute__((ext_vector_type(8))) short;
using f32x4  = __attribute__((ext_vector_type(4))) float;

__device__ __forceinline__ ushort f2bf(float v){
  __hip_bfloat16 h = __float2bfloat16(v);
  return *reinterpret_cast<ushort*>(&h);
}
__device__ __forceinline__ float bf2f(ushort u){
  return __uint_as_float(((unsigned)u) << 16);
}

// async global->LDS, 16B per lane; dest = wave-uniform base + lane*16
__device__ __forceinline__ void stage16(const ushort* g, ushort* l){
  __builtin_amdgcn_global_load_lds((const __attribute__((address_space(1))) unsigned*)g,
                                   (__attribute__((address_space(3))) unsigned*)l,
                                   16, 0, 0);
}

// ---------- LayerNorm (ddof=1), f32 in -> bf16 out, one wave per row ----------
__global__ void ln_kernel(const float* __restrict__ x, const float* __restrict__ w,
                          const float* __restrict__ b, ushort* __restrict__ out, int nrows){
  int wid = threadIdx.x >> 6, lane = threadIdx.x & 63;
  int r = blockIdx.x * (blockDim.x >> 6) + wid;
  if (r >= nrows) return;
  float2 v = ((const float2*)(x + (size_t)r*128))[lane];
  float s = v.x + v.y;
  #pragma unroll
  for (int o = 32; o; o >>= 1) s += __shfl_xor(s, o);
  float mu = s * (1.0f/128.0f);
  float d0 = v.x - mu, d1 = v.y - mu;
  float ss = d0*d0 + d1*d1;
  #pragma unroll
  for (int o = 32; o; o >>= 1) ss += __shfl_xor(ss, o);
  float sd = sqrtf(ss * (1.0f/127.0f));
  float inv = 1.0f / (sd + LN_EPS);
  float2 wv = ((const float2*)w)[lane];
  float2 bv = ((const float2*)b)[lane];
  ushort2 o2 = { f2bf(d0*inv*wv.x + bv.x), f2bf(d1*inv*wv.y + bv.y) };
  ((ushort2*)(out + (size_t)r*128))[lane] = o2;
}

// ---------- weight f32 -> bf16 conversion (all 6 in one launch) ----------
struct CvtArgs { const float* s[6]; ushort* d[6]; int cnt[6]; };
__global__ void cvt6_kernel(CvtArgs a){
  int w = blockIdx.y;
  int i = blockIdx.x*blockDim.x + threadIdx.x;
  if (i < a.cnt[w]) a.d[w][i] = f2bf(a.s[w][i]);
}

// ---------- LDS-staged bf16 MFMA GEMM ----------
template<int K, int RELU, int RESID, int OUT_BF16>
__device__ __forceinline__ void gemm_lds_body(
    const ushort* __restrict__ A, const ushort* __restrict__ W,
    const float* __restrict__ bias, const float* __restrict__ resid,
    void* __restrict__ out, int M, int Nout, int cb, ushort* Wl){
  constexpr int NCH = K / 128;
  int t = threadIdx.x;
  int wid = t >> 6, lane = t & 63;
  int mb = blockIdx.x * 64 + wid * 16;
  int lrow = lane & 15, kgrp = lane >> 4;
  int row = mb + lrow;
  bool rowok = row < M;
  const ushort* arow = A + (size_t)(rowok ? row : (M-1)) * K + kgrp*8;

  f32x4 acc[8] = {};
  short8 af[2][4];

  #pragma unroll
  for (int p = 0; p < 8; ++p){
    int L = p*256 + t;
    int colp = L >> 4, sp = L & 15;
    stage16(W + (size_t)colp*K + ((sp ^ (colp & 7)) << 3),
            (ushort*)((char*)Wl + ((size_t)(p*256 + (t & ~63)))*16));
  }
  #pragma unroll
  for (int kk = 0; kk < 4; ++kk)
    af[0][kk] = *(const short8*)(arow + kk*32);

  #pragma unroll
  for (int ci = 0; ci < NCH; ++ci){
    __syncthreads();
    int cur = ci & 1;
    if (ci + 1 < NCH){
      #pragma unroll
      for (int kk = 0; kk < 4; ++kk)
        af[cur^1][kk] = *(const short8*)(arow + (ci+1)*128 + kk*32);
    }
    #pragma unroll
    for (int kk = 0; kk < 4; ++kk){
      #pragma unroll
      for (int nt = 0; nt < 8; ++nt){
        int colc = nt*16 + lrow;
        int g = kk*4 + kgrp;
        short8 bfv = *(const short8*)((const char*)Wl + colc*256 + ((g ^ (colc & 7))*16));
        acc[nt] = __builtin_amdgcn_mfma_f32_16x16x32_bf16(af[cur][kk], bfv, acc[nt], 0, 0, 0);
      }
    }
    if (ci + 1 < NCH){
      __syncthreads();
      const ushort* Wc = W + (ci+1)*128;
      #pragma unroll
      for (int p = 0; p < 8; ++p){
        int L = p*256 + t;
        int colp = L >> 4, sp = L & 15;
        stage16(Wc + (size_t)colp*K + ((sp ^ (colp & 7)) << 3),
                (ushort*)((char*)Wl + ((size_t)(p*256 + (t & ~63)))*16));
      }
    }
  }

  int r0 = mb + kgrp*4;
  #pragma unroll
  for (int nt = 0; nt < 8; ++nt){
    int c = cb + nt*16 + lrow;
    float bsum = bias[c];
    #pragma unroll
    for (int i = 0; i < 4; ++i){
      int r = r0 + i;
      if (r >= M) continue;
      float v = acc[nt][i] + bsum;
      if (RELU)  v = fmaxf(v, 0.0f);
      if (RESID) v += resid[(size_t)r*Nout + c];
      if (OUT_BF16) ((ushort*)out)[(size_t)r*Nout + c] = f2bf(v);
      else          ((float*)out)[(size_t)r*Nout + c] = v;
    }
  }
}

template<int K, int RELU, int RESID, int OUT_BF16>
__global__ __launch_bounds__(256) void gemm_lds(
    const ushort* __restrict__ A, const ushort* __restrict__ Wfull,
    const float* __restrict__ bias, const float* __restrict__ resid,
    void* __restrict__ out, int M, int Nout){
  __shared__ __align__(16) ushort Wl[16384];
  int cb = blockIdx.y * 128;
  gemm_lds_body<K,RELU,RESID,OUT_BF16>(A, Wfull + (size_t)cb*K, bias, resid, out, M, Nout, cb, Wl);
}

__global__ __launch_bounds__(256) void qkv_lds(
    const ushort* __restrict__ A, const ushort* __restrict__ Wcat,
    const float* __restrict__ bq, const float* __restrict__ bk, const float* __restrict__ bv,
    ushort* __restrict__ qb, ushort* __restrict__ kb, ushort* __restrict__ vb, int M){
  __shared__ __align__(16) ushort Wl[16384];
  int y = blockIdx.y;
  const float* bias = (y==0) ? bq : (y==1) ? bk : bv;
  ushort* out = (y==0) ? qb : (y==1) ? kb : vb;
  gemm_lds_body<128,0,0,1>(A, Wcat + (size_t)y*16384, bias, nullptr, out, M, 128, 0, Wl);
}

// ---------- CSR build, atomic-free, bin-segmented ----------
// merged row+col histograms: one chunk pass updates both (2 x ~6250 words, 50KB LDS)
__global__ __launch_bounds__(256) void hist_seg2(const int* __restrict__ ei,
    unsigned* __restrict__ copies, int E, int n, int nw, int chunk, int nsb){
  __shared__ unsigned hh[12544];
  int b = blockIdx.x, s = blockIdx.y, t = threadIdx.x;
  int bin0 = s * nsb;
  int bin1 = min(bin0 + nsb, n);
  int words = (bin1 - bin0 + 1) >> 1;
  for (int i = t; i < 2*words; i += 256) hh[i] = 0;
  __syncthreads();
  int lo = b*chunk, hi = min(lo + chunk, E);
  for (int e = lo + t; e < hi; e += 256){
    int2 rc = ((const int2*)ei)[e];
    if (rc.x >= bin0 && rc.x < bin1)
      atomicAdd(&hh[(rc.x - bin0) >> 1], 1u << ((rc.x & 1)*16));
    if (rc.y >= bin0 && rc.y < bin1)
      atomicAdd(&hh[words + ((rc.y - bin0) >> 1)], 1u << ((rc.y & 1)*16));
  }
  __syncthreads();
  unsigned* d0 = copies + (size_t)b*nw + (bin0 >> 1);
  unsigned* d1 = copies + (size_t)(NBCH + b)*nw + (bin0 >> 1);
  for (int i = t; i < words; i += 256){ d0[i] = hh[i]; d1[i] = hh[words + i]; }
}

__global__ __launch_bounds__(256) void scan_fold(const unsigned* __restrict__ copies,
    int* __restrict__ cnt2, int* __restrict__ choff, int n, int nw){
  int y = blockIdx.y;
  int bin = blockIdx.x*256 + threadIdx.x;
  if (bin >= n) return;
  const unsigned* cp = copies + (size_t)y*NBCH*nw + (bin >> 1);
  int sh = (bin & 1)*16;
  int run = 0;
  for (int b = 0; b < NBCH; ++b){
    int c = (int)((cp[(size_t)b*nw] >> sh) & 0xffffu);
    choff[((size_t)y*NBCH + b)*n + bin] = run;
    run += c;
  }
  cnt2[(size_t)y*n + bin] = run;
}

// ---------- parallel 3-phase exclusive scan over cnt2 (both arrays, gridDim.y=2) ----------
__global__ __launch_bounds__(256) void scan_reduce(const int* __restrict__ cnt0,
                                                   int* __restrict__ partial, int n, int nb){
  const int* cnt = cnt0 + (size_t)blockIdx.y * n;
  int t = threadIdx.x;
  int base = blockIdx.x*1024 + t*4;
  int s = 0;
  #pragma unroll
  for (int j = 0; j < 4; ++j){ int i = base+j; if (i < n) s += cnt[i]; }
  __shared__ int sm[256];
  sm[t] = s; __syncthreads();
  for (int off = 128; off; off >>= 1){
    if (t < off) sm[t] += sm[t+off];
    __syncthreads();
  }
  if (t == 0) partial[blockIdx.y*nb + blockIdx.x] = sm[0];
}

__global__ __launch_bounds__(256) void scan_mid(int* __restrict__ partial, int nb,
                                                int* __restrict__ rptr, int* __restrict__ cptr, int n){
  int y = blockIdx.y;
  int* p = partial + y*nb;
  int t = threadIdx.x;
  __shared__ int sm[256];
  sm[t] = (t < nb) ? p[t] : 0;
  __syncthreads();
  for (int off = 1; off < 256; off <<= 1){
    int v = (t >= off) ? sm[t-off] : 0;
    __syncthreads();
    sm[t] += v;
    __syncthreads();
  }
  if (t < nb) p[t] = (t == 0) ? 0 : sm[t-1];
  if (t == 0) (y ? cptr : rptr)[n] = sm[255];
}

__global__ __launch_bounds__(256) void scan_scatter(const int* __restrict__ cnt0,
                                                    const int* __restrict__ partial,
                                                    int* __restrict__ rptr, int* __restrict__ cptr,
                                                    int n, int nb){
  int y = blockIdx.y;
  const int* cnt = cnt0 + (size_t)y * n;
  int* ptr = y ? cptr : rptr;
  int t = threadIdx.x;
  int base = blockIdx.x*1024 + t*4;
  int v[4]; int s = 0;
  #pragma unroll
  for (int j = 0; j < 4; ++j){ int i = base+j; v[j] = (i<n)?cnt[i]:0; s += v[j]; }
  __shared__ int sm[256];
  sm[t] = s; __syncthreads();
  for (int off = 1; off < 256; off <<= 1){
    int x = (t >= off) ? sm[t-off] : 0;
    __syncthreads();
    sm[t] += x;
    __syncthreads();
  }
  int pre = partial[y*nb + blockIdx.x] + ((t==0)?0:sm[t-1]);
  #pragma unroll
  for (int j = 0; j < 4; ++j){
    int i = base+j;
    if (i < n){ ptr[i] = pre; pre += v[j]; }
  }
}

// fill via in-chunk LDS rank within bin segment; no global atomics
__global__ __launch_bounds__(256) void fill_r_seg(const int* __restrict__ ei,
    const int* __restrict__ rptr, const int* __restrict__ choffR,
    int* __restrict__ rcol, int* __restrict__ pose, int E, int n, int chunk, int nsb){
  __shared__ unsigned hh[8192];
  int b = blockIdx.x, s = blockIdx.y, t = threadIdx.x;
  int bin0 = s * nsb;
  int bin1 = min(bin0 + nsb, n);
  int words = (bin1 - bin0 + 1) >> 1;
  for (int i = t; i < words; i += 256) hh[i] = 0;
  __syncthreads();
  const int* chb = choffR + (size_t)b*n;
  int lo = b*chunk, hi = min(lo + chunk, E);
  for (int e = lo + t; e < hi; e += 256){
    int2 rc = ((const int2*)ei)[e];
    int bin = rc.x;
    if (bin < bin0 || bin >= bin1) continue;
    int sh = (bin & 1)*16;
    unsigned old = atomicAdd(&hh[(bin - bin0) >> 1], 1u << sh);
    int rank = (int)((old >> sh) & 0xffffu);
    int pos = rptr[bin] + chb[bin] + rank;
    rcol[pos] = rc.y;
    pose[e] = pos;
  }
}

__global__ __launch_bounds__(256) void fill_c_seg(const int* __restrict__ ei,
    const int* __restrict__ cptr, const int* __restrict__ choffC,
    const int* __restrict__ pose, int* __restrict__ crow, int* __restrict__ cposr,
    int E, int n, int chunk, int nsb){
  __shared__ unsigned hh[8192];
  int b = blockIdx.x, s = blockIdx.y, t = threadIdx.x;
  int bin0 = s * nsb;
  int bin1 = min(bin0 + nsb, n);
  int words = (bin1 - bin0 + 1) >> 1;
  for (int i = t; i < words; i += 256) hh[i] = 0;
  __syncthreads();
  const int* chb = choffC + (size_t)b*n;
  int lo = b*chunk, hi = min(lo + chunk, E);
  for (int e = lo + t; e < hi; e += 256){
    int2 rc = ((const int2*)ei)[e];
    int bin = rc.y;
    if (bin < bin0 || bin >= bin1) continue;
    int sh = (bin & 1)*16;
    unsigned old = atomicAdd(&hh[(bin - bin0) >> 1], 1u << sh);
    int rank = (int)((old >> sh) & 0xffffu);
    int pos = cptr[bin] + chb[bin] + rank;
    crow[pos] = rc.x;
    cposr[pose[e]] = pos;
  }
}

// ---------- q.k dot for one head (16 dims), kf kept in regs ----------
__device__ __forceinline__ float qdot16(const ushort* __restrict__ qb, int c, int h,
                                        const float kf[16]){
  const short8* qp = (const short8*)(qb + (size_t)c*128 + h*16);
  short8 q0 = qp[0], q1 = qp[1];
  float s = 0.f;
  #pragma unroll
  for (int i = 0; i < 8; ++i){
    s += bf2f((ushort)q0[i]) * kf[i];
    s += bf2f((ushort)q1[i]) * kf[8+i];
  }
  return s * 0.25f;   // 1/sqrt(16)
}

// ---------- fused segmented softmax over row-CSR, 3-pass (1 exp/edge) ----------
// scores in an 8-slot register ring (deg <= 64; Poisson(16) => ~always);
// deg > 64 tail recomputes. alpha written bf16 to col-CSR positions.
__global__ void row_softmax_kernel(const ushort* __restrict__ qb, const ushort* __restrict__ kb,
                                   const int* __restrict__ rptr, const int* __restrict__ rcol,
                                   const int* __restrict__ cposr,
                                   ushort* __restrict__ cbuf, int n){
  int wid = threadIdx.x >> 6, lane = threadIdx.x & 63;
  int r = blockIdx.x * (blockDim.x >> 6) + wid;
  if (r >= n) return;
  int lo = rptr[r], hi = rptr[r+1];
  if (lo >= hi) return;
  int h = lane & 7, el = lane >> 3;

  float kf[16];
  {
    const short8* kp = (const short8*)(kb + (size_t)r*128 + h*16);
    short8 k0 = kp[0], k1 = kp[1];
    #pragma unroll
    for (int i = 0; i < 8; ++i){
      kf[i]   = bf2f((ushort)k0[i]);
      kf[8+i] = bf2f((ushort)k1[i]);
    }
  }

  // pass 1: scores + max only (loads independent -> deep MLP)
  float sreg[8];
  float m = -1e30f;
  #pragma unroll
  for (int ts = 0; ts < 8; ++ts){
    int j = lo + el + ts*8;
    float s = (j < hi) ? qdot16(qb, rcol[j], h, kf) : -1e30f;
    sreg[ts] = s;
    m = fmaxf(m, s);
  }
  for (int j = lo + el + 64; j < hi; j += 8)      // deg>64 tail
    m = fmaxf(m, qdot16(qb, rcol[j], h, kf));
  #pragma unroll
  for (int o = 8; o < 64; o <<= 1) m = fmaxf(m, __shfl_xor(m, o));

  // pass 2: one exp per edge, stored in-place
  float d = 0.f;
  #pragma unroll
  for (int ts = 0; ts < 8; ++ts){
    int j = lo + el + ts*8;
    if (j < hi){ float e = __expf(sreg[ts] - m); sreg[ts] = e; d += e; }
  }
  for (int j = lo + el + 64; j < hi; j += 8)
    d += __expf(qdot16(qb, rcol[j], h, kf) - m);
  #pragma unroll
  for (int o = 8; o < 64; o <<= 1) d += __shfl_xor(d, o);
  float invd = 1.0f / d;

  // pass 3: scaled write to col-CSR positions
  #pragma unroll
  for (int ts = 0; ts < 8; ++ts){
    int j = lo + el + ts*8;
    if (j < hi) cbuf[(size_t)cposr[j]*8 + h] = f2bf(sreg[ts] * invd);
  }
  for (int j = lo + el + 64; j < hi; j += 8){
    float s = qdot16(qb, rcol[j], h, kf);
    cbuf[(size_t)cposr[j]*8 + h] = f2bf(__expf(s - m) * invd);
  }
}

// ---------- gather aggregation over col-CSR -> bf16 agg ----------
// eight 8-lane groups process alternate edges (8 chains in flight);
// lane l8 covers dims [l8*16, l8*16+16) == head l8 exactly (HD=16).
__global__ void agg_kernel(const ushort* __restrict__ vb, const ushort* __restrict__ cbuf,
                           const int* __restrict__ cptr, const int* __restrict__ crow,
                           ushort* __restrict__ aggb, int n){
  int wid = threadIdx.x >> 6, lane = threadIdx.x & 63;
  int node = blockIdx.x * (blockDim.x >> 6) + wid;
  if (node >= n) return;
  int lo = cptr[node], hi = cptr[node+1];
  int oct = lane >> 3, l8 = lane & 7;
  float acc[16] = {};
  for (int j = lo + oct; j < hi; j += 8){
    float a = bf2f(cbuf[(size_t)j*8 + l8]);
    int row = crow[j];
    const short8* vp = (const short8*)(vb + (size_t)row*128 + l8*16);
    short8 v0 = vp[0], v1 = vp[1];
    #pragma unroll
    for (int i = 0; i < 8; ++i){
      acc[i]   = fmaf(a, bf2f((ushort)v0[i]), acc[i]);
      acc[8+i] = fmaf(a, bf2f((ushort)v1[i]), acc[8+i]);
    }
  }
  #pragma unroll
  for (int i = 0; i < 16; ++i){
    acc[i] += __shfl_xor(acc[i], 8);
    acc[i] += __shfl_xor(acc[i], 16);
    acc[i] += __shfl_xor(acc[i], 32);
  }
  if (oct == 0){
    short8 o0, o1;
    #pragma unroll
    for (int i = 0; i < 8; ++i){ o0[i] = (short)f2bf(acc[i]); o1[i] = (short)f2bf(acc[8+i]); }
    short8* op = (short8*)(aggb + (size_t)node*128 + l8*16);
    op[0] = o0; op[1] = o1;
  }
}

extern "C" void kernel_launch(void* const* d_in, const int* in_sizes, int n_in,
                              void* d_out, int out_size, void* d_ws, size_t ws_size,
                              hipStream_t stream){
  const float* feats = (const float*)d_in[0];
  const int*   ei    = (const int*)  d_in[1];
  const float* Wq = (const float*)d_in[2];
  const float* bq = (const float*)d_in[3];
  const float* Wk = (const float*)d_in[4];
  const float* bk = (const float*)d_in[5];
  const float* Wv = (const float*)d_in[6];
  const float* bv = (const float*)d_in[7];
  const float* Wo = (const float*)d_in[8];
  const float* bo = (const float*)d_in[9];
  const float* ln1w = (const float*)d_in[10];
  const float* ln1b = (const float*)d_in[11];
  const float* ln2w = (const float*)d_in[12];
  const float* ln2b = (const float*)d_in[13];
  const float* W1 = (const float*)d_in[14];
  const float* b1 = (const float*)d_in[15];
  const float* W2 = (const float*)d_in[16];
  const float* b2 = (const float*)d_in[17];
  float* outp = (float*)d_out;

  int n = in_sizes[0] / 128;      // 50000 nodes
  int E = in_sizes[1] / 2;        // 800000 edges
  int nw = (n + 1) >> 1;          // packed u16 words per full histogram
  int chunk = (E + NBCH - 1) / NBCH;
  int nsb = (((n + NSEG - 1) / NSEG) + 1) & ~1;   // bins per segment (even)

  const size_t ND  = (size_t)n * 128;
  const size_t ND2 = ND / 2;
  const size_t EH  = (size_t)E * H_HEADS;

  float* ws = (float*)d_ws;
  ushort* x2b  = (ushort*)ws;                      // ND bf16
  ushort* qb   = (ushort*)(ws + ND2);
  ushort* kb   = (ushort*)(ws + 2*ND2);
  ushort* vb   = (ushort*)(ws + 3*ND2);
  ushort* cbuf = (ushort*)(ws + 4*ND2);            // EH bf16 (alpha, col order)
  ushort* aggb = (ushort*)(ws + 4*ND2 + EH/2);     // ND bf16
  int* crow    = (int*)(ws + 5*ND2 + EH/2);
  int* cposr   = crow + E;
  int* rcol    = cposr + E;
  int* pose    = rcol + E;
  int* rptr    = pose + E;
  int* cptr    = rptr + (n + 4);
  int* cnt2    = cptr + (n + 4);                   // [2][n]
  int* choff   = cnt2 + 2*n;                       // [2][NBCH][n]
  unsigned* copies = (unsigned*)(choff + (size_t)2*NBCH*n);  // [2][NBCH][nw]
  int* partial = (int*)(copies + (size_t)2*NBCH*nw);         // 2*nb ints
  ushort* wbuf = (ushort*)(partial + 512);
  ushort* Wqb = wbuf;                              // Wq,Wk,Wv contiguous for qkv
  ushort* Wkb = Wqb + 16384;
  ushort* Wvb = Wkb + 16384;
  ushort* Wob = Wvb + 16384;
  ushort* W1b = Wob + 16384;
  ushort* W2b = W1b + 65536;
  ushort* h1  = qb;                                // n*512 bf16 == qb..cbuf

  // weight conversion (independent)
  CvtArgs ca;
  ca.s[0]=Wq; ca.s[1]=Wk; ca.s[2]=Wv; ca.s[3]=Wo; ca.s[4]=W1; ca.s[5]=W2;
  ca.d[0]=Wqb; ca.d[1]=Wkb; ca.d[2]=Wvb; ca.d[3]=Wob; ca.d[4]=W1b; ca.d[5]=W2b;
  ca.cnt[0]=ca.cnt[1]=ca.cnt[2]=ca.cnt[3]=16384; ca.cnt[4]=ca.cnt[5]=65536;
  cvt6_kernel<<<dim3(65536/256, 6), 256, 0, stream>>>(ca);

  // atomic-free CSR build (bin-segmented LDS histograms, merged row+col pass)
  int nb = (n + 1023)/1024;
  hist_seg2 <<<dim3(NBCH,NSEG), 256, 0, stream>>>(ei, copies, E, n, nw, chunk, nsb);
  scan_fold <<<dim3((n+255)/256,2), 256, 0, stream>>>(copies, cnt2, choff, n, nw);
  scan_reduce <<<dim3(nb,2), 256, 0, stream>>>(cnt2, partial, n, nb);
  scan_mid    <<<dim3(1,2),  256, 0, stream>>>(partial, nb, rptr, cptr, n);
  scan_scatter<<<dim3(nb,2), 256, 0, stream>>>(cnt2, partial, rptr, cptr, n, nb);
  fill_r_seg<<<dim3(NBCH,NSEG), 256, 0, stream>>>(ei, rptr, choff,                  rcol, pose, E, n, chunk, nsb);
  fill_c_seg<<<dim3(NBCH,NSEG), 256, 0, stream>>>(ei, cptr, choff + (size_t)NBCH*n, pose, crow, cposr, E, n, chunk, nsb);

  // LN1 -> bf16
  ln_kernel<<<(n+3)/4, 256, 0, stream>>>(feats, ln1w, ln1b, x2b, n);

  // fused QKV projections (LDS-staged bf16 MFMA, bf16 out)
  int gm = (n + 63)/64;
  qkv_lds<<<dim3(gm,3), 256, 0, stream>>>(x2b, Wqb, bq, bk, bv, qb, kb, vb, n);

  // fused segmented softmax (3-pass, register ring), alpha bf16 -> col-CSR order
  row_softmax_kernel<<<(n+3)/4, 256, 0, stream>>>(qb, kb, rptr, rcol, cposr, cbuf, n);

  // gather aggregation (8 chains in flight) -> bf16
  agg_kernel<<<(n+3)/4, 256, 0, stream>>>(vb, cbuf, cptr, crow, aggb, n);

  // attention out projection + residual -> d_out (f32)
  gemm_lds<128,0,1,0><<<dim3(gm,1), 256, 0, stream>>>(aggb, Wob, bo, feats, outp, n, 128);

  // LN2 -> bf16
  ln_kernel<<<(n+3)/4, 256, 0, stream>>>(outp, ln2w, ln2b, x2b, n);

  // FFN
  gemm_lds<128,1,0,1><<<dim3(gm,4), 256, 0, stream>>>(x2b, W1b, b1, nullptr, h1,  n, 512);
  gemm_lds<512,1,1,0><<<dim3(gm,1), 256, 0, stream>>>(h1,  W2b, b2, outp,    outp, n, 128);
}

// Round 14
// 305.242 us; speedup vs baseline: 2.5848x; 1.0314x over previous
//
#include <hip/hip_runtime.h>
#include <hip/hip_bf16.h>
#include <math.h>

#define H_HEADS 8
constexpr float LN_EPS = 1e-5f;
constexpr int NBCH = 64;          // CSR build chunks (chunk <= 65535 for u16 counters)
constexpr int NSEG = 4;           // bin segments per chunk

using short8 = __attribute__((ext_vector_type(8))) short;
using f32x4  = __attribute__((ext_vector_type(4))) float;
using half2v = __attribute__((ext_vector_type(2))) _Float16;

#if defined(__has_builtin)
#  if __has_builtin(__builtin_amdgcn_fdot2)
#    define HAS_FDOT2 1
#  endif
#endif
#ifndef HAS_FDOT2
#  define HAS_FDOT2 0
#endif

__device__ __forceinline__ ushort f2bf(float v){
  __hip_bfloat16 h = __float2bfloat16(v);
  return *reinterpret_cast<ushort*>(&h);
}
__device__ __forceinline__ float bf2f(ushort u){
  return __uint_as_float(((unsigned)u) << 16);
}

// async global->LDS, 16B per lane; dest = wave-uniform base + lane*16
__device__ __forceinline__ void stage16(const ushort* g, ushort* l){
  __builtin_amdgcn_global_load_lds((const __attribute__((address_space(1))) unsigned*)g,
                                   (__attribute__((address_space(3))) unsigned*)l,
                                   16, 0, 0);
}

// ---------- LayerNorm (ddof=1), f32 in -> bf16 out, one wave per row ----------
__global__ void ln_kernel(const float* __restrict__ x, const float* __restrict__ w,
                          const float* __restrict__ b, ushort* __restrict__ out, int nrows){
  int wid = threadIdx.x >> 6, lane = threadIdx.x & 63;
  int r = blockIdx.x * (blockDim.x >> 6) + wid;
  if (r >= nrows) return;
  float2 v = ((const float2*)(x + (size_t)r*128))[lane];
  float s = v.x + v.y;
  #pragma unroll
  for (int o = 32; o; o >>= 1) s += __shfl_xor(s, o);
  float mu = s * (1.0f/128.0f);
  float d0 = v.x - mu, d1 = v.y - mu;
  float ss = d0*d0 + d1*d1;
  #pragma unroll
  for (int o = 32; o; o >>= 1) ss += __shfl_xor(ss, o);
  float sd = sqrtf(ss * (1.0f/127.0f));
  float inv = 1.0f / (sd + LN_EPS);
  float2 wv = ((const float2*)w)[lane];
  float2 bv = ((const float2*)b)[lane];
  ushort2 o2 = { f2bf(d0*inv*wv.x + bv.x), f2bf(d1*inv*wv.y + bv.y) };
  ((ushort2*)(out + (size_t)r*128))[lane] = o2;
}

// ---------- weight f32 -> bf16 conversion (all 6 in one launch) ----------
struct CvtArgs { const float* s[6]; ushort* d[6]; int cnt[6]; };
__global__ void cvt6_kernel(CvtArgs a){
  int w = blockIdx.y;
  int i = blockIdx.x*blockDim.x + threadIdx.x;
  if (i < a.cnt[w]) a.d[w][i] = f2bf(a.s[w][i]);
}

// ---------- LDS-staged bf16 MFMA GEMM ----------
// OUTMODE: 0 = f32, 1 = bf16, 2 = fp16
template<int K, int RELU, int RESID, int OUTMODE>
__device__ __forceinline__ void gemm_lds_body(
    const ushort* __restrict__ A, const ushort* __restrict__ W,
    const float* __restrict__ bias, const float* __restrict__ resid,
    void* __restrict__ out, int M, int Nout, int cb, ushort* Wl){
  constexpr int NCH = K / 128;
  int t = threadIdx.x;
  int wid = t >> 6, lane = t & 63;
  int mb = blockIdx.x * 64 + wid * 16;
  int lrow = lane & 15, kgrp = lane >> 4;
  int row = mb + lrow;
  bool rowok = row < M;
  const ushort* arow = A + (size_t)(rowok ? row : (M-1)) * K + kgrp*8;

  f32x4 acc[8] = {};
  short8 af[2][4];

  #pragma unroll
  for (int p = 0; p < 8; ++p){
    int L = p*256 + t;
    int colp = L >> 4, sp = L & 15;
    stage16(W + (size_t)colp*K + ((sp ^ (colp & 7)) << 3),
            (ushort*)((char*)Wl + ((size_t)(p*256 + (t & ~63)))*16));
  }
  #pragma unroll
  for (int kk = 0; kk < 4; ++kk)
    af[0][kk] = *(const short8*)(arow + kk*32);

  #pragma unroll
  for (int ci = 0; ci < NCH; ++ci){
    __syncthreads();
    int cur = ci & 1;
    if (ci + 1 < NCH){
      #pragma unroll
      for (int kk = 0; kk < 4; ++kk)
        af[cur^1][kk] = *(const short8*)(arow + (ci+1)*128 + kk*32);
    }
    #pragma unroll
    for (int kk = 0; kk < 4; ++kk){
      #pragma unroll
      for (int nt = 0; nt < 8; ++nt){
        int colc = nt*16 + lrow;
        int g = kk*4 + kgrp;
        short8 bfv = *(const short8*)((const char*)Wl + colc*256 + ((g ^ (colc & 7))*16));
        acc[nt] = __builtin_amdgcn_mfma_f32_16x16x32_bf16(af[cur][kk], bfv, acc[nt], 0, 0, 0);
      }
    }
    if (ci + 1 < NCH){
      __syncthreads();
      const ushort* Wc = W + (ci+1)*128;
      #pragma unroll
      for (int p = 0; p < 8; ++p){
        int L = p*256 + t;
        int colp = L >> 4, sp = L & 15;
        stage16(Wc + (size_t)colp*K + ((sp ^ (colp & 7)) << 3),
                (ushort*)((char*)Wl + ((size_t)(p*256 + (t & ~63)))*16));
      }
    }
  }

  int r0 = mb + kgrp*4;
  #pragma unroll
  for (int nt = 0; nt < 8; ++nt){
    int c = cb + nt*16 + lrow;
    float bsum = bias[c];
    #pragma unroll
    for (int i = 0; i < 4; ++i){
      int r = r0 + i;
      if (r >= M) continue;
      float v = acc[nt][i] + bsum;
      if (RELU)  v = fmaxf(v, 0.0f);
      if (RESID) v += resid[(size_t)r*Nout + c];
      if (OUTMODE == 1) ((ushort*)out)[(size_t)r*Nout + c] = f2bf(v);
      else if (OUTMODE == 2){
        _Float16 hv = (_Float16)v;
        ((ushort*)out)[(size_t)r*Nout + c] = __builtin_bit_cast(ushort, hv);
      } else ((float*)out)[(size_t)r*Nout + c] = v;
    }
  }
}

template<int K, int RELU, int RESID, int OUTMODE>
__global__ __launch_bounds__(256) void gemm_lds(
    const ushort* __restrict__ A, const ushort* __restrict__ Wfull,
    const float* __restrict__ bias, const float* __restrict__ resid,
    void* __restrict__ out, int M, int Nout){
  __shared__ __align__(16) ushort Wl[16384];
  int cb = blockIdx.y * 128;
  gemm_lds_body<K,RELU,RESID,OUTMODE>(A, Wfull + (size_t)cb*K, bias, resid, out, M, Nout, cb, Wl);
}

// q,k -> fp16 (OUTMODE 2); v -> bf16 (OUTMODE 1, feeds MFMA later)
__global__ __launch_bounds__(256) void qkv_lds(
    const ushort* __restrict__ A, const ushort* __restrict__ Wcat,
    const float* __restrict__ bq, const float* __restrict__ bk, const float* __restrict__ bv,
    ushort* __restrict__ qb, ushort* __restrict__ kb, ushort* __restrict__ vb, int M){
  __shared__ __align__(16) ushort Wl[16384];
  int y = blockIdx.y;
  const float* bias = (y==0) ? bq : (y==1) ? bk : bv;
  ushort* out = (y==0) ? qb : (y==1) ? kb : vb;
  if (y == 2)
    gemm_lds_body<128,0,0,1>(A, Wcat + (size_t)y*16384, bias, nullptr, out, M, 128, 0, Wl);
  else
    gemm_lds_body<128,0,0,2>(A, Wcat + (size_t)y*16384, bias, nullptr, out, M, 128, 0, Wl);
}

// ---------- CSR build, atomic-free, bin-segmented ----------
// merged row+col histograms: one chunk pass updates both (2 x ~6250 words, 50KB LDS)
__global__ __launch_bounds__(256) void hist_seg2(const int* __restrict__ ei,
    unsigned* __restrict__ copies, int E, int n, int nw, int chunk, int nsb){
  __shared__ unsigned hh[12544];
  int b = blockIdx.x, s = blockIdx.y, t = threadIdx.x;
  int bin0 = s * nsb;
  int bin1 = min(bin0 + nsb, n);
  int words = (bin1 - bin0 + 1) >> 1;
  for (int i = t; i < 2*words; i += 256) hh[i] = 0;
  __syncthreads();
  int lo = b*chunk, hi = min(lo + chunk, E);
  for (int e = lo + t; e < hi; e += 256){
    int2 rc = ((const int2*)ei)[e];
    if (rc.x >= bin0 && rc.x < bin1)
      atomicAdd(&hh[(rc.x - bin0) >> 1], 1u << ((rc.x & 1)*16));
    if (rc.y >= bin0 && rc.y < bin1)
      atomicAdd(&hh[words + ((rc.y - bin0) >> 1)], 1u << ((rc.y & 1)*16));
  }
  __syncthreads();
  unsigned* d0 = copies + (size_t)b*nw + (bin0 >> 1);
  unsigned* d1 = copies + (size_t)(NBCH + b)*nw + (bin0 >> 1);
  for (int i = t; i < words; i += 256){ d0[i] = hh[i]; d1[i] = hh[words + i]; }
}

// fold copies: cnt[y][bin] total + per-chunk exclusive offsets (u16) choff[y][b][bin]
__global__ __launch_bounds__(256) void scan_fold(const unsigned* __restrict__ copies,
    int* __restrict__ cnt2, ushort* __restrict__ choff, int n, int nw){
  int y = blockIdx.y;
  int bin = blockIdx.x*256 + threadIdx.x;
  if (bin >= n) return;
  const unsigned* cp = copies + (size_t)y*NBCH*nw + (bin >> 1);
  int sh = (bin & 1)*16;
  int run = 0;
  for (int b = 0; b < NBCH; ++b){
    int c = (int)((cp[(size_t)b*nw] >> sh) & 0xffffu);
    choff[((size_t)y*NBCH + b)*n + bin] = (ushort)run;
    run += c;
  }
  cnt2[(size_t)y*n + bin] = run;
}

// ---------- parallel 3-phase exclusive scan over cnt2 (both arrays, gridDim.y=2) ----------
__global__ __launch_bounds__(256) void scan_reduce(const int* __restrict__ cnt0,
                                                   int* __restrict__ partial, int n, int nb){
  const int* cnt = cnt0 + (size_t)blockIdx.y * n;
  int t = threadIdx.x;
  int base = blockIdx.x*1024 + t*4;
  int s = 0;
  #pragma unroll
  for (int j = 0; j < 4; ++j){ int i = base+j; if (i < n) s += cnt[i]; }
  __shared__ int sm[256];
  sm[t] = s; __syncthreads();
  for (int off = 128; off; off >>= 1){
    if (t < off) sm[t] += sm[t+off];
    __syncthreads();
  }
  if (t == 0) partial[blockIdx.y*nb + blockIdx.x] = sm[0];
}

__global__ __launch_bounds__(256) void scan_mid(int* __restrict__ partial, int nb,
                                                int* __restrict__ rptr, int* __restrict__ cptr, int n){
  int y = blockIdx.y;
  int* p = partial + y*nb;
  int t = threadIdx.x;
  __shared__ int sm[256];
  sm[t] = (t < nb) ? p[t] : 0;
  __syncthreads();
  for (int off = 1; off < 256; off <<= 1){
    int v = (t >= off) ? sm[t-off] : 0;
    __syncthreads();
    sm[t] += v;
    __syncthreads();
  }
  if (t < nb) p[t] = (t == 0) ? 0 : sm[t-1];
  if (t == 0) (y ? cptr : rptr)[n] = sm[255];
}

__global__ __launch_bounds__(256) void scan_scatter(const int* __restrict__ cnt0,
                                                    const int* __restrict__ partial,
                                                    int* __restrict__ rptr, int* __restrict__ cptr,
                                                    int n, int nb){
  int y = blockIdx.y;
  const int* cnt = cnt0 + (size_t)y * n;
  int* ptr = y ? cptr : rptr;
  int t = threadIdx.x;
  int base = blockIdx.x*1024 + t*4;
  int v[4]; int s = 0;
  #pragma unroll
  for (int j = 0; j < 4; ++j){ int i = base+j; v[j] = (i<n)?cnt[i]:0; s += v[j]; }
  __shared__ int sm[256];
  sm[t] = s; __syncthreads();
  for (int off = 1; off < 256; off <<= 1){
    int x = (t >= off) ? sm[t-off] : 0;
    __syncthreads();
    sm[t] += x;
    __syncthreads();
  }
  int pre = partial[y*nb + blockIdx.x] + ((t==0)?0:sm[t-1]);
  #pragma unroll
  for (int j = 0; j < 4; ++j){
    int i = base+j;
    if (i < n){ ptr[i] = pre; pre += v[j]; }
  }
}

// fill via in-chunk LDS rank within bin segment; no global atomics
__global__ __launch_bounds__(256) void fill_r_seg(const int* __restrict__ ei,
    const int* __restrict__ rptr, const ushort* __restrict__ choffR,
    int* __restrict__ rcol, int* __restrict__ pose, int E, int n, int chunk, int nsb){
  __shared__ unsigned hh[8192];
  int b = blockIdx.x, s = blockIdx.y, t = threadIdx.x;
  int bin0 = s * nsb;
  int bin1 = min(bin0 + nsb, n);
  int words = (bin1 - bin0 + 1) >> 1;
  for (int i = t; i < words; i += 256) hh[i] = 0;
  __syncthreads();
  const ushort* chb = choffR + (size_t)b*n;
  int lo = b*chunk, hi = min(lo + chunk, E);
  for (int e = lo + t; e < hi; e += 256){
    int2 rc = ((const int2*)ei)[e];
    int bin = rc.x;
    if (bin < bin0 || bin >= bin1) continue;
    int sh = (bin & 1)*16;
    unsigned old = atomicAdd(&hh[(bin - bin0) >> 1], 1u << sh);
    int rank = (int)((old >> sh) & 0xffffu);
    int pos = rptr[bin] + (int)chb[bin] + rank;
    rcol[pos] = rc.y;
    pose[e] = pos;
  }
}

__global__ __launch_bounds__(256) void fill_c_seg(const int* __restrict__ ei,
    const int* __restrict__ cptr, const ushort* __restrict__ choffC,
    const int* __restrict__ pose, int* __restrict__ crow, int* __restrict__ cposr,
    int E, int n, int chunk, int nsb){
  __shared__ unsigned hh[8192];
  int b = blockIdx.x, s = blockIdx.y, t = threadIdx.x;
  int bin0 = s * nsb;
  int bin1 = min(bin0 + nsb, n);
  int words = (bin1 - bin0 + 1) >> 1;
  for (int i = t; i < words; i += 256) hh[i] = 0;
  __syncthreads();
  const ushort* chb = choffC + (size_t)b*n;
  int lo = b*chunk, hi = min(lo + chunk, E);
  for (int e = lo + t; e < hi; e += 256){
    int2 rc = ((const int2*)ei)[e];
    int bin = rc.y;
    if (bin < bin0 || bin >= bin1) continue;
    int sh = (bin & 1)*16;
    unsigned old = atomicAdd(&hh[(bin - bin0) >> 1], 1u << sh);
    int rank = (int)((old >> sh) & 0xffffu);
    int pos = cptr[bin] + (int)chb[bin] + rank;
    crow[pos] = rc.x;
    cposr[pose[e]] = pos;
  }
}

// ---------- q.k dot for one head (16 dims), fp16 inputs ----------
__device__ __forceinline__ float qdot16h(const ushort* __restrict__ qb, int c, int h,
                                         const half2v* kf2){
  const int4* qp = (const int4*)(qb + (size_t)c*128 + h*16);
  int4 a = qp[0], b = qp[1];
  int qa[8] = {a.x, a.y, a.z, a.w, b.x, b.y, b.z, b.w};
  float s = 0.f;
#if HAS_FDOT2
  #pragma unroll
  for (int i = 0; i < 8; ++i)
    s = __builtin_amdgcn_fdot2(__builtin_bit_cast(half2v, qa[i]), kf2[i], s, false);
#else
  #pragma unroll
  for (int i = 0; i < 8; ++i){
    half2v q2 = __builtin_bit_cast(half2v, qa[i]);
    s += (float)q2.x * (float)kf2[i].x + (float)q2.y * (float)kf2[i].y;
  }
#endif
  return s * 0.25f;   // 1/sqrt(16)
}

// degree-templated softmax body: NS unroll slots (NS*8 edges capacity)
template<int NS>
__device__ __forceinline__ void softmax_rows(const ushort* __restrict__ qb,
    const int* __restrict__ rcol, const int* __restrict__ cposr,
    ushort* __restrict__ cbuf, const half2v* kf2, int lo, int hi, int h, int el){
  float sreg[NS];
  float m = -1e30f;
  #pragma unroll
  for (int ts = 0; ts < NS; ++ts){
    int j = lo + el + ts*8;
    float s = (j < hi) ? qdot16h(qb, rcol[j], h, kf2) : -1e30f;
    sreg[ts] = s;
    m = fmaxf(m, s);
  }
  if (NS == 8)
    for (int j = lo + el + 64; j < hi; j += 8)
      m = fmaxf(m, qdot16h(qb, rcol[j], h, kf2));
  #pragma unroll
  for (int o = 8; o < 64; o <<= 1) m = fmaxf(m, __shfl_xor(m, o));

  float d = 0.f;
  #pragma unroll
  for (int ts = 0; ts < NS; ++ts){
    int j = lo + el + ts*8;
    if (j < hi){ float e = __expf(sreg[ts] - m); sreg[ts] = e; d += e; }
  }
  if (NS == 8)
    for (int j = lo + el + 64; j < hi; j += 8)
      d += __expf(qdot16h(qb, rcol[j], h, kf2) - m);
  #pragma unroll
  for (int o = 8; o < 64; o <<= 1) d += __shfl_xor(d, o);
  float invd = 1.0f / d;

  #pragma unroll
  for (int ts = 0; ts < NS; ++ts){
    int j = lo + el + ts*8;
    if (j < hi) cbuf[(size_t)cposr[j]*8 + h] = f2bf(sreg[ts] * invd);
  }
  if (NS == 8)
    for (int j = lo + el + 64; j < hi; j += 8){
      float s = qdot16h(qb, rcol[j], h, kf2);
      cbuf[(size_t)cposr[j]*8 + h] = f2bf(__expf(s - m) * invd);
    }
}

// ---------- fused segmented softmax over row-CSR (fp16 q/k, degree-branched) ----------
__global__ void row_softmax_kernel(const ushort* __restrict__ qb, const ushort* __restrict__ kb,
                                   const int* __restrict__ rptr, const int* __restrict__ rcol,
                                   const int* __restrict__ cposr,
                                   ushort* __restrict__ cbuf, int n){
  int wid = threadIdx.x >> 6, lane = threadIdx.x & 63;
  int r = blockIdx.x * (blockDim.x >> 6) + wid;
  if (r >= n) return;
  int lo = rptr[r], hi = rptr[r+1];
  if (lo >= hi) return;
  int h = lane & 7, el = lane >> 3;

  half2v kf2[8];
  {
    const int4* kp = (const int4*)(kb + (size_t)r*128 + h*16);
    int4 k0 = kp[0], k1 = kp[1];
    kf2[0] = __builtin_bit_cast(half2v, k0.x);
    kf2[1] = __builtin_bit_cast(half2v, k0.y);
    kf2[2] = __builtin_bit_cast(half2v, k0.z);
    kf2[3] = __builtin_bit_cast(half2v, k0.w);
    kf2[4] = __builtin_bit_cast(half2v, k1.x);
    kf2[5] = __builtin_bit_cast(half2v, k1.y);
    kf2[6] = __builtin_bit_cast(half2v, k1.z);
    kf2[7] = __builtin_bit_cast(half2v, k1.w);
  }

  int deg = hi - lo;   // wave-uniform
  if (deg <= 16)      softmax_rows<2>(qb, rcol, cposr, cbuf, kf2, lo, hi, h, el);
  else if (deg <= 32) softmax_rows<4>(qb, rcol, cposr, cbuf, kf2, lo, hi, h, el);
  else                softmax_rows<8>(qb, rcol, cposr, cbuf, kf2, lo, hi, h, el);
}

// ---------- gather aggregation over col-CSR -> bf16 agg ----------
// eight 8-lane groups process alternate edges (8 chains in flight);
// lane l8 covers dims [l8*16, l8*16+16) == head l8 exactly (HD=16).
__global__ void agg_kernel(const ushort* __restrict__ vb, const ushort* __restrict__ cbuf,
                           const int* __restrict__ cptr, const int* __restrict__ crow,
                           ushort* __restrict__ aggb, int n){
  int wid = threadIdx.x >> 6, lane = threadIdx.x & 63;
  int node = blockIdx.x * (blockDim.x >> 6) + wid;
  if (node >= n) return;
  int lo = cptr[node], hi = cptr[node+1];
  int oct = lane >> 3, l8 = lane & 7;
  float acc[16] = {};
  for (int j = lo + oct; j < hi; j += 8){
    float a = bf2f(cbuf[(size_t)j*8 + l8]);
    int row = crow[j];
    const short8* vp = (const short8*)(vb + (size_t)row*128 + l8*16);
    short8 v0 = vp[0], v1 = vp[1];
    #pragma unroll
    for (int i = 0; i < 8; ++i){
      acc[i]   = fmaf(a, bf2f((ushort)v0[i]), acc[i]);
      acc[8+i] = fmaf(a, bf2f((ushort)v1[i]), acc[8+i]);
    }
  }
  #pragma unroll
  for (int i = 0; i < 16; ++i){
    acc[i] += __shfl_xor(acc[i], 8);
    acc[i] += __shfl_xor(acc[i], 16);
    acc[i] += __shfl_xor(acc[i], 32);
  }
  if (oct == 0){
    short8 o0, o1;
    #pragma unroll
    for (int i = 0; i < 8; ++i){ o0[i] = (short)f2bf(acc[i]); o1[i] = (short)f2bf(acc[8+i]); }
    short8* op = (short8*)(aggb + (size_t)node*128 + l8*16);
    op[0] = o0; op[1] = o1;
  }
}

extern "C" void kernel_launch(void* const* d_in, const int* in_sizes, int n_in,
                              void* d_out, int out_size, void* d_ws, size_t ws_size,
                              hipStream_t stream){
  const float* feats = (const float*)d_in[0];
  const int*   ei    = (const int*)  d_in[1];
  const float* Wq = (const float*)d_in[2];
  const float* bq = (const float*)d_in[3];
  const float* Wk = (const float*)d_in[4];
  const float* bk = (const float*)d_in[5];
  const float* Wv = (const float*)d_in[6];
  const float* bv = (const float*)d_in[7];
  const float* Wo = (const float*)d_in[8];
  const float* bo = (const float*)d_in[9];
  const float* ln1w = (const float*)d_in[10];
  const float* ln1b = (const float*)d_in[11];
  const float* ln2w = (const float*)d_in[12];
  const float* ln2b = (const float*)d_in[13];
  const float* W1 = (const float*)d_in[14];
  const float* b1 = (const float*)d_in[15];
  const float* W2 = (const float*)d_in[16];
  const float* b2 = (const float*)d_in[17];
  float* outp = (float*)d_out;

  int n = in_sizes[0] / 128;      // 50000 nodes
  int E = in_sizes[1] / 2;        // 800000 edges
  int nw = (n + 1) >> 1;          // packed u16 words per full histogram
  int chunk = (E + NBCH - 1) / NBCH;
  int nsb = (((n + NSEG - 1) / NSEG) + 1) & ~1;   // bins per segment (even)

  const size_t ND  = (size_t)n * 128;
  const size_t ND2 = ND / 2;
  const size_t EH  = (size_t)E * H_HEADS;

  float* ws = (float*)d_ws;
  ushort* x2b  = (ushort*)ws;                      // ND bf16
  ushort* qb   = (ushort*)(ws + ND2);              // ND fp16
  ushort* kb   = (ushort*)(ws + 2*ND2);            // ND fp16
  ushort* vb   = (ushort*)(ws + 3*ND2);            // ND bf16
  ushort* cbuf = (ushort*)(ws + 4*ND2);            // EH bf16 (alpha, col order)
  ushort* aggb = (ushort*)(ws + 4*ND2 + EH/2);     // ND bf16
  int* crow    = (int*)(ws + 5*ND2 + EH/2);
  int* cposr   = crow + E;
  int* rcol    = cposr + E;
  int* pose    = rcol + E;
  int* rptr    = pose + E;
  int* cptr    = rptr + (n + 4);
  int* cnt2    = cptr + (n + 4);                   // [2][n]
  ushort* choff = (ushort*)(cnt2 + 2*n);           // [2][NBCH][n] u16
  unsigned* copies = (unsigned*)(choff + (size_t)2*NBCH*n);  // [2][NBCH][nw]
  int* partial = (int*)(copies + (size_t)2*NBCH*nw);         // 2*nb ints
  ushort* wbuf = (ushort*)(partial + 512);
  ushort* Wqb = wbuf;                              // Wq,Wk,Wv contiguous for qkv
  ushort* Wkb = Wqb + 16384;
  ushort* Wvb = Wkb + 16384;
  ushort* Wob = Wvb + 16384;
  ushort* W1b = Wob + 16384;
  ushort* W2b = W1b + 65536;
  ushort* h1  = qb;                                // n*512 bf16 == qb..cbuf

  // weight conversion (independent)
  CvtArgs ca;
  ca.s[0]=Wq; ca.s[1]=Wk; ca.s[2]=Wv; ca.s[3]=Wo; ca.s[4]=W1; ca.s[5]=W2;
  ca.d[0]=Wqb; ca.d[1]=Wkb; ca.d[2]=Wvb; ca.d[3]=Wob; ca.d[4]=W1b; ca.d[5]=W2b;
  ca.cnt[0]=ca.cnt[1]=ca.cnt[2]=ca.cnt[3]=16384; ca.cnt[4]=ca.cnt[5]=65536;
  cvt6_kernel<<<dim3(65536/256, 6), 256, 0, stream>>>(ca);

  // atomic-free CSR build (bin-segmented LDS histograms, merged row+col pass)
  int nb = (n + 1023)/1024;
  hist_seg2 <<<dim3(NBCH,NSEG), 256, 0, stream>>>(ei, copies, E, n, nw, chunk, nsb);
  scan_fold <<<dim3((n+255)/256,2), 256, 0, stream>>>(copies, cnt2, choff, n, nw);
  scan_reduce <<<dim3(nb,2), 256, 0, stream>>>(cnt2, partial, n, nb);
  scan_mid    <<<dim3(1,2),  256, 0, stream>>>(partial, nb, rptr, cptr, n);
  scan_scatter<<<dim3(nb,2), 256, 0, stream>>>(cnt2, partial, rptr, cptr, n, nb);
  fill_r_seg<<<dim3(NBCH,NSEG), 256, 0, stream>>>(ei, rptr, choff,                  rcol, pose, E, n, chunk, nsb);
  fill_c_seg<<<dim3(NBCH,NSEG), 256, 0, stream>>>(ei, cptr, choff + (size_t)NBCH*n, pose, crow, cposr, E, n, chunk, nsb);

  // LN1 -> bf16
  ln_kernel<<<(n+3)/4, 256, 0, stream>>>(feats, ln1w, ln1b, x2b, n);

  // fused QKV projections (LDS-staged bf16 MFMA; q,k fp16 / v bf16 out)
  int gm = (n + 63)/64;
  qkv_lds<<<dim3(gm,3), 256, 0, stream>>>(x2b, Wqb, bq, bk, bv, qb, kb, vb, n);

  // fused segmented softmax (fp16 fdot2, degree-branched), alpha bf16 -> col-CSR order
  row_softmax_kernel<<<(n+3)/4, 256, 0, stream>>>(qb, kb, rptr, rcol, cposr, cbuf, n);

  // gather aggregation (8 chains in flight) -> bf16
  agg_kernel<<<(n+3)/4, 256, 0, stream>>>(vb, cbuf, cptr, crow, aggb, n);

  // attention out projection + residual -> d_out (f32)
  gemm_lds<128,0,1,0><<<dim3(gm,1), 256, 0, stream>>>(aggb, Wob, bo, feats, outp, n, 128);

  // LN2 -> bf16
  ln_kernel<<<(n+3)/4, 256, 0, stream>>>(outp, ln2w, ln2b, x2b, n);

  // FFN
  gemm_lds<128,1,0,1><<<dim3(gm,4), 256, 0, stream>>>(x2b, W1b, b1, nullptr, h1,  n, 512);
  gemm_lds<512,1,1,0><<<dim3(gm,1), 256, 0, stream>>>(h1,  W2b, b2, outp,    outp, n, 128);
}

// Round 16
// 284.292 us; speedup vs baseline: 2.7753x; 1.0737x over previous
//
#include <hip/hip_runtime.h>
#include <hip/hip_bf16.h>
#include <math.h>

#define H_HEADS 8
constexpr float LN_EPS = 1e-5f;
constexpr int NBCH = 64;          // CSR build chunks (chunk <= 65535 for u16 counters)
constexpr int NSEG = 4;           // bin segments per chunk

using short8 = __attribute__((ext_vector_type(8))) short;
using f32x4  = __attribute__((ext_vector_type(4))) float;
using half2v = __attribute__((ext_vector_type(2))) _Float16;

#if defined(__has_builtin)
#  if __has_builtin(__builtin_amdgcn_fdot2)
#    define HAS_FDOT2 1
#  endif
#endif
#ifndef HAS_FDOT2
#  define HAS_FDOT2 0
#endif

__device__ __forceinline__ ushort f2bf(float v){
  __hip_bfloat16 h = __float2bfloat16(v);
  return *reinterpret_cast<ushort*>(&h);
}
__device__ __forceinline__ float bf2f(ushort u){
  return __uint_as_float(((unsigned)u) << 16);
}

// async global->LDS, 16B per lane; dest = wave-uniform base + lane*16
__device__ __forceinline__ void stage16(const ushort* g, ushort* l){
  __builtin_amdgcn_global_load_lds((const __attribute__((address_space(1))) unsigned*)g,
                                   (__attribute__((address_space(3))) unsigned*)l,
                                   16, 0, 0);
}

// ---------- LayerNorm (ddof=1), f32 in -> bf16 out, one wave per row ----------
__global__ void ln_kernel(const float* __restrict__ x, const float* __restrict__ w,
                          const float* __restrict__ b, ushort* __restrict__ out, int nrows){
  int wid = threadIdx.x >> 6, lane = threadIdx.x & 63;
  int r = blockIdx.x * (blockDim.x >> 6) + wid;
  if (r >= nrows) return;
  float2 v = ((const float2*)(x + (size_t)r*128))[lane];
  float s = v.x + v.y;
  #pragma unroll
  for (int o = 32; o; o >>= 1) s += __shfl_xor(s, o);
  float mu = s * (1.0f/128.0f);
  float d0 = v.x - mu, d1 = v.y - mu;
  float ss = d0*d0 + d1*d1;
  #pragma unroll
  for (int o = 32; o; o >>= 1) ss += __shfl_xor(ss, o);
  float sd = sqrtf(ss * (1.0f/127.0f));
  float inv = 1.0f / (sd + LN_EPS);
  float2 wv = ((const float2*)w)[lane];
  float2 bv = ((const float2*)b)[lane];
  ushort2 o2 = { f2bf(d0*inv*wv.x + bv.x), f2bf(d1*inv*wv.y + bv.y) };
  ((ushort2*)(out + (size_t)r*128))[lane] = o2;
}

// ---------- weight f32 -> bf16 conversion (all 6 in one launch) ----------
struct CvtArgs { const float* s[6]; ushort* d[6]; int cnt[6]; };
__global__ void cvt6_kernel(CvtArgs a){
  int w = blockIdx.y;
  int i = blockIdx.x*blockDim.x + threadIdx.x;
  if (i < a.cnt[w]) a.d[w][i] = f2bf(a.s[w][i]);
}

// ---------- LDS-staged bf16 MFMA GEMM, 128-row blocks (8 waves / 512 thr) ----------
// OUTMODE: 0 = f32, 1 = bf16, 2 = fp16
// Staging is WAVE-UNIFORM (all threads) — compute/A-prefetch guarded by mb<M,
// never a barrier inside divergent code (round-15 bugfix).
template<int K, int RELU, int RESID, int OUTMODE>
__device__ __forceinline__ void gemm_lds_body(
    const ushort* __restrict__ A, const ushort* __restrict__ W,
    const float* __restrict__ bias, const float* __restrict__ resid,
    void* __restrict__ out, int M, int Nout, int cb, ushort* Wl){
  constexpr int NCH = K / 128;
  int t = threadIdx.x;
  int wid = t >> 6, lane = t & 63;
  int mb = blockIdx.x * 128 + wid * 16;
  int lrow = lane & 15, kgrp = lane >> 4;
  int row = mb + lrow;
  bool waveok = mb < M;
  bool rowok = row < M;
  const ushort* arow = A + (size_t)(rowok ? row : (M-1)) * K + kgrp*8;

  f32x4 acc[8] = {};
  short8 af[2][4];

  #pragma unroll
  for (int p = 0; p < 4; ++p){
    int L = p*512 + t;
    int colp = L >> 4, sp = L & 15;
    stage16(W + (size_t)colp*K + ((sp ^ (colp & 7)) << 3),
            (ushort*)((char*)Wl + ((size_t)(p*512 + (t & ~63)))*16));
  }
  if (waveok){
    #pragma unroll
    for (int kk = 0; kk < 4; ++kk)
      af[0][kk] = *(const short8*)(arow + kk*32);
  }

  #pragma unroll
  for (int ci = 0; ci < NCH; ++ci){
    __syncthreads();                       // chunk ci staged + A regs ready
    int cur = ci & 1;
    if (waveok){
      if (ci + 1 < NCH){                   // prefetch next A chunk under compute
        #pragma unroll
        for (int kk = 0; kk < 4; ++kk)
          af[cur^1][kk] = *(const short8*)(arow + (ci+1)*128 + kk*32);
      }
      #pragma unroll
      for (int kk = 0; kk < 4; ++kk){
        #pragma unroll
        for (int nt = 0; nt < 8; ++nt){
          int colc = nt*16 + lrow;
          int g = kk*4 + kgrp;
          short8 bfv = *(const short8*)((const char*)Wl + colc*256 + ((g ^ (colc & 7))*16));
          acc[nt] = __builtin_amdgcn_mfma_f32_16x16x32_bf16(af[cur][kk], bfv, acc[nt], 0, 0, 0);
        }
      }
    }
    if (ci + 1 < NCH){
      __syncthreads();                     // readers done; restage (ALL threads)
      const ushort* Wc = W + (ci+1)*128;
      #pragma unroll
      for (int p = 0; p < 4; ++p){
        int L = p*512 + t;
        int colp = L >> 4, sp = L & 15;
        stage16(Wc + (size_t)colp*K + ((sp ^ (colp & 7)) << 3),
                (ushort*)((char*)Wl + ((size_t)(p*512 + (t & ~63)))*16));
      }
    }
  }
  if (!waveok) return;

  int r0 = mb + kgrp*4;
  #pragma unroll
  for (int nt = 0; nt < 8; ++nt){
    int c = cb + nt*16 + lrow;
    float bsum = bias[c];
    #pragma unroll
    for (int i = 0; i < 4; ++i){
      int r = r0 + i;
      if (r >= M) continue;
      float v = acc[nt][i] + bsum;
      if (RELU)  v = fmaxf(v, 0.0f);
      if (RESID) v += resid[(size_t)r*Nout + c];
      if (OUTMODE == 1) ((ushort*)out)[(size_t)r*Nout + c] = f2bf(v);
      else if (OUTMODE == 2){
        _Float16 hv = (_Float16)v;
        ((ushort*)out)[(size_t)r*Nout + c] = __builtin_bit_cast(ushort, hv);
      } else ((float*)out)[(size_t)r*Nout + c] = v;
    }
  }
}

template<int K, int RELU, int RESID, int OUTMODE>
__global__ __launch_bounds__(512) void gemm_lds(
    const ushort* __restrict__ A, const ushort* __restrict__ Wfull,
    const float* __restrict__ bias, const float* __restrict__ resid,
    void* __restrict__ out, int M, int Nout){
  __shared__ __align__(16) ushort Wl[16384];
  int cb = blockIdx.y * 128;
  gemm_lds_body<K,RELU,RESID,OUTMODE>(A, Wfull + (size_t)cb*K, bias, resid, out, M, Nout, cb, Wl);
}

// q,k -> fp16 (OUTMODE 2); v -> bf16 (OUTMODE 1)
__global__ __launch_bounds__(512) void qkv_lds(
    const ushort* __restrict__ A, const ushort* __restrict__ Wcat,
    const float* __restrict__ bq, const float* __restrict__ bk, const float* __restrict__ bv,
    ushort* __restrict__ qb, ushort* __restrict__ kb, ushort* __restrict__ vb, int M){
  __shared__ __align__(16) ushort Wl[16384];
  int y = blockIdx.y;
  const float* bias = (y==0) ? bq : (y==1) ? bk : bv;
  ushort* out = (y==0) ? qb : (y==1) ? kb : vb;
  if (y == 2)
    gemm_lds_body<128,0,0,1>(A, Wcat + (size_t)y*16384, bias, nullptr, out, M, 128, 0, Wl);
  else
    gemm_lds_body<128,0,0,2>(A, Wcat + (size_t)y*16384, bias, nullptr, out, M, 128, 0, Wl);
}

// ---------- Wo GEMM + residual + fused LN2: outp (f32) and x2b (bf16) ----------
__global__ __launch_bounds__(512) void gemm_wo_ln2(
    const ushort* __restrict__ A, const ushort* __restrict__ W,
    const float* __restrict__ bias, const float* __restrict__ feats,
    const float* __restrict__ lnw, const float* __restrict__ lnb,
    float* __restrict__ outp, ushort* __restrict__ x2b, int M){
  constexpr int K = 128;
  __shared__ __align__(16) ushort Wl[16384];
  int t = threadIdx.x;
  int wid = t >> 6, lane = t & 63;
  int mb = blockIdx.x * 128 + wid * 16;
  int lrow = lane & 15, kgrp = lane >> 4;
  int row = mb + lrow;
  bool waveok = mb < M;
  bool rowok = row < M;
  const ushort* arow = A + (size_t)(rowok ? row : (M-1)) * K + kgrp*8;

  f32x4 acc[8] = {};
  short8 af[4];

  #pragma unroll
  for (int p = 0; p < 4; ++p){
    int L = p*512 + t;
    int colp = L >> 4, sp = L & 15;
    stage16(W + (size_t)colp*K + ((sp ^ (colp & 7)) << 3),
            (ushort*)((char*)Wl + ((size_t)(p*512 + (t & ~63)))*16));
  }
  if (waveok){
    #pragma unroll
    for (int kk = 0; kk < 4; ++kk)
      af[kk] = *(const short8*)(arow + kk*32);
  }
  __syncthreads();
  if (!waveok) return;

  #pragma unroll
  for (int kk = 0; kk < 4; ++kk){
    #pragma unroll
    for (int nt = 0; nt < 8; ++nt){
      int colc = nt*16 + lrow;
      int g = kk*4 + kgrp;
      short8 bfv = *(const short8*)((const char*)Wl + colc*256 + ((g ^ (colc & 7))*16));
      acc[nt] = __builtin_amdgcn_mfma_f32_16x16x32_bf16(af[kk], bfv, acc[nt], 0, 0, 0);
    }
  }

  // epilogue: v = acc + bias + feats; write outp; fused LN2 -> x2b
  int r0 = mb + kgrp*4;
  float vv[8][4];
  float lw[8], lb[8];
  #pragma unroll
  for (int nt = 0; nt < 8; ++nt){
    int c = nt*16 + lrow;
    float bsum = bias[c];
    lw[nt] = lnw[c]; lb[nt] = lnb[c];
    #pragma unroll
    for (int i = 0; i < 4; ++i){
      int r = r0 + i;
      float v = 0.f;
      if (r < M){
        v = acc[nt][i] + bsum + feats[(size_t)r*128 + c];
        outp[(size_t)r*128 + c] = v;
      }
      vv[nt][i] = v;
    }
  }
  #pragma unroll
  for (int i = 0; i < 4; ++i){
    int r = r0 + i;
    float s = 0.f;
    #pragma unroll
    for (int nt = 0; nt < 8; ++nt) s += vv[nt][i];
    #pragma unroll
    for (int o = 1; o < 16; o <<= 1) s += __shfl_xor(s, o);
    float mu = s * (1.0f/128.0f);
    float ss = 0.f;
    float d[8];
    #pragma unroll
    for (int nt = 0; nt < 8; ++nt){ d[nt] = vv[nt][i] - mu; ss += d[nt]*d[nt]; }
    #pragma unroll
    for (int o = 1; o < 16; o <<= 1) ss += __shfl_xor(ss, o);
    float sd = sqrtf(ss * (1.0f/127.0f));
    float inv = 1.0f / (sd + LN_EPS);
    if (r < M){
      #pragma unroll
      for (int nt = 0; nt < 8; ++nt){
        int c = nt*16 + lrow;
        x2b[(size_t)r*128 + c] = f2bf(d[nt]*inv*lw[nt] + lb[nt]);
      }
    }
  }
}

// ---------- CSR build, atomic-free, bin-segmented ----------
__global__ __launch_bounds__(256) void hist_seg2(const int* __restrict__ ei,
    unsigned* __restrict__ copies, int E, int n, int nw, int chunk, int nsb){
  __shared__ unsigned hh[12544];
  int b = blockIdx.x, s = blockIdx.y, t = threadIdx.x;
  int bin0 = s * nsb;
  int bin1 = min(bin0 + nsb, n);
  int words = (bin1 - bin0 + 1) >> 1;
  for (int i = t; i < 2*words; i += 256) hh[i] = 0;
  __syncthreads();
  int lo = b*chunk, hi = min(lo + chunk, E);
  for (int e = lo + t; e < hi; e += 256){
    int2 rc = ((const int2*)ei)[e];
    if (rc.x >= bin0 && rc.x < bin1)
      atomicAdd(&hh[(rc.x - bin0) >> 1], 1u << ((rc.x & 1)*16));
    if (rc.y >= bin0 && rc.y < bin1)
      atomicAdd(&hh[words + ((rc.y - bin0) >> 1)], 1u << ((rc.y & 1)*16));
  }
  __syncthreads();
  unsigned* d0 = copies + (size_t)b*nw + (bin0 >> 1);
  unsigned* d1 = copies + (size_t)(NBCH + b)*nw + (bin0 >> 1);
  for (int i = t; i < words; i += 256){ d0[i] = hh[i]; d1[i] = hh[words + i]; }
}

__global__ __launch_bounds__(256) void scan_fold(const unsigned* __restrict__ copies,
    int* __restrict__ cnt2, ushort* __restrict__ choff, int n, int nw){
  int y = blockIdx.y;
  int bin = blockIdx.x*256 + threadIdx.x;
  if (bin >= n) return;
  const unsigned* cp = copies + (size_t)y*NBCH*nw + (bin >> 1);
  int sh = (bin & 1)*16;
  int run = 0;
  for (int b = 0; b < NBCH; ++b){
    int c = (int)((cp[(size_t)b*nw] >> sh) & 0xffffu);
    choff[((size_t)y*NBCH + b)*n + bin] = (ushort)run;
    run += c;
  }
  cnt2[(size_t)y*n + bin] = run;
}

// ---------- parallel 3-phase exclusive scan over cnt2 (both arrays, gridDim.y=2) ----------
__global__ __launch_bounds__(256) void scan_reduce(const int* __restrict__ cnt0,
                                                   int* __restrict__ partial, int n, int nb){
  const int* cnt = cnt0 + (size_t)blockIdx.y * n;
  int t = threadIdx.x;
  int base = blockIdx.x*1024 + t*4;
  int s = 0;
  #pragma unroll
  for (int j = 0; j < 4; ++j){ int i = base+j; if (i < n) s += cnt[i]; }
  __shared__ int sm[256];
  sm[t] = s; __syncthreads();
  for (int off = 128; off; off >>= 1){
    if (t < off) sm[t] += sm[t+off];
    __syncthreads();
  }
  if (t == 0) partial[blockIdx.y*nb + blockIdx.x] = sm[0];
}

__global__ __launch_bounds__(256) void scan_mid(int* __restrict__ partial, int nb,
                                                int* __restrict__ rptr, int* __restrict__ cptr, int n){
  int y = blockIdx.y;
  int* p = partial + y*nb;
  int t = threadIdx.x;
  __shared__ int sm[256];
  sm[t] = (t < nb) ? p[t] : 0;
  __syncthreads();
  for (int off = 1; off < 256; off <<= 1){
    int v = (t >= off) ? sm[t-off] : 0;
    __syncthreads();
    sm[t] += v;
    __syncthreads();
  }
  if (t < nb) p[t] = (t == 0) ? 0 : sm[t-1];
  if (t == 0) (y ? cptr : rptr)[n] = sm[255];
}

__global__ __launch_bounds__(256) void scan_scatter(const int* __restrict__ cnt0,
                                                    const int* __restrict__ partial,
                                                    int* __restrict__ rptr, int* __restrict__ cptr,
                                                    int n, int nb){
  int y = blockIdx.y;
  const int* cnt = cnt0 + (size_t)y * n;
  int* ptr = y ? cptr : rptr;
  int t = threadIdx.x;
  int base = blockIdx.x*1024 + t*4;
  int v[4]; int s = 0;
  #pragma unroll
  for (int j = 0; j < 4; ++j){ int i = base+j; v[j] = (i<n)?cnt[i]:0; s += v[j]; }
  __shared__ int sm[256];
  sm[t] = s; __syncthreads();
  for (int off = 1; off < 256; off <<= 1){
    int x = (t >= off) ? sm[t-off] : 0;
    __syncthreads();
    sm[t] += x;
    __syncthreads();
  }
  int pre = partial[y*nb + blockIdx.x] + ((t==0)?0:sm[t-1]);
  #pragma unroll
  for (int j = 0; j < 4; ++j){
    int i = base+j;
    if (i < n){ ptr[i] = pre; pre += v[j]; }
  }
}

// fill via in-chunk LDS rank within bin segment; no global atomics
__global__ __launch_bounds__(256) void fill_r_seg(const int* __restrict__ ei,
    const int* __restrict__ rptr, const ushort* __restrict__ choffR,
    int* __restrict__ rcol, int* __restrict__ pose, int E, int n, int chunk, int nsb){
  __shared__ unsigned hh[8192];
  int b = blockIdx.x, s = blockIdx.y, t = threadIdx.x;
  int bin0 = s * nsb;
  int bin1 = min(bin0 + nsb, n);
  int words = (bin1 - bin0 + 1) >> 1;
  for (int i = t; i < words; i += 256) hh[i] = 0;
  __syncthreads();
  const ushort* chb = choffR + (size_t)b*n;
  int lo = b*chunk, hi = min(lo + chunk, E);
  for (int e = lo + t; e < hi; e += 256){
    int2 rc = ((const int2*)ei)[e];
    int bin = rc.x;
    if (bin < bin0 || bin >= bin1) continue;
    int sh = (bin & 1)*16;
    unsigned old = atomicAdd(&hh[(bin - bin0) >> 1], 1u << sh);
    int rank = (int)((old >> sh) & 0xffffu);
    int pos = rptr[bin] + (int)chb[bin] + rank;
    rcol[pos] = rc.y;
    pose[e] = pos;
  }
}

__global__ __launch_bounds__(256) void fill_c_seg(const int* __restrict__ ei,
    const int* __restrict__ cptr, const ushort* __restrict__ choffC,
    const int* __restrict__ pose, int* __restrict__ crow, int* __restrict__ cposr,
    int E, int n, int chunk, int nsb){
  __shared__ unsigned hh[8192];
  int b = blockIdx.x, s = blockIdx.y, t = threadIdx.x;
  int bin0 = s * nsb;
  int bin1 = min(bin0 + nsb, n);
  int words = (bin1 - bin0 + 1) >> 1;
  for (int i = t; i < words; i += 256) hh[i] = 0;
  __syncthreads();
  const ushort* chb = choffC + (size_t)b*n;
  int lo = b*chunk, hi = min(lo + chunk, E);
  for (int e = lo + t; e < hi; e += 256){
    int2 rc = ((const int2*)ei)[e];
    int bin = rc.y;
    if (bin < bin0 || bin >= bin1) continue;
    int sh = (bin & 1)*16;
    unsigned old = atomicAdd(&hh[(bin - bin0) >> 1], 1u << sh);
    int rank = (int)((old >> sh) & 0xffffu);
    int pos = cptr[bin] + (int)chb[bin] + rank;
    crow[pos] = rc.x;
    cposr[pose[e]] = pos;
  }
}

// ---------- q.k dot for one head (16 dims), fp16 inputs ----------
__device__ __forceinline__ float qdot16h(const ushort* __restrict__ qb, int c, int h,
                                         const half2v* kf2){
  const int4* qp = (const int4*)(qb + (size_t)c*128 + h*16);
  int4 a = qp[0], b = qp[1];
  int qa[8] = {a.x, a.y, a.z, a.w, b.x, b.y, b.z, b.w};
  float s = 0.f;
#if HAS_FDOT2
  #pragma unroll
  for (int i = 0; i < 8; ++i)
    s = __builtin_amdgcn_fdot2(__builtin_bit_cast(half2v, qa[i]), kf2[i], s, false);
#else
  #pragma unroll
  for (int i = 0; i < 8; ++i){
    half2v q2 = __builtin_bit_cast(half2v, qa[i]);
    s += (float)q2.x * (float)kf2[i].x + (float)q2.y * (float)kf2[i].y;
  }
#endif
  return s * 0.25f;   // 1/sqrt(16)
}

// degree-templated softmax body: NS unroll slots (NS*8 edges capacity)
template<int NS>
__device__ __forceinline__ void softmax_rows(const ushort* __restrict__ qb,
    const int* __restrict__ rcol, const int* __restrict__ cposr,
    ushort* __restrict__ cbuf, const half2v* kf2, int lo, int hi, int h, int el){
  float sreg[NS];
  float m = -1e30f;
  #pragma unroll
  for (int ts = 0; ts < NS; ++ts){
    int j = lo + el + ts*8;
    float s = (j < hi) ? qdot16h(qb, rcol[j], h, kf2) : -1e30f;
    sreg[ts] = s;
    m = fmaxf(m, s);
  }
  if (NS == 8)
    for (int j = lo + el + 64; j < hi; j += 8)
      m = fmaxf(m, qdot16h(qb, rcol[j], h, kf2));
  #pragma unroll
  for (int o = 8; o < 64; o <<= 1) m = fmaxf(m, __shfl_xor(m, o));

  float d = 0.f;
  #pragma unroll
  for (int ts = 0; ts < NS; ++ts){
    int j = lo + el + ts*8;
    if (j < hi){ float e = __expf(sreg[ts] - m); sreg[ts] = e; d += e; }
  }
  if (NS == 8)
    for (int j = lo + el + 64; j < hi; j += 8)
      d += __expf(qdot16h(qb, rcol[j], h, kf2) - m);
  #pragma unroll
  for (int o = 8; o < 64; o <<= 1) d += __shfl_xor(d, o);
  float invd = 1.0f / d;

  #pragma unroll
  for (int ts = 0; ts < NS; ++ts){
    int j = lo + el + ts*8;
    if (j < hi) cbuf[(size_t)cposr[j]*8 + h] = f2bf(sreg[ts] * invd);
  }
  if (NS == 8)
    for (int j = lo + el + 64; j < hi; j += 8){
      float s = qdot16h(qb, rcol[j], h, kf2);
      cbuf[(size_t)cposr[j]*8 + h] = f2bf(__expf(s - m) * invd);
    }
}

// ---------- fused segmented softmax over row-CSR (fp16 q/k, degree-branched) ----------
__global__ void row_softmax_kernel(const ushort* __restrict__ qb, const ushort* __restrict__ kb,
                                   const int* __restrict__ rptr, const int* __restrict__ rcol,
                                   const int* __restrict__ cposr,
                                   ushort* __restrict__ cbuf, int n){
  int wid = threadIdx.x >> 6, lane = threadIdx.x & 63;
  int r = blockIdx.x * (blockDim.x >> 6) + wid;
  if (r >= n) return;
  int lo = rptr[r], hi = rptr[r+1];
  if (lo >= hi) return;
  int h = lane & 7, el = lane >> 3;

  half2v kf2[8];
  {
    const int4* kp = (const int4*)(kb + (size_t)r*128 + h*16);
    int4 k0 = kp[0], k1 = kp[1];
    kf2[0] = __builtin_bit_cast(half2v, k0.x);
    kf2[1] = __builtin_bit_cast(half2v, k0.y);
    kf2[2] = __builtin_bit_cast(half2v, k0.z);
    kf2[3] = __builtin_bit_cast(half2v, k0.w);
    kf2[4] = __builtin_bit_cast(half2v, k1.x);
    kf2[5] = __builtin_bit_cast(half2v, k1.y);
    kf2[6] = __builtin_bit_cast(half2v, k1.z);
    kf2[7] = __builtin_bit_cast(half2v, k1.w);
  }

  int deg = hi - lo;   // wave-uniform
  if (deg <= 16)      softmax_rows<2>(qb, rcol, cposr, cbuf, kf2, lo, hi, h, el);
  else if (deg <= 32) softmax_rows<4>(qb, rcol, cposr, cbuf, kf2, lo, hi, h, el);
  else                softmax_rows<8>(qb, rcol, cposr, cbuf, kf2, lo, hi, h, el);
}

// ---------- gather aggregation over col-CSR -> bf16 agg ----------
__global__ void agg_kernel(const ushort* __restrict__ vb, const ushort* __restrict__ cbuf,
                           const int* __restrict__ cptr, const int* __restrict__ crow,
                           ushort* __restrict__ aggb, int n){
  int wid = threadIdx.x >> 6, lane = threadIdx.x & 63;
  int node = blockIdx.x * (blockDim.x >> 6) + wid;
  if (node >= n) return;
  int lo = cptr[node], hi = cptr[node+1];
  int oct = lane >> 3, l8 = lane & 7;
  float acc[16] = {};
  for (int j = lo + oct; j < hi; j += 8){
    float a = bf2f(cbuf[(size_t)j*8 + l8]);
    int row = crow[j];
    const short8* vp = (const short8*)(vb + (size_t)row*128 + l8*16);
    short8 v0 = vp[0], v1 = vp[1];
    #pragma unroll
    for (int i = 0; i < 8; ++i){
      acc[i]   = fmaf(a, bf2f((ushort)v0[i]), acc[i]);
      acc[8+i] = fmaf(a, bf2f((ushort)v1[i]), acc[8+i]);
    }
  }
  #pragma unroll
  for (int i = 0; i < 16; ++i){
    acc[i] += __shfl_xor(acc[i], 8);
    acc[i] += __shfl_xor(acc[i], 16);
    acc[i] += __shfl_xor(acc[i], 32);
  }
  if (oct == 0){
    short8 o0, o1;
    #pragma unroll
    for (int i = 0; i < 8; ++i){ o0[i] = (short)f2bf(acc[i]); o1[i] = (short)f2bf(acc[8+i]); }
    short8* op = (short8*)(aggb + (size_t)node*128 + l8*16);
    op[0] = o0; op[1] = o1;
  }
}

extern "C" void kernel_launch(void* const* d_in, const int* in_sizes, int n_in,
                              void* d_out, int out_size, void* d_ws, size_t ws_size,
                              hipStream_t stream){
  const float* feats = (const float*)d_in[0];
  const int*   ei    = (const int*)  d_in[1];
  const float* Wq = (const float*)d_in[2];
  const float* bq = (const float*)d_in[3];
  const float* Wk = (const float*)d_in[4];
  const float* bk = (const float*)d_in[5];
  const float* Wv = (const float*)d_in[6];
  const float* bv = (const float*)d_in[7];
  const float* Wo = (const float*)d_in[8];
  const float* bo = (const float*)d_in[9];
  const float* ln1w = (const float*)d_in[10];
  const float* ln1b = (const float*)d_in[11];
  const float* ln2w = (const float*)d_in[12];
  const float* ln2b = (const float*)d_in[13];
  const float* W1 = (const float*)d_in[14];
  const float* b1 = (const float*)d_in[15];
  const float* W2 = (const float*)d_in[16];
  const float* b2 = (const float*)d_in[17];
  float* outp = (float*)d_out;

  int n = in_sizes[0] / 128;      // 50000 nodes
  int E = in_sizes[1] / 2;        // 800000 edges
  int nw = (n + 1) >> 1;          // packed u16 words per full histogram
  int chunk = (E + NBCH - 1) / NBCH;
  int nsb = (((n + NSEG - 1) / NSEG) + 1) & ~1;   // bins per segment (even)

  const size_t ND  = (size_t)n * 128;
  const size_t ND2 = ND / 2;
  const size_t EH  = (size_t)E * H_HEADS;

  float* ws = (float*)d_ws;
  ushort* x2b  = (ushort*)ws;                      // ND bf16
  ushort* qb   = (ushort*)(ws + ND2);              // ND fp16
  ushort* kb   = (ushort*)(ws + 2*ND2);            // ND fp16
  ushort* vb   = (ushort*)(ws + 3*ND2);            // ND bf16
  ushort* cbuf = (ushort*)(ws + 4*ND2);            // EH bf16 (alpha, col order)
  ushort* aggb = (ushort*)(ws + 4*ND2 + EH/2);     // ND bf16
  int* crow    = (int*)(ws + 5*ND2 + EH/2);
  int* cposr   = crow + E;
  int* rcol    = cposr + E;
  int* pose    = rcol + E;
  int* rptr    = pose + E;
  int* cptr    = rptr + (n + 4);
  int* cnt2    = cptr + (n + 4);                   // [2][n]
  ushort* choff = (ushort*)(cnt2 + 2*n);           // [2][NBCH][n] u16
  unsigned* copies = (unsigned*)(choff + (size_t)2*NBCH*n);  // [2][NBCH][nw]
  int* partial = (int*)(copies + (size_t)2*NBCH*nw);         // 2*nb ints
  ushort* wbuf = (ushort*)(partial + 512);
  ushort* Wqb = wbuf;                              // Wq,Wk,Wv contiguous for qkv
  ushort* Wkb = Wqb + 16384;
  ushort* Wvb = Wkb + 16384;
  ushort* Wob = Wvb + 16384;
  ushort* W1b = Wob + 16384;
  ushort* W2b = W1b + 65536;
  ushort* h1  = qb;                                // n*512 bf16 == qb..cbuf

  // weight conversion (independent)
  CvtArgs ca;
  ca.s[0]=Wq; ca.s[1]=Wk; ca.s[2]=Wv; ca.s[3]=Wo; ca.s[4]=W1; ca.s[5]=W2;
  ca.d[0]=Wqb; ca.d[1]=Wkb; ca.d[2]=Wvb; ca.d[3]=Wob; ca.d[4]=W1b; ca.d[5]=W2b;
  ca.cnt[0]=ca.cnt[1]=ca.cnt[2]=ca.cnt[3]=16384; ca.cnt[4]=ca.cnt[5]=65536;
  cvt6_kernel<<<dim3(65536/256, 6), 256, 0, stream>>>(ca);

  // atomic-free CSR build (bin-segmented LDS histograms, merged row+col pass)
  int nb = (n + 1023)/1024;
  hist_seg2 <<<dim3(NBCH,NSEG), 256, 0, stream>>>(ei, copies, E, n, nw, chunk, nsb);
  scan_fold <<<dim3((n+255)/256,2), 256, 0, stream>>>(copies, cnt2, choff, n, nw);
  scan_reduce <<<dim3(nb,2), 256, 0, stream>>>(cnt2, partial, n, nb);
  scan_mid    <<<dim3(1,2),  256, 0, stream>>>(partial, nb, rptr, cptr, n);
  scan_scatter<<<dim3(nb,2), 256, 0, stream>>>(cnt2, partial, rptr, cptr, n, nb);
  fill_r_seg<<<dim3(NBCH,NSEG), 256, 0, stream>>>(ei, rptr, choff,                  rcol, pose, E, n, chunk, nsb);
  fill_c_seg<<<dim3(NBCH,NSEG), 256, 0, stream>>>(ei, cptr, choff + (size_t)NBCH*n, pose, crow, cposr, E, n, chunk, nsb);

  // LN1 -> bf16
  ln_kernel<<<(n+3)/4, 256, 0, stream>>>(feats, ln1w, ln1b, x2b, n);

  // fused QKV projections (128-row blocks; q,k fp16 / v bf16 out)
  int gm = (n + 127)/128;
  qkv_lds<<<dim3(gm,3), 512, 0, stream>>>(x2b, Wqb, bq, bk, bv, qb, kb, vb, n);

  // fused segmented softmax (fp16 fdot2, degree-branched), alpha bf16 -> col-CSR order
  row_softmax_kernel<<<(n+3)/4, 256, 0, stream>>>(qb, kb, rptr, rcol, cposr, cbuf, n);

  // gather aggregation (8 chains in flight) -> bf16
  agg_kernel<<<(n+3)/4, 256, 0, stream>>>(vb, cbuf, cptr, crow, aggb, n);

  // attention out projection + residual + fused LN2 -> outp (f32) + x2b (bf16)
  gemm_wo_ln2<<<gm, 512, 0, stream>>>(aggb, Wob, bo, feats, ln2w, ln2b, outp, x2b, n);

  // FFN
  gemm_lds<128,1,0,1><<<dim3(gm,4), 512, 0, stream>>>(x2b, W1b, b1, nullptr, h1,  n, 512);
  gemm_lds<512,1,1,0><<<dim3(gm,1), 512, 0, stream>>>(h1,  W2b, b2, outp,    outp, n, 128);
}

// Round 18
// 282.685 us; speedup vs baseline: 2.7910x; 1.0057x over previous
//
#include <hip/hip_runtime.h>
#include <hip/hip_bf16.h>
#include <math.h>

#define H_HEADS 8
constexpr float LN_EPS = 1e-5f;
constexpr int NBCH = 64;          // CSR build chunks (chunk <= 65535 for u16 counters)
constexpr int NSEG = 4;           // bin segments per chunk

using short8 = __attribute__((ext_vector_type(8))) short;
using f32x4  = __attribute__((ext_vector_type(4))) float;
using half2v = __attribute__((ext_vector_type(2))) _Float16;

#if defined(__has_builtin)
#  if __has_builtin(__builtin_amdgcn_fdot2)
#    define HAS_FDOT2 1
#  endif
#endif
#ifndef HAS_FDOT2
#  define HAS_FDOT2 0
#endif

__device__ __forceinline__ ushort f2bf(float v){
  __hip_bfloat16 h = __float2bfloat16(v);
  return *reinterpret_cast<ushort*>(&h);
}
__device__ __forceinline__ float bf2f(ushort u){
  return __uint_as_float(((unsigned)u) << 16);
}

// async global->LDS, 16B per lane; dest = wave-uniform base + lane*16
__device__ __forceinline__ void stage16(const ushort* g, ushort* l){
  __builtin_amdgcn_global_load_lds((const __attribute__((address_space(1))) unsigned*)g,
                                   (__attribute__((address_space(3))) unsigned*)l,
                                   16, 0, 0);
}

// ---------- LayerNorm (ddof=1), f32 in -> bf16 out, one wave per row ----------
__global__ void ln_kernel(const float* __restrict__ x, const float* __restrict__ w,
                          const float* __restrict__ b, ushort* __restrict__ out, int nrows){
  int wid = threadIdx.x >> 6, lane = threadIdx.x & 63;
  int r = blockIdx.x * (blockDim.x >> 6) + wid;
  if (r >= nrows) return;
  float2 v = ((const float2*)(x + (size_t)r*128))[lane];
  float s = v.x + v.y;
  #pragma unroll
  for (int o = 32; o; o >>= 1) s += __shfl_xor(s, o);
  float mu = s * (1.0f/128.0f);
  float d0 = v.x - mu, d1 = v.y - mu;
  float ss = d0*d0 + d1*d1;
  #pragma unroll
  for (int o = 32; o; o >>= 1) ss += __shfl_xor(ss, o);
  float sd = sqrtf(ss * (1.0f/127.0f));
  float inv = 1.0f / (sd + LN_EPS);
  float2 wv = ((const float2*)w)[lane];
  float2 bv = ((const float2*)b)[lane];
  ushort2 o2 = { f2bf(d0*inv*wv.x + bv.x), f2bf(d1*inv*wv.y + bv.y) };
  ((ushort2*)(out + (size_t)r*128))[lane] = o2;
}

// ---------- weight f32 -> bf16 conversion (all 6 in one launch) ----------
struct CvtArgs { const float* s[6]; ushort* d[6]; int cnt[6]; };
__global__ void cvt6_kernel(CvtArgs a){
  int w = blockIdx.y;
  int i = blockIdx.x*blockDim.x + threadIdx.x;
  if (i < a.cnt[w]) a.d[w][i] = f2bf(a.s[w][i]);
}

// ---------- LDS-staged bf16 MFMA GEMM, 128-row blocks (8 waves / 512 thr) ----------
// OUTMODE: 0 = f32, 1 = bf16, 2 = fp16
// Staging is WAVE-UNIFORM; compute/A-prefetch guarded by mb<M (round-15 bugfix).
template<int K, int RELU, int RESID, int OUTMODE>
__device__ __forceinline__ void gemm_lds_body(
    const ushort* __restrict__ A, const ushort* __restrict__ W,
    const float* __restrict__ bias, const float* __restrict__ resid,
    void* __restrict__ out, int M, int Nout, int cb, ushort* Wl){
  constexpr int NCH = K / 128;
  int t = threadIdx.x;
  int wid = t >> 6, lane = t & 63;
  int mb = blockIdx.x * 128 + wid * 16;
  int lrow = lane & 15, kgrp = lane >> 4;
  int row = mb + lrow;
  bool waveok = mb < M;
  bool rowok = row < M;
  const ushort* arow = A + (size_t)(rowok ? row : (M-1)) * K + kgrp*8;

  f32x4 acc[8] = {};
  short8 af[2][4];

  #pragma unroll
  for (int p = 0; p < 4; ++p){
    int L = p*512 + t;
    int colp = L >> 4, sp = L & 15;
    stage16(W + (size_t)colp*K + ((sp ^ (colp & 7)) << 3),
            (ushort*)((char*)Wl + ((size_t)(p*512 + (t & ~63)))*16));
  }
  if (waveok){
    #pragma unroll
    for (int kk = 0; kk < 4; ++kk)
      af[0][kk] = *(const short8*)(arow + kk*32);
  }

  #pragma unroll
  for (int ci = 0; ci < NCH; ++ci){
    __syncthreads();                       // chunk ci staged + A regs ready
    int cur = ci & 1;
    if (waveok){
      if (ci + 1 < NCH){
        #pragma unroll
        for (int kk = 0; kk < 4; ++kk)
          af[cur^1][kk] = *(const short8*)(arow + (ci+1)*128 + kk*32);
      }
      #pragma unroll
      for (int kk = 0; kk < 4; ++kk){
        #pragma unroll
        for (int nt = 0; nt < 8; ++nt){
          int colc = nt*16 + lrow;
          int g = kk*4 + kgrp;
          short8 bfv = *(const short8*)((const char*)Wl + colc*256 + ((g ^ (colc & 7))*16));
          acc[nt] = __builtin_amdgcn_mfma_f32_16x16x32_bf16(af[cur][kk], bfv, acc[nt], 0, 0, 0);
        }
      }
    }
    if (ci + 1 < NCH){
      __syncthreads();                     // readers done; restage (ALL threads)
      const ushort* Wc = W + (ci+1)*128;
      #pragma unroll
      for (int p = 0; p < 4; ++p){
        int L = p*512 + t;
        int colp = L >> 4, sp = L & 15;
        stage16(Wc + (size_t)colp*K + ((sp ^ (colp & 7)) << 3),
                (ushort*)((char*)Wl + ((size_t)(p*512 + (t & ~63)))*16));
      }
    }
  }
  if (!waveok) return;

  int r0 = mb + kgrp*4;
  #pragma unroll
  for (int nt = 0; nt < 8; ++nt){
    int c = cb + nt*16 + lrow;
    float bsum = bias[c];
    #pragma unroll
    for (int i = 0; i < 4; ++i){
      int r = r0 + i;
      if (r >= M) continue;
      float v = acc[nt][i] + bsum;
      if (RELU)  v = fmaxf(v, 0.0f);
      if (RESID) v += resid[(size_t)r*Nout + c];
      if (OUTMODE == 1) ((ushort*)out)[(size_t)r*Nout + c] = f2bf(v);
      else if (OUTMODE == 2){
        _Float16 hv = (_Float16)v;
        ((ushort*)out)[(size_t)r*Nout + c] = __builtin_bit_cast(ushort, hv);
      } else ((float*)out)[(size_t)r*Nout + c] = v;
    }
  }
}

template<int K, int RELU, int RESID, int OUTMODE>
__global__ __launch_bounds__(512) void gemm_lds(
    const ushort* __restrict__ A, const ushort* __restrict__ Wfull,
    const float* __restrict__ bias, const float* __restrict__ resid,
    void* __restrict__ out, int M, int Nout){
  __shared__ __align__(16) ushort Wl[16384];
  int cb = blockIdx.y * 128;
  gemm_lds_body<K,RELU,RESID,OUTMODE>(A, Wfull + (size_t)cb*K, bias, resid, out, M, Nout, cb, Wl);
}

// q,k -> fp16 (OUTMODE 2); v -> bf16 (OUTMODE 1)
__global__ __launch_bounds__(512) void qkv_lds(
    const ushort* __restrict__ A, const ushort* __restrict__ Wcat,
    const float* __restrict__ bq, const float* __restrict__ bk, const float* __restrict__ bv,
    ushort* __restrict__ qb, ushort* __restrict__ kb, ushort* __restrict__ vb, int M){
  __shared__ __align__(16) ushort Wl[16384];
  int y = blockIdx.y;
  const float* bias = (y==0) ? bq : (y==1) ? bk : bv;
  ushort* out = (y==0) ? qb : (y==1) ? kb : vb;
  if (y == 2)
    gemm_lds_body<128,0,0,1>(A, Wcat + (size_t)y*16384, bias, nullptr, out, M, 128, 0, Wl);
  else
    gemm_lds_body<128,0,0,2>(A, Wcat + (size_t)y*16384, bias, nullptr, out, M, 128, 0, Wl);
}

// ---------- Wo GEMM + residual + fused LN2: outp (f32) and x2b (bf16) ----------
__global__ __launch_bounds__(512) void gemm_wo_ln2(
    const ushort* __restrict__ A, const ushort* __restrict__ W,
    const float* __restrict__ bias, const float* __restrict__ feats,
    const float* __restrict__ lnw, const float* __restrict__ lnb,
    float* __restrict__ outp, ushort* __restrict__ x2b, int M){
  constexpr int K = 128;
  __shared__ __align__(16) ushort Wl[16384];
  int t = threadIdx.x;
  int wid = t >> 6, lane = t & 63;
  int mb = blockIdx.x * 128 + wid * 16;
  int lrow = lane & 15, kgrp = lane >> 4;
  int row = mb + lrow;
  bool waveok = mb < M;
  bool rowok = row < M;
  const ushort* arow = A + (size_t)(rowok ? row : (M-1)) * K + kgrp*8;

  f32x4 acc[8] = {};
  short8 af[4];

  #pragma unroll
  for (int p = 0; p < 4; ++p){
    int L = p*512 + t;
    int colp = L >> 4, sp = L & 15;
    stage16(W + (size_t)colp*K + ((sp ^ (colp & 7)) << 3),
            (ushort*)((char*)Wl + ((size_t)(p*512 + (t & ~63)))*16));
  }
  if (waveok){
    #pragma unroll
    for (int kk = 0; kk < 4; ++kk)
      af[kk] = *(const short8*)(arow + kk*32);
  }
  __syncthreads();
  if (!waveok) return;

  #pragma unroll
  for (int kk = 0; kk < 4; ++kk){
    #pragma unroll
    for (int nt = 0; nt < 8; ++nt){
      int colc = nt*16 + lrow;
      int g = kk*4 + kgrp;
      short8 bfv = *(const short8*)((const char*)Wl + colc*256 + ((g ^ (colc & 7))*16));
      acc[nt] = __builtin_amdgcn_mfma_f32_16x16x32_bf16(af[kk], bfv, acc[nt], 0, 0, 0);
    }
  }

  // epilogue: v = acc + bias + feats; write outp; fused LN2 -> x2b
  int r0 = mb + kgrp*4;
  float vv[8][4];
  float lw[8], lb[8];
  #pragma unroll
  for (int nt = 0; nt < 8; ++nt){
    int c = nt*16 + lrow;
    float bsum = bias[c];
    lw[nt] = lnw[c]; lb[nt] = lnb[c];
    #pragma unroll
    for (int i = 0; i < 4; ++i){
      int r = r0 + i;
      float v = 0.f;
      if (r < M){
        v = acc[nt][i] + bsum + feats[(size_t)r*128 + c];
        outp[(size_t)r*128 + c] = v;
      }
      vv[nt][i] = v;
    }
  }
  #pragma unroll
  for (int i = 0; i < 4; ++i){
    int r = r0 + i;
    float s = 0.f;
    #pragma unroll
    for (int nt = 0; nt < 8; ++nt) s += vv[nt][i];
    #pragma unroll
    for (int o = 1; o < 16; o <<= 1) s += __shfl_xor(s, o);
    float mu = s * (1.0f/128.0f);
    float ss = 0.f;
    float d[8];
    #pragma unroll
    for (int nt = 0; nt < 8; ++nt){ d[nt] = vv[nt][i] - mu; ss += d[nt]*d[nt]; }
    #pragma unroll
    for (int o = 1; o < 16; o <<= 1) ss += __shfl_xor(ss, o);
    float sd = sqrtf(ss * (1.0f/127.0f));
    float inv = 1.0f / (sd + LN_EPS);
    if (r < M){
      #pragma unroll
      for (int nt = 0; nt < 8; ++nt){
        int c = nt*16 + lrow;
        x2b[(size_t)r*128 + c] = f2bf(d[nt]*inv*lw[nt] + lb[nt]);
      }
    }
  }
}

// ---------- CSR build, atomic-free, bin-segmented ----------
__global__ __launch_bounds__(256) void hist_seg2(const int* __restrict__ ei,
    unsigned* __restrict__ copies, int E, int n, int nw, int chunk, int nsb){
  __shared__ unsigned hh[12544];
  int b = blockIdx.x, s = blockIdx.y, t = threadIdx.x;
  int bin0 = s * nsb;
  int bin1 = min(bin0 + nsb, n);
  int words = (bin1 - bin0 + 1) >> 1;
  for (int i = t; i < 2*words; i += 256) hh[i] = 0;
  __syncthreads();
  int lo = b*chunk, hi = min(lo + chunk, E);
  for (int e = lo + t; e < hi; e += 256){
    int2 rc = ((const int2*)ei)[e];
    if (rc.x >= bin0 && rc.x < bin1)
      atomicAdd(&hh[(rc.x - bin0) >> 1], 1u << ((rc.x & 1)*16));
    if (rc.y >= bin0 && rc.y < bin1)
      atomicAdd(&hh[words + ((rc.y - bin0) >> 1)], 1u << ((rc.y & 1)*16));
  }
  __syncthreads();
  unsigned* d0 = copies + (size_t)b*nw + (bin0 >> 1);
  unsigned* d1 = copies + (size_t)(NBCH + b)*nw + (bin0 >> 1);
  for (int i = t; i < words; i += 256){ d0[i] = hh[i]; d1[i] = hh[words + i]; }
}

__global__ __launch_bounds__(256) void scan_fold(const unsigned* __restrict__ copies,
    int* __restrict__ cnt2, ushort* __restrict__ choff, int n, int nw){
  int y = blockIdx.y;
  int bin = blockIdx.x*256 + threadIdx.x;
  if (bin >= n) return;
  const unsigned* cp = copies + (size_t)y*NBCH*nw + (bin >> 1);
  int sh = (bin & 1)*16;
  int run = 0;
  for (int b = 0; b < NBCH; ++b){
    int c = (int)((cp[(size_t)b*nw] >> sh) & 0xffffu);
    choff[((size_t)y*NBCH + b)*n + bin] = (ushort)run;
    run += c;
  }
  cnt2[(size_t)y*n + bin] = run;
}

// ---------- parallel 3-phase exclusive scan over cnt2 (both arrays, gridDim.y=2) ----------
__global__ __launch_bounds__(256) void scan_reduce(const int* __restrict__ cnt0,
                                                   int* __restrict__ partial, int n, int nb){
  const int* cnt = cnt0 + (size_t)blockIdx.y * n;
  int t = threadIdx.x;
  int base = blockIdx.x*1024 + t*4;
  int s = 0;
  #pragma unroll
  for (int j = 0; j < 4; ++j){ int i = base+j; if (i < n) s += cnt[i]; }
  __shared__ int sm[256];
  sm[t] = s; __syncthreads();
  for (int off = 128; off; off >>= 1){
    if (t < off) sm[t] += sm[t+off];
    __syncthreads();
  }
  if (t == 0) partial[blockIdx.y*nb + blockIdx.x] = sm[0];
}

__global__ __launch_bounds__(256) void scan_mid(int* __restrict__ partial, int nb,
                                                int* __restrict__ rptr, int* __restrict__ cptr, int n){
  int y = blockIdx.y;
  int* p = partial + y*nb;
  int t = threadIdx.x;
  __shared__ int sm[256];
  sm[t] = (t < nb) ? p[t] : 0;
  __syncthreads();
  for (int off = 1; off < 256; off <<= 1){
    int v = (t >= off) ? sm[t-off] : 0;
    __syncthreads();
    sm[t] += v;
    __syncthreads();
  }
  if (t < nb) p[t] = (t == 0) ? 0 : sm[t-1];
  if (t == 0) (y ? cptr : rptr)[n] = sm[255];
}

__global__ __launch_bounds__(256) void scan_scatter(const int* __restrict__ cnt0,
                                                    const int* __restrict__ partial,
                                                    int* __restrict__ rptr, int* __restrict__ cptr,
                                                    int n, int nb){
  int y = blockIdx.y;
  const int* cnt = cnt0 + (size_t)y * n;
  int* ptr = y ? cptr : rptr;
  int t = threadIdx.x;
  int base = blockIdx.x*1024 + t*4;
  int v[4]; int s = 0;
  #pragma unroll
  for (int j = 0; j < 4; ++j){ int i = base+j; v[j] = (i<n)?cnt[i]:0; s += v[j]; }
  __shared__ int sm[256];
  sm[t] = s; __syncthreads();
  for (int off = 1; off < 256; off <<= 1){
    int x = (t >= off) ? sm[t-off] : 0;
    __syncthreads();
    sm[t] += x;
    __syncthreads();
  }
  int pre = partial[y*nb + blockIdx.x] + ((t==0)?0:sm[t-1]);
  #pragma unroll
  for (int j = 0; j < 4; ++j){
    int i = base+j;
    if (i < n){ ptr[i] = pre; pre += v[j]; }
  }
}

// fill via in-chunk LDS rank within bin segment; no global atomics
__global__ __launch_bounds__(256) void fill_r_seg(const int* __restrict__ ei,
    const int* __restrict__ rptr, const ushort* __restrict__ choffR,
    int* __restrict__ rcol, int* __restrict__ pose, int E, int n, int chunk, int nsb){
  __shared__ unsigned hh[8192];
  int b = blockIdx.x, s = blockIdx.y, t = threadIdx.x;
  int bin0 = s * nsb;
  int bin1 = min(bin0 + nsb, n);
  int words = (bin1 - bin0 + 1) >> 1;
  for (int i = t; i < words; i += 256) hh[i] = 0;
  __syncthreads();
  const ushort* chb = choffR + (size_t)b*n;
  int lo = b*chunk, hi = min(lo + chunk, E);
  for (int e = lo + t; e < hi; e += 256){
    int2 rc = ((const int2*)ei)[e];
    int bin = rc.x;
    if (bin < bin0 || bin >= bin1) continue;
    int sh = (bin & 1)*16;
    unsigned old = atomicAdd(&hh[(bin - bin0) >> 1], 1u << sh);
    int rank = (int)((old >> sh) & 0xffffu);
    int pos = rptr[bin] + (int)chb[bin] + rank;
    rcol[pos] = rc.y;
    pose[e] = pos;
  }
}

__global__ __launch_bounds__(256) void fill_c_seg(const int* __restrict__ ei,
    const int* __restrict__ cptr, const ushort* __restrict__ choffC,
    const int* __restrict__ pose, int* __restrict__ crow, int* __restrict__ cposr,
    int E, int n, int chunk, int nsb){
  __shared__ unsigned hh[8192];
  int b = blockIdx.x, s = blockIdx.y, t = threadIdx.x;
  int bin0 = s * nsb;
  int bin1 = min(bin0 + nsb, n);
  int words = (bin1 - bin0 + 1) >> 1;
  for (int i = t; i < words; i += 256) hh[i] = 0;
  __syncthreads();
  const ushort* chb = choffC + (size_t)b*n;
  int lo = b*chunk, hi = min(lo + chunk, E);
  for (int e = lo + t; e < hi; e += 256){
    int2 rc = ((const int2*)ei)[e];
    int bin = rc.y;
    if (bin < bin0 || bin >= bin1) continue;
    int sh = (bin & 1)*16;
    unsigned old = atomicAdd(&hh[(bin - bin0) >> 1], 1u << sh);
    int rank = (int)((old >> sh) & 0xffffu);
    int pos = cptr[bin] + (int)chb[bin] + rank;
    crow[pos] = rc.x;
    cposr[pose[e]] = pos;
  }
}

// ---------- q.k dot for one head (16 dims), fp16 inputs ----------
__device__ __forceinline__ float qdot16h(const ushort* __restrict__ qb, int c, int h,
                                         const half2v* kf2){
  const int4* qp = (const int4*)(qb + (size_t)c*128 + h*16);
  int4 a = qp[0], b = qp[1];
  int qa[8] = {a.x, a.y, a.z, a.w, b.x, b.y, b.z, b.w};
  float s = 0.f;
#if HAS_FDOT2
  #pragma unroll
  for (int i = 0; i < 8; ++i)
    s = __builtin_amdgcn_fdot2(__builtin_bit_cast(half2v, qa[i]), kf2[i], s, false);
#else
  #pragma unroll
  for (int i = 0; i < 8; ++i){
    half2v q2 = __builtin_bit_cast(half2v, qa[i]);
    s += (float)q2.x * (float)kf2[i].x + (float)q2.y * (float)kf2[i].y;
  }
#endif
  return s * 0.25f;   // 1/sqrt(16)
}

// degree-templated softmax body: NS unroll slots (NS*8 edges capacity).
// rl/cpl = wave-preloaded rcol/cposr at lo+lane. ALL __shfl calls are
// UNCONDITIONAL (round-17 bugfix: ds_bpermute from an exec-masked-off
// source lane returns garbage) — results discarded for j >= hi slots.
template<int NS>
__device__ __forceinline__ void softmax_rows(const ushort* __restrict__ qb,
    const int* __restrict__ rcol, const int* __restrict__ cposr,
    ushort* __restrict__ cbuf, const half2v* kf2, int lo, int hi, int h, int el,
    int rl, int cpl){
  float sreg[NS];
  float m = -1e30f;
  #pragma unroll
  for (int ts = 0; ts < NS; ++ts){
    int c = __shfl(rl, el + ts*8);        // all 64 lanes active here
    int j = lo + el + ts*8;
    float s = -1e30f;
    if (j < hi) s = qdot16h(qb, c, h, kf2);
    sreg[ts] = s;
    m = fmaxf(m, s);
  }
  if (NS == 8)
    for (int j = lo + el + 64; j < hi; j += 8)
      m = fmaxf(m, qdot16h(qb, rcol[j], h, kf2));
  #pragma unroll
  for (int o = 8; o < 64; o <<= 1) m = fmaxf(m, __shfl_xor(m, o));

  float d = 0.f;
  #pragma unroll
  for (int ts = 0; ts < NS; ++ts){
    int j = lo + el + ts*8;
    if (j < hi){ float e = __expf(sreg[ts] - m); sreg[ts] = e; d += e; }
  }
  if (NS == 8)
    for (int j = lo + el + 64; j < hi; j += 8)
      d += __expf(qdot16h(qb, rcol[j], h, kf2) - m);
  #pragma unroll
  for (int o = 8; o < 64; o <<= 1) d += __shfl_xor(d, o);
  float invd = 1.0f / d;

  #pragma unroll
  for (int ts = 0; ts < NS; ++ts){
    int cp = __shfl(cpl, el + ts*8);      // unconditional (all lanes active)
    int j = lo + el + ts*8;
    if (j < hi) cbuf[(size_t)cp*8 + h] = f2bf(sreg[ts] * invd);
  }
  if (NS == 8)
    for (int j = lo + el + 64; j < hi; j += 8){
      float s = qdot16h(qb, rcol[j], h, kf2);
      cbuf[(size_t)cposr[j]*8 + h] = f2bf(__expf(s - m) * invd);
    }
}

// ---------- fused segmented softmax over row-CSR (fp16 q/k, degree-branched) ----------
__global__ void row_softmax_kernel(const ushort* __restrict__ qb, const ushort* __restrict__ kb,
                                   const int* __restrict__ rptr, const int* __restrict__ rcol,
                                   const int* __restrict__ cposr,
                                   ushort* __restrict__ cbuf, int n){
  int wid = threadIdx.x >> 6, lane = threadIdx.x & 63;
  int r = blockIdx.x * (blockDim.x >> 6) + wid;
  if (r >= n) return;
  int lo = rptr[r], hi = rptr[r+1];
  if (lo >= hi) return;
  int h = lane & 7, el = lane >> 3;

  // wave-preload edge indices (coalesced; covers first 64 edges of the row)
  int jl = lo + lane;
  bool jok = jl < hi;
  int rl  = rcol [jok ? jl : lo];
  int cpl = cposr[jok ? jl : lo];

  half2v kf2[8];
  {
    const int4* kp = (const int4*)(kb + (size_t)r*128 + h*16);
    int4 k0 = kp[0], k1 = kp[1];
    kf2[0] = __builtin_bit_cast(half2v, k0.x);
    kf2[1] = __builtin_bit_cast(half2v, k0.y);
    kf2[2] = __builtin_bit_cast(half2v, k0.z);
    kf2[3] = __builtin_bit_cast(half2v, k0.w);
    kf2[4] = __builtin_bit_cast(half2v, k1.x);
    kf2[5] = __builtin_bit_cast(half2v, k1.y);
    kf2[6] = __builtin_bit_cast(half2v, k1.z);
    kf2[7] = __builtin_bit_cast(half2v, k1.w);
  }

  int deg = hi - lo;   // wave-uniform
  if (deg <= 16)      softmax_rows<2>(qb, rcol, cposr, cbuf, kf2, lo, hi, h, el, rl, cpl);
  else if (deg <= 32) softmax_rows<4>(qb, rcol, cposr, cbuf, kf2, lo, hi, h, el, rl, cpl);
  else                softmax_rows<8>(qb, rcol, cposr, cbuf, kf2, lo, hi, h, el, rl, cpl);
}

// ---------- gather aggregation over col-CSR -> bf16 agg ----------
// eight 8-lane groups; crow wave-preloaded, shuffled UNCONDITIONALLY inside a
// wave-uniform trip-count loop (round-17 bugfix). lane l8 = head l8 (HD=16).
__global__ void agg_kernel(const ushort* __restrict__ vb, const ushort* __restrict__ cbuf,
                           const int* __restrict__ cptr, const int* __restrict__ crow,
                           ushort* __restrict__ aggb, int n){
  int wid = threadIdx.x >> 6, lane = threadIdx.x & 63;
  int node = blockIdx.x * (blockDim.x >> 6) + wid;
  if (node >= n) return;
  int lo = cptr[node], hi = cptr[node+1];
  int deg = hi - lo;                    // wave-uniform
  int oct = lane >> 3, l8 = lane & 7;

  int jl = lo + lane;
  int crl = crow[jl < hi ? jl : lo];    // first 64 edges preloaded

  float acc[16] = {};
  int tmax = (deg + 7) >> 3;            // wave-uniform trip count
  for (int ts = 0; ts < tmax; ++ts){
    int li = oct + ts*8;
    int row = __shfl(crl, li & 63);     // all 64 lanes active
    if (li < deg){
      if (li >= 64) row = crow[lo + li];
      float a = bf2f(cbuf[(size_t)(lo + li)*8 + l8]);
      const short8* vp = (const short8*)(vb + (size_t)row*128 + l8*16);
      short8 v0 = vp[0], v1 = vp[1];
      #pragma unroll
      for (int i = 0; i < 8; ++i){
        acc[i]   = fmaf(a, bf2f((ushort)v0[i]), acc[i]);
        acc[8+i] = fmaf(a, bf2f((ushort)v1[i]), acc[8+i]);
      }
    }
  }
  #pragma unroll
  for (int i = 0; i < 16; ++i){
    acc[i] += __shfl_xor(acc[i], 8);
    acc[i] += __shfl_xor(acc[i], 16);
    acc[i] += __shfl_xor(acc[i], 32);
  }
  if (oct == 0){
    short8 o0, o1;
    #pragma unroll
    for (int i = 0; i < 8; ++i){ o0[i] = (short)f2bf(acc[i]); o1[i] = (short)f2bf(acc[8+i]); }
    short8* op = (short8*)(aggb + (size_t)node*128 + l8*16);
    op[0] = o0; op[1] = o1;
  }
}

extern "C" void kernel_launch(void* const* d_in, const int* in_sizes, int n_in,
                              void* d_out, int out_size, void* d_ws, size_t ws_size,
                              hipStream_t stream){
  const float* feats = (const float*)d_in[0];
  const int*   ei    = (const int*)  d_in[1];
  const float* Wq = (const float*)d_in[2];
  const float* bq = (const float*)d_in[3];
  const float* Wk = (const float*)d_in[4];
  const float* bk = (const float*)d_in[5];
  const float* Wv = (const float*)d_in[6];
  const float* bv = (const float*)d_in[7];
  const float* Wo = (const float*)d_in[8];
  const float* bo = (const float*)d_in[9];
  const float* ln1w = (const float*)d_in[10];
  const float* ln1b = (const float*)d_in[11];
  const float* ln2w = (const float*)d_in[12];
  const float* ln2b = (const float*)d_in[13];
  const float* W1 = (const float*)d_in[14];
  const float* b1 = (const float*)d_in[15];
  const float* W2 = (const float*)d_in[16];
  const float* b2 = (const float*)d_in[17];
  float* outp = (float*)d_out;

  int n = in_sizes[0] / 128;      // 50000 nodes
  int E = in_sizes[1] / 2;        // 800000 edges
  int nw = (n + 1) >> 1;          // packed u16 words per full histogram
  int chunk = (E + NBCH - 1) / NBCH;
  int nsb = (((n + NSEG - 1) / NSEG) + 1) & ~1;   // bins per segment (even)

  const size_t ND  = (size_t)n * 128;
  const size_t ND2 = ND / 2;
  const size_t EH  = (size_t)E * H_HEADS;

  float* ws = (float*)d_ws;
  ushort* x2b  = (ushort*)ws;                      // ND bf16
  ushort* qb   = (ushort*)(ws + ND2);              // ND fp16
  ushort* kb   = (ushort*)(ws + 2*ND2);            // ND fp16
  ushort* vb   = (ushort*)(ws + 3*ND2);            // ND bf16
  ushort* cbuf = (ushort*)(ws + 4*ND2);            // EH bf16 (alpha, col order)
  ushort* aggb = (ushort*)(ws + 4*ND2 + EH/2);     // ND bf16
  int* crow    = (int*)(ws + 5*ND2 + EH/2);
  int* cposr   = crow + E;
  int* rcol    = cposr + E;
  int* pose    = rcol + E;
  int* rptr    = pose + E;
  int* cptr    = rptr + (n + 4);
  int* cnt2    = cptr + (n + 4);                   // [2][n]
  ushort* choff = (ushort*)(cnt2 + 2*n);           // [2][NBCH][n] u16
  unsigned* copies = (unsigned*)(choff + (size_t)2*NBCH*n);  // [2][NBCH][nw]
  int* partial = (int*)(copies + (size_t)2*NBCH*nw);         // 2*nb ints
  ushort* wbuf = (ushort*)(partial + 512);
  ushort* Wqb = wbuf;                              // Wq,Wk,Wv contiguous for qkv
  ushort* Wkb = Wqb + 16384;
  ushort* Wvb = Wkb + 16384;
  ushort* Wob = Wvb + 16384;
  ushort* W1b = Wob + 16384;
  ushort* W2b = W1b + 65536;
  ushort* h1  = qb;                                // n*512 bf16 == qb..cbuf

  // weight conversion (independent)
  CvtArgs ca;
  ca.s[0]=Wq; ca.s[1]=Wk; ca.s[2]=Wv; ca.s[3]=Wo; ca.s[4]=W1; ca.s[5]=W2;
  ca.d[0]=Wqb; ca.d[1]=Wkb; ca.d[2]=Wvb; ca.d[3]=Wob; ca.d[4]=W1b; ca.d[5]=W2b;
  ca.cnt[0]=ca.cnt[1]=ca.cnt[2]=ca.cnt[3]=16384; ca.cnt[4]=ca.cnt[5]=65536;
  cvt6_kernel<<<dim3(65536/256, 6), 256, 0, stream>>>(ca);

  // atomic-free CSR build (bin-segmented LDS histograms, merged row+col pass)
  int nb = (n + 1023)/1024;
  hist_seg2 <<<dim3(NBCH,NSEG), 256, 0, stream>>>(ei, copies, E, n, nw, chunk, nsb);
  scan_fold <<<dim3((n+255)/256,2), 256, 0, stream>>>(copies, cnt2, choff, n, nw);
  scan_reduce <<<dim3(nb,2), 256, 0, stream>>>(cnt2, partial, n, nb);
  scan_mid    <<<dim3(1,2),  256, 0, stream>>>(partial, nb, rptr, cptr, n);
  scan_scatter<<<dim3(nb,2), 256, 0, stream>>>(cnt2, partial, rptr, cptr, n, nb);
  fill_r_seg<<<dim3(NBCH,NSEG), 256, 0, stream>>>(ei, rptr, choff,                  rcol, pose, E, n, chunk, nsb);
  fill_c_seg<<<dim3(NBCH,NSEG), 256, 0, stream>>>(ei, cptr, choff + (size_t)NBCH*n, pose, crow, cposr, E, n, chunk, nsb);

  // LN1 -> bf16
  ln_kernel<<<(n+3)/4, 256, 0, stream>>>(feats, ln1w, ln1b, x2b, n);

  // fused QKV projections (128-row blocks; q,k fp16 / v bf16 out)
  int gm = (n + 127)/128;
  qkv_lds<<<dim3(gm,3), 512, 0, stream>>>(x2b, Wqb, bq, bk, bv, qb, kb, vb, n);

  // fused segmented softmax (fp16 fdot2, degree-branched, preloaded indices)
  row_softmax_kernel<<<(n+3)/4, 256, 0, stream>>>(qb, kb, rptr, rcol, cposr, cbuf, n);

  // gather aggregation (8 chains in flight, preloaded crow) -> bf16
  agg_kernel<<<(n+3)/4, 256, 0, stream>>>(vb, cbuf, cptr, crow, aggb, n);

  // attention out projection + residual + fused LN2 -> outp (f32) + x2b (bf16)
  gemm_wo_ln2<<<gm, 512, 0, stream>>>(aggb, Wob, bo, feats, ln2w, ln2b, outp, x2b, n);

  // FFN
  gemm_lds<128,1,0,1><<<dim3(gm,4), 512, 0, stream>>>(x2b, W1b, b1, nullptr, h1,  n, 512);
  gemm_lds<512,1,1,0><<<dim3(gm,1), 512, 0, stream>>>(h1,  W2b, b2, outp,    outp, n, 128);
}

// Round 19
// 274.643 us; speedup vs baseline: 2.8728x; 1.0293x over previous
//
#include <hip/hip_runtime.h>
#include <hip/hip_bf16.h>
#include <math.h>

#define H_HEADS 8
constexpr float LN_EPS = 1e-5f;
constexpr int NBCH = 64;          // CSR build chunks (chunk <= 65535 for u16 counters)
constexpr int NSEG = 4;           // bin segments per chunk

using short8 = __attribute__((ext_vector_type(8))) short;
using f32x4  = __attribute__((ext_vector_type(4))) float;
using f32x2  = __attribute__((ext_vector_type(2))) float;
using half2v = __attribute__((ext_vector_type(2))) _Float16;

#if defined(__has_builtin)
#  if __has_builtin(__builtin_amdgcn_fdot2)
#    define HAS_FDOT2 1
#  endif
#  if __has_builtin(__builtin_amdgcn_cvt_pk_f32_fp8) && __has_builtin(__builtin_amdgcn_cvt_pk_fp8_f32)
#    define HAS_CVT_FP8 1
#  endif
#endif
#ifndef HAS_FDOT2
#  define HAS_FDOT2 0
#endif
#ifndef HAS_CVT_FP8
#  define HAS_CVT_FP8 0
#endif

__device__ __forceinline__ ushort f2bf(float v){
  __hip_bfloat16 h = __float2bfloat16(v);
  return *reinterpret_cast<ushort*>(&h);
}
__device__ __forceinline__ float bf2f(ushort u){
  return __uint_as_float(((unsigned)u) << 16);
}

// ---- fp8 e4m3fn helpers (HW cvt when available; fp16 bit-trick fallback) ----
__device__ __forceinline__ unsigned char f32_to_fp8(float v){
#if HAS_CVT_FP8
  return (unsigned char)(__builtin_amdgcn_cvt_pk_fp8_f32(v, v, 0, false) & 0xff);
#else
  _Float16 hv = (_Float16)v;
  ushort h = __builtin_bit_cast(ushort, hv);
  unsigned sign = (h >> 8) & 0x80;
  unsigned p = h & 0x7fff;
  if (p < 0x2400u) return (unsigned char)sign;   // flush |v|<2^-6 (incl. denorms) to 0
  unsigned q = (p - 0x2000u + 0x40u) >> 7;       // rebias fp16->fp8, round-half-up
  if (q > 0x7eu) q = 0x7eu;                      // clamp to max normal 448
  return (unsigned char)(sign | q);
#endif
}
__device__ __forceinline__ float fp8_to_f32(unsigned b){
  unsigned p = b & 0x7f;
  ushort hbits = (ushort)(((b & 0x80) << 8) | (p ? ((p << 7) + 0x2000u) : 0));
  _Float16 hv = __builtin_bit_cast(_Float16, hbits);
  return (float)hv;
}

// async global->LDS, 16B per lane; dest = wave-uniform base + lane*16
__device__ __forceinline__ void stage16(const ushort* g, ushort* l){
  __builtin_amdgcn_global_load_lds((const __attribute__((address_space(1))) unsigned*)g,
                                   (__attribute__((address_space(3))) unsigned*)l,
                                   16, 0, 0);
}

// ---------- LayerNorm (ddof=1), f32 in -> bf16 out, one wave per row ----------
__global__ void ln_kernel(const float* __restrict__ x, const float* __restrict__ w,
                          const float* __restrict__ b, ushort* __restrict__ out, int nrows){
  int wid = threadIdx.x >> 6, lane = threadIdx.x & 63;
  int r = blockIdx.x * (blockDim.x >> 6) + wid;
  if (r >= nrows) return;
  float2 v = ((const float2*)(x + (size_t)r*128))[lane];
  float s = v.x + v.y;
  #pragma unroll
  for (int o = 32; o; o >>= 1) s += __shfl_xor(s, o);
  float mu = s * (1.0f/128.0f);
  float d0 = v.x - mu, d1 = v.y - mu;
  float ss = d0*d0 + d1*d1;
  #pragma unroll
  for (int o = 32; o; o >>= 1) ss += __shfl_xor(ss, o);
  float sd = sqrtf(ss * (1.0f/127.0f));
  float inv = 1.0f / (sd + LN_EPS);
  float2 wv = ((const float2*)w)[lane];
  float2 bv = ((const float2*)b)[lane];
  ushort2 o2 = { f2bf(d0*inv*wv.x + bv.x), f2bf(d1*inv*wv.y + bv.y) };
  ((ushort2*)(out + (size_t)r*128))[lane] = o2;
}

// ---------- weight f32 -> bf16 conversion (all 6 in one launch) ----------
struct CvtArgs { const float* s[6]; ushort* d[6]; int cnt[6]; };
__global__ void cvt6_kernel(CvtArgs a){
  int w = blockIdx.y;
  int i = blockIdx.x*blockDim.x + threadIdx.x;
  if (i < a.cnt[w]) a.d[w][i] = f2bf(a.s[w][i]);
}

// ---------- LDS-staged bf16 MFMA GEMM, 128-row blocks (8 waves / 512 thr) ----------
// OUTMODE: 0 = f32, 1 = bf16, 2 = fp16
template<int K, int RELU, int RESID, int OUTMODE>
__device__ __forceinline__ void gemm_lds_body(
    const ushort* __restrict__ A, const ushort* __restrict__ W,
    const float* __restrict__ bias, const float* __restrict__ resid,
    void* __restrict__ out, int M, int Nout, int cb, ushort* Wl){
  constexpr int NCH = K / 128;
  int t = threadIdx.x;
  int wid = t >> 6, lane = t & 63;
  int mb = blockIdx.x * 128 + wid * 16;
  int lrow = lane & 15, kgrp = lane >> 4;
  int row = mb + lrow;
  bool waveok = mb < M;
  bool rowok = row < M;
  const ushort* arow = A + (size_t)(rowok ? row : (M-1)) * K + kgrp*8;

  f32x4 acc[8] = {};
  short8 af[2][4];

  #pragma unroll
  for (int p = 0; p < 4; ++p){
    int L = p*512 + t;
    int colp = L >> 4, sp = L & 15;
    stage16(W + (size_t)colp*K + ((sp ^ (colp & 7)) << 3),
            (ushort*)((char*)Wl + ((size_t)(p*512 + (t & ~63)))*16));
  }
  if (waveok){
    #pragma unroll
    for (int kk = 0; kk < 4; ++kk)
      af[0][kk] = *(const short8*)(arow + kk*32);
  }

  #pragma unroll
  for (int ci = 0; ci < NCH; ++ci){
    __syncthreads();                       // chunk ci staged + A regs ready
    int cur = ci & 1;
    if (waveok){
      if (ci + 1 < NCH){
        #pragma unroll
        for (int kk = 0; kk < 4; ++kk)
          af[cur^1][kk] = *(const short8*)(arow + (ci+1)*128 + kk*32);
      }
      #pragma unroll
      for (int kk = 0; kk < 4; ++kk){
        #pragma unroll
        for (int nt = 0; nt < 8; ++nt){
          int colc = nt*16 + lrow;
          int g = kk*4 + kgrp;
          short8 bfv = *(const short8*)((const char*)Wl + colc*256 + ((g ^ (colc & 7))*16));
          acc[nt] = __builtin_amdgcn_mfma_f32_16x16x32_bf16(af[cur][kk], bfv, acc[nt], 0, 0, 0);
        }
      }
    }
    if (ci + 1 < NCH){
      __syncthreads();                     // readers done; restage (ALL threads)
      const ushort* Wc = W + (ci+1)*128;
      #pragma unroll
      for (int p = 0; p < 4; ++p){
        int L = p*512 + t;
        int colp = L >> 4, sp = L & 15;
        stage16(Wc + (size_t)colp*K + ((sp ^ (colp & 7)) << 3),
                (ushort*)((char*)Wl + ((size_t)(p*512 + (t & ~63)))*16));
      }
    }
  }
  if (!waveok) return;

  int r0 = mb + kgrp*4;
  #pragma unroll
  for (int nt = 0; nt < 8; ++nt){
    int c = cb + nt*16 + lrow;
    float bsum = bias[c];
    #pragma unroll
    for (int i = 0; i < 4; ++i){
      int r = r0 + i;
      if (r >= M) continue;
      float v = acc[nt][i] + bsum;
      if (RELU)  v = fmaxf(v, 0.0f);
      if (RESID) v += resid[(size_t)r*Nout + c];
      if (OUTMODE == 1) ((ushort*)out)[(size_t)r*Nout + c] = f2bf(v);
      else if (OUTMODE == 2){
        _Float16 hv = (_Float16)v;
        ((ushort*)out)[(size_t)r*Nout + c] = __builtin_bit_cast(ushort, hv);
      } else ((float*)out)[(size_t)r*Nout + c] = v;
    }
  }
}

template<int K, int RELU, int RESID, int OUTMODE>
__global__ __launch_bounds__(512) void gemm_lds(
    const ushort* __restrict__ A, const ushort* __restrict__ Wfull,
    const float* __restrict__ bias, const float* __restrict__ resid,
    void* __restrict__ out, int M, int Nout){
  __shared__ __align__(16) ushort Wl[16384];
  int cb = blockIdx.y * 128;
  gemm_lds_body<K,RELU,RESID,OUTMODE>(A, Wfull + (size_t)cb*K, bias, resid, out, M, Nout, cb, Wl);
}

// ---------- fused QKV: single pass over A (read once), y-loop unrolled ----------
// q -> fp8 e4m3, k -> fp16, v -> bf16
__global__ __launch_bounds__(512) void qkv_fused(
    const ushort* __restrict__ A, const ushort* __restrict__ Wcat,
    const float* __restrict__ bq, const float* __restrict__ bk, const float* __restrict__ bv,
    unsigned char* __restrict__ qb8, ushort* __restrict__ kb, ushort* __restrict__ vb, int M){
  constexpr int K = 128;
  __shared__ __align__(16) ushort Wl[16384];
  int t = threadIdx.x;
  int wid = t >> 6, lane = t & 63;
  int mb = blockIdx.x * 128 + wid * 16;
  int lrow = lane & 15, kgrp = lane >> 4;
  int row = mb + lrow;
  bool waveok = mb < M;
  bool rowok = row < M;
  const ushort* arow = A + (size_t)(rowok ? row : (M-1)) * K + kgrp*8;

  short8 af[4];
  if (waveok){
    #pragma unroll
    for (int kk = 0; kk < 4; ++kk)
      af[kk] = *(const short8*)(arow + kk*32);
  }

  #pragma unroll
  for (int y = 0; y < 3; ++y){
    if (y) __syncthreads();                // previous MFMA LDS reads done
    const ushort* W = Wcat + (size_t)y*16384;
    #pragma unroll
    for (int p = 0; p < 4; ++p){           // stage Wy (ALL threads, wave-uniform)
      int L = p*512 + t;
      int colp = L >> 4, sp = L & 15;
      stage16(W + (size_t)colp*K + ((sp ^ (colp & 7)) << 3),
              (ushort*)((char*)Wl + ((size_t)(p*512 + (t & ~63)))*16));
    }
    __syncthreads();
    if (waveok){
      const float* bias = (y==0) ? bq : (y==1) ? bk : bv;
      f32x4 acc[8] = {};
      #pragma unroll
      for (int kk = 0; kk < 4; ++kk){
        #pragma unroll
        for (int nt = 0; nt < 8; ++nt){
          int colc = nt*16 + lrow;
          int g = kk*4 + kgrp;
          short8 bfv = *(const short8*)((const char*)Wl + colc*256 + ((g ^ (colc & 7))*16));
          acc[nt] = __builtin_amdgcn_mfma_f32_16x16x32_bf16(af[kk], bfv, acc[nt], 0, 0, 0);
        }
      }
      int r0 = mb + kgrp*4;
      #pragma unroll
      for (int nt = 0; nt < 8; ++nt){
        int c = nt*16 + lrow;
        float bsum = bias[c];
        #pragma unroll
        for (int i = 0; i < 4; ++i){
          int r = r0 + i;
          if (r >= M) continue;
          float v = acc[nt][i] + bsum;
          if (y == 0)      qb8[(size_t)r*128 + c] = f32_to_fp8(v);
          else if (y == 1){
            _Float16 hv = (_Float16)v;
            kb[(size_t)r*128 + c] = __builtin_bit_cast(ushort, hv);
          } else           vb[(size_t)r*128 + c] = f2bf(v);
        }
      }
    }
  }
}

// ---------- Wo GEMM + residual + fused LN2: outp (f32) and x2b (bf16) ----------
__global__ __launch_bounds__(512) void gemm_wo_ln2(
    const ushort* __restrict__ A, const ushort* __restrict__ W,
    const float* __restrict__ bias, const float* __restrict__ feats,
    const float* __restrict__ lnw, const float* __restrict__ lnb,
    float* __restrict__ outp, ushort* __restrict__ x2b, int M){
  constexpr int K = 128;
  __shared__ __align__(16) ushort Wl[16384];
  int t = threadIdx.x;
  int wid = t >> 6, lane = t & 63;
  int mb = blockIdx.x * 128 + wid * 16;
  int lrow = lane & 15, kgrp = lane >> 4;
  int row = mb + lrow;
  bool waveok = mb < M;
  bool rowok = row < M;
  const ushort* arow = A + (size_t)(rowok ? row : (M-1)) * K + kgrp*8;

  f32x4 acc[8] = {};
  short8 af[4];

  #pragma unroll
  for (int p = 0; p < 4; ++p){
    int L = p*512 + t;
    int colp = L >> 4, sp = L & 15;
    stage16(W + (size_t)colp*K + ((sp ^ (colp & 7)) << 3),
            (ushort*)((char*)Wl + ((size_t)(p*512 + (t & ~63)))*16));
  }
  if (waveok){
    #pragma unroll
    for (int kk = 0; kk < 4; ++kk)
      af[kk] = *(const short8*)(arow + kk*32);
  }
  __syncthreads();
  if (!waveok) return;

  #pragma unroll
  for (int kk = 0; kk < 4; ++kk){
    #pragma unroll
    for (int nt = 0; nt < 8; ++nt){
      int colc = nt*16 + lrow;
      int g = kk*4 + kgrp;
      short8 bfv = *(const short8*)((const char*)Wl + colc*256 + ((g ^ (colc & 7))*16));
      acc[nt] = __builtin_amdgcn_mfma_f32_16x16x32_bf16(af[kk], bfv, acc[nt], 0, 0, 0);
    }
  }

  int r0 = mb + kgrp*4;
  float vv[8][4];
  float lw[8], lb[8];
  #pragma unroll
  for (int nt = 0; nt < 8; ++nt){
    int c = nt*16 + lrow;
    float bsum = bias[c];
    lw[nt] = lnw[c]; lb[nt] = lnb[c];
    #pragma unroll
    for (int i = 0; i < 4; ++i){
      int r = r0 + i;
      float v = 0.f;
      if (r < M){
        v = acc[nt][i] + bsum + feats[(size_t)r*128 + c];
        outp[(size_t)r*128 + c] = v;
      }
      vv[nt][i] = v;
    }
  }
  #pragma unroll
  for (int i = 0; i < 4; ++i){
    int r = r0 + i;
    float s = 0.f;
    #pragma unroll
    for (int nt = 0; nt < 8; ++nt) s += vv[nt][i];
    #pragma unroll
    for (int o = 1; o < 16; o <<= 1) s += __shfl_xor(s, o);
    float mu = s * (1.0f/128.0f);
    float ss = 0.f;
    float d[8];
    #pragma unroll
    for (int nt = 0; nt < 8; ++nt){ d[nt] = vv[nt][i] - mu; ss += d[nt]*d[nt]; }
    #pragma unroll
    for (int o = 1; o < 16; o <<= 1) ss += __shfl_xor(ss, o);
    float sd = sqrtf(ss * (1.0f/127.0f));
    float inv = 1.0f / (sd + LN_EPS);
    if (r < M){
      #pragma unroll
      for (int nt = 0; nt < 8; ++nt){
        int c = nt*16 + lrow;
        x2b[(size_t)r*128 + c] = f2bf(d[nt]*inv*lw[nt] + lb[nt]);
      }
    }
  }
}

// ---------- CSR build, atomic-free, bin-segmented ----------
__global__ __launch_bounds__(256) void hist_seg2(const int* __restrict__ ei,
    unsigned* __restrict__ copies, int E, int n, int nw, int chunk, int nsb){
  __shared__ unsigned hh[12544];
  int b = blockIdx.x, s = blockIdx.y, t = threadIdx.x;
  int bin0 = s * nsb;
  int bin1 = min(bin0 + nsb, n);
  int words = (bin1 - bin0 + 1) >> 1;
  for (int i = t; i < 2*words; i += 256) hh[i] = 0;
  __syncthreads();
  int lo = b*chunk, hi = min(lo + chunk, E);
  for (int e = lo + t; e < hi; e += 256){
    int2 rc = ((const int2*)ei)[e];
    if (rc.x >= bin0 && rc.x < bin1)
      atomicAdd(&hh[(rc.x - bin0) >> 1], 1u << ((rc.x & 1)*16));
    if (rc.y >= bin0 && rc.y < bin1)
      atomicAdd(&hh[words + ((rc.y - bin0) >> 1)], 1u << ((rc.y & 1)*16));
  }
  __syncthreads();
  unsigned* d0 = copies + (size_t)b*nw + (bin0 >> 1);
  unsigned* d1 = copies + (size_t)(NBCH + b)*nw + (bin0 >> 1);
  for (int i = t; i < words; i += 256){ d0[i] = hh[i]; d1[i] = hh[words + i]; }
}

__global__ __launch_bounds__(256) void scan_fold(const unsigned* __restrict__ copies,
    int* __restrict__ cnt2, ushort* __restrict__ choff, int n, int nw){
  int y = blockIdx.y;
  int bin = blockIdx.x*256 + threadIdx.x;
  if (bin >= n) return;
  const unsigned* cp = copies + (size_t)y*NBCH*nw + (bin >> 1);
  int sh = (bin & 1)*16;
  int run = 0;
  for (int b = 0; b < NBCH; ++b){
    int c = (int)((cp[(size_t)b*nw] >> sh) & 0xffffu);
    choff[((size_t)y*NBCH + b)*n + bin] = (ushort)run;
    run += c;
  }
  cnt2[(size_t)y*n + bin] = run;
}

__global__ __launch_bounds__(256) void scan_reduce(const int* __restrict__ cnt0,
                                                   int* __restrict__ partial, int n, int nb){
  const int* cnt = cnt0 + (size_t)blockIdx.y * n;
  int t = threadIdx.x;
  int base = blockIdx.x*1024 + t*4;
  int s = 0;
  #pragma unroll
  for (int j = 0; j < 4; ++j){ int i = base+j; if (i < n) s += cnt[i]; }
  __shared__ int sm[256];
  sm[t] = s; __syncthreads();
  for (int off = 128; off; off >>= 1){
    if (t < off) sm[t] += sm[t+off];
    __syncthreads();
  }
  if (t == 0) partial[blockIdx.y*nb + blockIdx.x] = sm[0];
}

__global__ __launch_bounds__(256) void scan_mid(int* __restrict__ partial, int nb,
                                                int* __restrict__ rptr, int* __restrict__ cptr, int n){
  int y = blockIdx.y;
  int* p = partial + y*nb;
  int t = threadIdx.x;
  __shared__ int sm[256];
  sm[t] = (t < nb) ? p[t] : 0;
  __syncthreads();
  for (int off = 1; off < 256; off <<= 1){
    int v = (t >= off) ? sm[t-off] : 0;
    __syncthreads();
    sm[t] += v;
    __syncthreads();
  }
  if (t < nb) p[t] = (t == 0) ? 0 : sm[t-1];
  if (t == 0) (y ? cptr : rptr)[n] = sm[255];
}

__global__ __launch_bounds__(256) void scan_scatter(const int* __restrict__ cnt0,
                                                    const int* __restrict__ partial,
                                                    int* __restrict__ rptr, int* __restrict__ cptr,
                                                    int n, int nb){
  int y = blockIdx.y;
  const int* cnt = cnt0 + (size_t)y * n;
  int* ptr = y ? cptr : rptr;
  int t = threadIdx.x;
  int base = blockIdx.x*1024 + t*4;
  int v[4]; int s = 0;
  #pragma unroll
  for (int j = 0; j < 4; ++j){ int i = base+j; v[j] = (i<n)?cnt[i]:0; s += v[j]; }
  __shared__ int sm[256];
  sm[t] = s; __syncthreads();
  for (int off = 1; off < 256; off <<= 1){
    int x = (t >= off) ? sm[t-off] : 0;
    __syncthreads();
    sm[t] += x;
    __syncthreads();
  }
  int pre = partial[y*nb + blockIdx.x] + ((t==0)?0:sm[t-1]);
  #pragma unroll
  for (int j = 0; j < 4; ++j){
    int i = base+j;
    if (i < n){ ptr[i] = pre; pre += v[j]; }
  }
}

__global__ __launch_bounds__(256) void fill_r_seg(const int* __restrict__ ei,
    const int* __restrict__ rptr, const ushort* __restrict__ choffR,
    int* __restrict__ rcol, int* __restrict__ pose, int E, int n, int chunk, int nsb){
  __shared__ unsigned hh[8192];
  int b = blockIdx.x, s = blockIdx.y, t = threadIdx.x;
  int bin0 = s * nsb;
  int bin1 = min(bin0 + nsb, n);
  int words = (bin1 - bin0 + 1) >> 1;
  for (int i = t; i < words; i += 256) hh[i] = 0;
  __syncthreads();
  const ushort* chb = choffR + (size_t)b*n;
  int lo = b*chunk, hi = min(lo + chunk, E);
  for (int e = lo + t; e < hi; e += 256){
    int2 rc = ((const int2*)ei)[e];
    int bin = rc.x;
    if (bin < bin0 || bin >= bin1) continue;
    int sh = (bin & 1)*16;
    unsigned old = atomicAdd(&hh[(bin - bin0) >> 1], 1u << sh);
    int rank = (int)((old >> sh) & 0xffffu);
    int pos = rptr[bin] + (int)chb[bin] + rank;
    rcol[pos] = rc.y;
    pose[e] = pos;
  }
}

__global__ __launch_bounds__(256) void fill_c_seg(const int* __restrict__ ei,
    const int* __restrict__ cptr, const ushort* __restrict__ choffC,
    const int* __restrict__ pose, int* __restrict__ crow, int* __restrict__ cposr,
    int E, int n, int chunk, int nsb){
  __shared__ unsigned hh[8192];
  int b = blockIdx.x, s = blockIdx.y, t = threadIdx.x;
  int bin0 = s * nsb;
  int bin1 = min(bin0 + nsb, n);
  int words = (bin1 - bin0 + 1) >> 1;
  for (int i = t; i < words; i += 256) hh[i] = 0;
  __syncthreads();
  const ushort* chb = choffC + (size_t)b*n;
  int lo = b*chunk, hi = min(lo + chunk, E);
  for (int e = lo + t; e < hi; e += 256){
    int2 rc = ((const int2*)ei)[e];
    int bin = rc.y;
    if (bin < bin0 || bin >= bin1) continue;
    int sh = (bin & 1)*16;
    unsigned old = atomicAdd(&hh[(bin - bin0) >> 1], 1u << sh);
    int rank = (int)((old >> sh) & 0xffffu);
    int pos = cptr[bin] + (int)chb[bin] + rank;
    crow[pos] = rc.x;
    cposr[pose[e]] = pos;
  }
}

// ---------- q.k dot for one head (16 dims): q fp8, k as f32 regs ----------
__device__ __forceinline__ float qdot16q8(const unsigned char* __restrict__ qb8, int c, int h,
                                          const float* kf){
  const uint4* qp = (const uint4*)(qb8 + (size_t)c*128 + h*16);
  uint4 q = *qp;
  unsigned w[4] = {q.x, q.y, q.z, q.w};
  float s = 0.f;
  #pragma unroll
  for (int i = 0; i < 4; ++i){
#if HAS_CVT_FP8
    f32x2 lo = __builtin_amdgcn_cvt_pk_f32_fp8(w[i], false);
    f32x2 hi = __builtin_amdgcn_cvt_pk_f32_fp8(w[i], true);
    s = fmaf(lo[0], kf[4*i+0], s);
    s = fmaf(lo[1], kf[4*i+1], s);
    s = fmaf(hi[0], kf[4*i+2], s);
    s = fmaf(hi[1], kf[4*i+3], s);
#else
    #pragma unroll
    for (int j = 0; j < 4; ++j)
      s = fmaf(fp8_to_f32((w[i] >> (8*j)) & 0xffu), kf[4*i+j], s);
#endif
  }
  return s * 0.25f;   // 1/sqrt(16)
}

// degree-templated softmax body: NS unroll slots (NS*8 edges capacity).
// rl/cpl = wave-preloaded rcol/cposr at lo+lane; __shfl UNCONDITIONAL.
template<int NS>
__device__ __forceinline__ void softmax_rows(const unsigned char* __restrict__ qb8,
    const int* __restrict__ rcol, const int* __restrict__ cposr,
    ushort* __restrict__ cbuf, const float* kf, int lo, int hi, int h, int el,
    int rl, int cpl){
  float sreg[NS];
  float m = -1e30f;
  #pragma unroll
  for (int ts = 0; ts < NS; ++ts){
    int c = __shfl(rl, el + ts*8);        // all 64 lanes active here
    int j = lo + el + ts*8;
    float s = -1e30f;
    if (j < hi) s = qdot16q8(qb8, c, h, kf);
    sreg[ts] = s;
    m = fmaxf(m, s);
  }
  if (NS == 8)
    for (int j = lo + el + 64; j < hi; j += 8)
      m = fmaxf(m, qdot16q8(qb8, rcol[j], h, kf));
  #pragma unroll
  for (int o = 8; o < 64; o <<= 1) m = fmaxf(m, __shfl_xor(m, o));

  float d = 0.f;
  #pragma unroll
  for (int ts = 0; ts < NS; ++ts){
    int j = lo + el + ts*8;
    if (j < hi){ float e = __expf(sreg[ts] - m); sreg[ts] = e; d += e; }
  }
  if (NS == 8)
    for (int j = lo + el + 64; j < hi; j += 8)
      d += __expf(qdot16q8(qb8, rcol[j], h, kf) - m);
  #pragma unroll
  for (int o = 8; o < 64; o <<= 1) d += __shfl_xor(d, o);
  float invd = 1.0f / d;

  #pragma unroll
  for (int ts = 0; ts < NS; ++ts){
    int cp = __shfl(cpl, el + ts*8);      // unconditional
    int j = lo + el + ts*8;
    if (j < hi) cbuf[(size_t)cp*8 + h] = f2bf(sreg[ts] * invd);
  }
  if (NS == 8)
    for (int j = lo + el + 64; j < hi; j += 8){
      float s = qdot16q8(qb8, rcol[j], h, kf);
      cbuf[(size_t)cposr[j]*8 + h] = f2bf(__expf(s - m) * invd);
    }
}

// ---------- fused segmented softmax over row-CSR (fp8 q, fp16 k) ----------
__global__ void row_softmax_kernel(const unsigned char* __restrict__ qb8,
                                   const ushort* __restrict__ kb,
                                   const int* __restrict__ rptr, const int* __restrict__ rcol,
                                   const int* __restrict__ cposr,
                                   ushort* __restrict__ cbuf, int n){
  int wid = threadIdx.x >> 6, lane = threadIdx.x & 63;
  int r = blockIdx.x * (blockDim.x >> 6) + wid;
  if (r >= n) return;
  int lo = rptr[r], hi = rptr[r+1];
  if (lo >= hi) return;
  int h = lane & 7, el = lane >> 3;

  int jl = lo + lane;
  bool jok = jl < hi;
  int rl  = rcol [jok ? jl : lo];
  int cpl = cposr[jok ? jl : lo];

  float kf[16];
  {
    const int4* kp = (const int4*)(kb + (size_t)r*128 + h*16);
    int4 k0 = kp[0], k1 = kp[1];
    int kw[8] = {k0.x,k0.y,k0.z,k0.w,k1.x,k1.y,k1.z,k1.w};
    #pragma unroll
    for (int i = 0; i < 8; ++i){
      half2v k2 = __builtin_bit_cast(half2v, kw[i]);
      kf[2*i]   = (float)k2.x;
      kf[2*i+1] = (float)k2.y;
    }
  }

  int deg = hi - lo;   // wave-uniform
  if (deg <= 16)      softmax_rows<2>(qb8, rcol, cposr, cbuf, kf, lo, hi, h, el, rl, cpl);
  else if (deg <= 32) softmax_rows<4>(qb8, rcol, cposr, cbuf, kf, lo, hi, h, el, rl, cpl);
  else                softmax_rows<8>(qb8, rcol, cposr, cbuf, kf, lo, hi, h, el, rl, cpl);
}

// ---------- gather aggregation over col-CSR -> bf16 agg ----------
__global__ void agg_kernel(const ushort* __restrict__ vb, const ushort* __restrict__ cbuf,
                           const int* __restrict__ cptr, const int* __restrict__ crow,
                           ushort* __restrict__ aggb, int n){
  int wid = threadIdx.x >> 6, lane = threadIdx.x & 63;
  int node = blockIdx.x * (blockDim.x >> 6) + wid;
  if (node >= n) return;
  int lo = cptr[node], hi = cptr[node+1];
  int deg = hi - lo;                    // wave-uniform
  int oct = lane >> 3, l8 = lane & 7;

  int jl = lo + lane;
  int crl = crow[jl < hi ? jl : lo];

  float acc[16] = {};
  int tmax = (deg + 7) >> 3;
  for (int ts = 0; ts < tmax; ++ts){
    int li = oct + ts*8;
    int row = __shfl(crl, li & 63);     // all 64 lanes active
    if (li < deg){
      if (li >= 64) row = crow[lo + li];
      float a = bf2f(cbuf[(size_t)(lo + li)*8 + l8]);
      const short8* vp = (const short8*)(vb + (size_t)row*128 + l8*16);
      short8 v0 = vp[0], v1 = vp[1];
      #pragma unroll
      for (int i = 0; i < 8; ++i){
        acc[i]   = fmaf(a, bf2f((ushort)v0[i]), acc[i]);
        acc[8+i] = fmaf(a, bf2f((ushort)v1[i]), acc[8+i]);
      }
    }
  }
  #pragma unroll
  for (int i = 0; i < 16; ++i){
    acc[i] += __shfl_xor(acc[i], 8);
    acc[i] += __shfl_xor(acc[i], 16);
    acc[i] += __shfl_xor(acc[i], 32);
  }
  if (oct == 0){
    short8 o0, o1;
    #pragma unroll
    for (int i = 0; i < 8; ++i){ o0[i] = (short)f2bf(acc[i]); o1[i] = (short)f2bf(acc[8+i]); }
    short8* op = (short8*)(aggb + (size_t)node*128 + l8*16);
    op[0] = o0; op[1] = o1;
  }
}

extern "C" void kernel_launch(void* const* d_in, const int* in_sizes, int n_in,
                              void* d_out, int out_size, void* d_ws, size_t ws_size,
                              hipStream_t stream){
  const float* feats = (const float*)d_in[0];
  const int*   ei    = (const int*)  d_in[1];
  const float* Wq = (const float*)d_in[2];
  const float* bq = (const float*)d_in[3];
  const float* Wk = (const float*)d_in[4];
  const float* bk = (const float*)d_in[5];
  const float* Wv = (const float*)d_in[6];
  const float* bv = (const float*)d_in[7];
  const float* Wo = (const float*)d_in[8];
  const float* bo = (const float*)d_in[9];
  const float* ln1w = (const float*)d_in[10];
  const float* ln1b = (const float*)d_in[11];
  const float* ln2w = (const float*)d_in[12];
  const float* ln2b = (const float*)d_in[13];
  const float* W1 = (const float*)d_in[14];
  const float* b1 = (const float*)d_in[15];
  const float* W2 = (const float*)d_in[16];
  const float* b2 = (const float*)d_in[17];
  float* outp = (float*)d_out;

  int n = in_sizes[0] / 128;      // 50000 nodes
  int E = in_sizes[1] / 2;        // 800000 edges
  int nw = (n + 1) >> 1;          // packed u16 words per full histogram
  int chunk = (E + NBCH - 1) / NBCH;
  int nsb = (((n + NSEG - 1) / NSEG) + 1) & ~1;   // bins per segment (even)

  const size_t ND  = (size_t)n * 128;
  const size_t ND2 = ND / 2;
  const size_t EH  = (size_t)E * H_HEADS;

  float* ws = (float*)d_ws;
  ushort* x2b  = (ushort*)ws;                      // ND bf16
  unsigned char* qb8 = (unsigned char*)(ws + ND2); // ND fp8 (slot sized ND2 f32)
  ushort* kb   = (ushort*)(ws + 2*ND2);            // ND fp16
  ushort* vb   = (ushort*)(ws + 3*ND2);            // ND bf16
  ushort* cbuf = (ushort*)(ws + 4*ND2);            // EH bf16 (alpha, col order)
  ushort* aggb = (ushort*)(ws + 4*ND2 + EH/2);     // ND bf16
  int* crow    = (int*)(ws + 5*ND2 + EH/2);
  int* cposr   = crow + E;
  int* rcol    = cposr + E;
  int* pose    = rcol + E;
  int* rptr    = pose + E;
  int* cptr    = rptr + (n + 4);
  int* cnt2    = cptr + (n + 4);                   // [2][n]
  ushort* choff = (ushort*)(cnt2 + 2*n);           // [2][NBCH][n] u16
  unsigned* copies = (unsigned*)(choff + (size_t)2*NBCH*n);  // [2][NBCH][nw]
  int* partial = (int*)(copies + (size_t)2*NBCH*nw);         // 2*nb ints
  ushort* wbuf = (ushort*)(partial + 512);
  ushort* Wqb = wbuf;                              // Wq,Wk,Wv contiguous for qkv
  ushort* Wkb = Wqb + 16384;
  ushort* Wvb = Wkb + 16384;
  ushort* Wob = Wvb + 16384;
  ushort* W1b = Wob + 16384;
  ushort* W2b = W1b + 65536;
  ushort* h1  = (ushort*)qb8;                      // n*512 bf16 == qb8..cbuf slots

  // weight conversion (independent)
  CvtArgs ca;
  ca.s[0]=Wq; ca.s[1]=Wk; ca.s[2]=Wv; ca.s[3]=Wo; ca.s[4]=W1; ca.s[5]=W2;
  ca.d[0]=Wqb; ca.d[1]=Wkb; ca.d[2]=Wvb; ca.d[3]=Wob; ca.d[4]=W1b; ca.d[5]=W2b;
  ca.cnt[0]=ca.cnt[1]=ca.cnt[2]=ca.cnt[3]=16384; ca.cnt[4]=ca.cnt[5]=65536;
  cvt6_kernel<<<dim3(65536/256, 6), 256, 0, stream>>>(ca);

  // atomic-free CSR build (bin-segmented LDS histograms, merged row+col pass)
  int nb = (n + 1023)/1024;
  hist_seg2 <<<dim3(NBCH,NSEG), 256, 0, stream>>>(ei, copies, E, n, nw, chunk, nsb);
  scan_fold <<<dim3((n+255)/256,2), 256, 0, stream>>>(copies, cnt2, choff, n, nw);
  scan_reduce <<<dim3(nb,2), 256, 0, stream>>>(cnt2, partial, n, nb);
  scan_mid    <<<dim3(1,2),  256, 0, stream>>>(partial, nb, rptr, cptr, n);
  scan_scatter<<<dim3(nb,2), 256, 0, stream>>>(cnt2, partial, rptr, cptr, n, nb);
  fill_r_seg<<<dim3(NBCH,NSEG), 256, 0, stream>>>(ei, rptr, choff,                  rcol, pose, E, n, chunk, nsb);
  fill_c_seg<<<dim3(NBCH,NSEG), 256, 0, stream>>>(ei, cptr, choff + (size_t)NBCH*n, pose, crow, cposr, E, n, chunk, nsb);

  // LN1 -> bf16
  ln_kernel<<<(n+3)/4, 256, 0, stream>>>(feats, ln1w, ln1b, x2b, n);

  // fused QKV (A read once; q fp8 / k fp16 / v bf16)
  int gm = (n + 127)/128;
  qkv_fused<<<gm, 512, 0, stream>>>(x2b, Wqb, bq, bk, bv, qb8, kb, vb, n);

  // fused segmented softmax (fp8 q gathers, degree-branched, preloaded indices)
  row_softmax_kernel<<<(n+3)/4, 256, 0, stream>>>(qb8, kb, rptr, rcol, cposr, cbuf, n);

  // gather aggregation (8 chains in flight, preloaded crow) -> bf16
  agg_kernel<<<(n+3)/4, 256, 0, stream>>>(vb, cbuf, cptr, crow, aggb, n);

  // attention out projection + residual + fused LN2 -> outp (f32) + x2b (bf16)
  gemm_wo_ln2<<<gm, 512, 0, stream>>>(aggb, Wob, bo, feats, ln2w, ln2b, outp, x2b, n);

  // FFN
  gemm_lds<128,1,0,1><<<dim3(gm,4), 512, 0, stream>>>(x2b, W1b, b1, nullptr, h1,  n, 512);
  gemm_lds<512,1,1,0><<<dim3(gm,1), 512, 0, stream>>>(h1,  W2b, b2, outp,    outp, n, 128);
}

// Round 20
// 266.046 us; speedup vs baseline: 2.9656x; 1.0323x over previous
//
#include <hip/hip_runtime.h>
#include <hip/hip_bf16.h>
#include <math.h>

#define H_HEADS 8
constexpr float LN_EPS = 1e-5f;
constexpr int NBCH = 64;          // CSR build chunks (chunk <= 65535 for u16 counters)
constexpr int NSEG = 4;           // bin segments per chunk

using short8 = __attribute__((ext_vector_type(8))) short;
using f32x4  = __attribute__((ext_vector_type(4))) float;
using f32x2  = __attribute__((ext_vector_type(2))) float;
using half2v = __attribute__((ext_vector_type(2))) _Float16;

#if defined(__has_builtin)
#  if __has_builtin(__builtin_amdgcn_cvt_pk_f32_fp8) && __has_builtin(__builtin_amdgcn_cvt_pk_fp8_f32)
#    define HAS_CVT_FP8 1
#  endif
#endif
#ifndef HAS_CVT_FP8
#  define HAS_CVT_FP8 0
#endif

__device__ __forceinline__ ushort f2bf(float v){
  __hip_bfloat16 h = __float2bfloat16(v);
  return *reinterpret_cast<ushort*>(&h);
}
__device__ __forceinline__ float bf2f(ushort u){
  return __uint_as_float(((unsigned)u) << 16);
}

// ---- fp8 e4m3fn helpers (HW cvt when available; fp16 bit-trick fallback) ----
__device__ __forceinline__ unsigned char f32_to_fp8(float v){
#if HAS_CVT_FP8
  return (unsigned char)(__builtin_amdgcn_cvt_pk_fp8_f32(v, v, 0, false) & 0xff);
#else
  _Float16 hv = (_Float16)v;
  ushort h = __builtin_bit_cast(ushort, hv);
  unsigned sign = (h >> 8) & 0x80;
  unsigned p = h & 0x7fff;
  if (p < 0x2400u) return (unsigned char)sign;   // flush |v|<2^-6 to 0
  unsigned q = (p - 0x2000u + 0x40u) >> 7;       // rebias fp16->fp8, round
  if (q > 0x7eu) q = 0x7eu;                      // clamp to max normal 448
  return (unsigned char)(sign | q);
#endif
}
__device__ __forceinline__ float fp8_to_f32(unsigned b){
  unsigned p = b & 0x7f;
  ushort hbits = (ushort)(((b & 0x80) << 8) | (p ? ((p << 7) + 0x2000u) : 0));
  _Float16 hv = __builtin_bit_cast(_Float16, hbits);
  return (float)hv;
}

// async global->LDS, 16B per lane; dest = wave-uniform base + lane*16
__device__ __forceinline__ void stage16(const ushort* g, ushort* l){
  __builtin_amdgcn_global_load_lds((const __attribute__((address_space(1))) unsigned*)g,
                                   (__attribute__((address_space(3))) unsigned*)l,
                                   16, 0, 0);
}

// ---------- weight f32 -> bf16 conversion (all 6 in one launch) ----------
struct CvtArgs { const float* s[6]; ushort* d[6]; int cnt[6]; };
__global__ void cvt6_kernel(CvtArgs a){
  int w = blockIdx.y;
  int i = blockIdx.x*blockDim.x + threadIdx.x;
  if (i < a.cnt[w]) a.d[w][i] = f2bf(a.s[w][i]);
}

// ---------- LDS-staged bf16 MFMA GEMM, 128-row blocks (8 waves / 512 thr) ----------
// OUTMODE: 0 = f32, 1 = bf16, 2 = fp16
template<int K, int RELU, int RESID, int OUTMODE>
__device__ __forceinline__ void gemm_lds_body(
    const ushort* __restrict__ A, const ushort* __restrict__ W,
    const float* __restrict__ bias, const float* __restrict__ resid,
    void* __restrict__ out, int M, int Nout, int cb, ushort* Wl){
  constexpr int NCH = K / 128;
  int t = threadIdx.x;
  int wid = t >> 6, lane = t & 63;
  int mb = blockIdx.x * 128 + wid * 16;
  int lrow = lane & 15, kgrp = lane >> 4;
  int row = mb + lrow;
  bool waveok = mb < M;
  bool rowok = row < M;
  const ushort* arow = A + (size_t)(rowok ? row : (M-1)) * K + kgrp*8;

  f32x4 acc[8] = {};
  short8 af[2][4];

  #pragma unroll
  for (int p = 0; p < 4; ++p){
    int L = p*512 + t;
    int colp = L >> 4, sp = L & 15;
    stage16(W + (size_t)colp*K + ((sp ^ (colp & 7)) << 3),
            (ushort*)((char*)Wl + ((size_t)(p*512 + (t & ~63)))*16));
  }
  if (waveok){
    #pragma unroll
    for (int kk = 0; kk < 4; ++kk)
      af[0][kk] = *(const short8*)(arow + kk*32);
  }

  #pragma unroll
  for (int ci = 0; ci < NCH; ++ci){
    __syncthreads();                       // chunk ci staged + A regs ready
    int cur = ci & 1;
    if (waveok){
      if (ci + 1 < NCH){
        #pragma unroll
        for (int kk = 0; kk < 4; ++kk)
          af[cur^1][kk] = *(const short8*)(arow + (ci+1)*128 + kk*32);
      }
      #pragma unroll
      for (int kk = 0; kk < 4; ++kk){
        #pragma unroll
        for (int nt = 0; nt < 8; ++nt){
          int colc = nt*16 + lrow;
          int g = kk*4 + kgrp;
          short8 bfv = *(const short8*)((const char*)Wl + colc*256 + ((g ^ (colc & 7))*16));
          acc[nt] = __builtin_amdgcn_mfma_f32_16x16x32_bf16(af[cur][kk], bfv, acc[nt], 0, 0, 0);
        }
      }
    }
    if (ci + 1 < NCH){
      __syncthreads();                     // readers done; restage (ALL threads)
      const ushort* Wc = W + (ci+1)*128;
      #pragma unroll
      for (int p = 0; p < 4; ++p){
        int L = p*512 + t;
        int colp = L >> 4, sp = L & 15;
        stage16(Wc + (size_t)colp*K + ((sp ^ (colp & 7)) << 3),
                (ushort*)((char*)Wl + ((size_t)(p*512 + (t & ~63)))*16));
      }
    }
  }
  if (!waveok) return;

  int r0 = mb + kgrp*4;
  #pragma unroll
  for (int nt = 0; nt < 8; ++nt){
    int c = cb + nt*16 + lrow;
    float bsum = bias[c];
    #pragma unroll
    for (int i = 0; i < 4; ++i){
      int r = r0 + i;
      if (r >= M) continue;
      float v = acc[nt][i] + bsum;
      if (RELU)  v = fmaxf(v, 0.0f);
      if (RESID) v += resid[(size_t)r*Nout + c];
      if (OUTMODE == 1) ((ushort*)out)[(size_t)r*Nout + c] = f2bf(v);
      else if (OUTMODE == 2){
        _Float16 hv = (_Float16)v;
        ((ushort*)out)[(size_t)r*Nout + c] = __builtin_bit_cast(ushort, hv);
      } else ((float*)out)[(size_t)r*Nout + c] = v;
    }
  }
}

template<int K, int RELU, int RESID, int OUTMODE>
__global__ __launch_bounds__(512) void gemm_lds(
    const ushort* __restrict__ A, const ushort* __restrict__ Wfull,
    const float* __restrict__ bias, const float* __restrict__ resid,
    void* __restrict__ out, int M, int Nout){
  __shared__ __align__(16) ushort Wl[16384];
  int cb = blockIdx.y * 128;
  gemm_lds_body<K,RELU,RESID,OUTMODE>(A, Wfull + (size_t)cb*K, bias, resid, out, M, Nout, cb, Wl);
}

// ---------- fused LN1 + QKV: feats f32 in, in-register LN, A read once ----------
// q -> fp8 e4m3, k -> fp16, v -> bf16
__global__ __launch_bounds__(512) void qkv_fused(
    const float* __restrict__ feats, const ushort* __restrict__ Wcat,
    const float* __restrict__ ln1w, const float* __restrict__ ln1b,
    const float* __restrict__ bq, const float* __restrict__ bk, const float* __restrict__ bv,
    unsigned char* __restrict__ qb8, ushort* __restrict__ kb, ushort* __restrict__ vb, int M){
  constexpr int K = 128;
  __shared__ __align__(16) ushort Wl[16384];
  int t = threadIdx.x;
  int wid = t >> 6, lane = t & 63;
  int mb = blockIdx.x * 128 + wid * 16;
  int lrow = lane & 15, kgrp = lane >> 4;
  int row = mb + lrow;
  bool waveok = mb < M;
  bool rowok = row < M;
  int rclamp = rowok ? row : (M-1);
  const float* frow = feats + (size_t)rclamp*K + kgrp*8;

  // load this lane's 32 row elements (f32) — 4 lanes (kgrp 0..3) cover the row
  float fx[32];
  #pragma unroll
  for (int kk = 0; kk < 4; ++kk){
    float4 a = *(const float4*)(frow + kk*32);
    float4 b = *(const float4*)(frow + kk*32 + 4);
    fx[kk*8+0]=a.x; fx[kk*8+1]=a.y; fx[kk*8+2]=a.z; fx[kk*8+3]=a.w;
    fx[kk*8+4]=b.x; fx[kk*8+5]=b.y; fx[kk*8+6]=b.z; fx[kk*8+7]=b.w;
  }
  // in-register LayerNorm (ddof=1) across the 4 k-group lanes (all lanes active)
  float s = 0.f;
  #pragma unroll
  for (int i = 0; i < 32; ++i) s += fx[i];
  s += __shfl_xor(s, 16); s += __shfl_xor(s, 32);
  float mu = s * (1.0f/128.0f);
  float ss = 0.f;
  #pragma unroll
  for (int i = 0; i < 32; ++i){ fx[i] -= mu; ss += fx[i]*fx[i]; }
  ss += __shfl_xor(ss, 16); ss += __shfl_xor(ss, 32);
  float inv = 1.0f / (sqrtf(ss * (1.0f/127.0f)) + LN_EPS);

  short8 af[4];
  #pragma unroll
  for (int kk = 0; kk < 4; ++kk){
    const float* wp = ln1w + kgrp*8 + kk*32;
    const float* bp = ln1b + kgrp*8 + kk*32;
    float4 w0 = *(const float4*)wp,  w1 = *(const float4*)(wp+4);
    float4 b0 = *(const float4*)bp,  b1 = *(const float4*)(bp+4);
    float wv[8] = {w0.x,w0.y,w0.z,w0.w,w1.x,w1.y,w1.z,w1.w};
    float bvv[8]= {b0.x,b0.y,b0.z,b0.w,b1.x,b1.y,b1.z,b1.w};
    #pragma unroll
    for (int j = 0; j < 8; ++j)
      af[kk][j] = (short)f2bf(fx[kk*8+j]*inv*wv[j] + bvv[j]);
  }

  #pragma unroll
  for (int y = 0; y < 3; ++y){
    if (y) __syncthreads();                // previous MFMA LDS reads done
    const ushort* W = Wcat + (size_t)y*16384;
    #pragma unroll
    for (int p = 0; p < 4; ++p){           // stage Wy (ALL threads, wave-uniform)
      int L = p*512 + t;
      int colp = L >> 4, sp = L & 15;
      stage16(W + (size_t)colp*K + ((sp ^ (colp & 7)) << 3),
              (ushort*)((char*)Wl + ((size_t)(p*512 + (t & ~63)))*16));
    }
    __syncthreads();
    if (waveok){
      const float* bias = (y==0) ? bq : (y==1) ? bk : bv;
      f32x4 acc[8] = {};
      #pragma unroll
      for (int kk = 0; kk < 4; ++kk){
        #pragma unroll
        for (int nt = 0; nt < 8; ++nt){
          int colc = nt*16 + lrow;
          int g = kk*4 + kgrp;
          short8 bfv = *(const short8*)((const char*)Wl + colc*256 + ((g ^ (colc & 7))*16));
          acc[nt] = __builtin_amdgcn_mfma_f32_16x16x32_bf16(af[kk], bfv, acc[nt], 0, 0, 0);
        }
      }
      int r0 = mb + kgrp*4;
      #pragma unroll
      for (int nt = 0; nt < 8; ++nt){
        int c = nt*16 + lrow;
        float bsum = bias[c];
        #pragma unroll
        for (int i = 0; i < 4; ++i){
          int r = r0 + i;
          if (r >= M) continue;
          float v = acc[nt][i] + bsum;
          if (y == 0)      qb8[(size_t)r*128 + c] = f32_to_fp8(v);
          else if (y == 1){
            _Float16 hv = (_Float16)v;
            kb[(size_t)r*128 + c] = __builtin_bit_cast(ushort, hv);
          } else           vb[(size_t)r*128 + c] = f2bf(v);
        }
      }
    }
  }
}

// ---------- Wo GEMM + residual + fused LN2: outp (f32) and x2b (bf16) ----------
__global__ __launch_bounds__(512) void gemm_wo_ln2(
    const ushort* __restrict__ A, const ushort* __restrict__ W,
    const float* __restrict__ bias, const float* __restrict__ feats,
    const float* __restrict__ lnw, const float* __restrict__ lnb,
    float* __restrict__ outp, ushort* __restrict__ x2b, int M){
  constexpr int K = 128;
  __shared__ __align__(16) ushort Wl[16384];
  int t = threadIdx.x;
  int wid = t >> 6, lane = t & 63;
  int mb = blockIdx.x * 128 + wid * 16;
  int lrow = lane & 15, kgrp = lane >> 4;
  int row = mb + lrow;
  bool waveok = mb < M;
  bool rowok = row < M;
  const ushort* arow = A + (size_t)(rowok ? row : (M-1)) * K + kgrp*8;

  f32x4 acc[8] = {};
  short8 af[4];

  #pragma unroll
  for (int p = 0; p < 4; ++p){
    int L = p*512 + t;
    int colp = L >> 4, sp = L & 15;
    stage16(W + (size_t)colp*K + ((sp ^ (colp & 7)) << 3),
            (ushort*)((char*)Wl + ((size_t)(p*512 + (t & ~63)))*16));
  }
  if (waveok){
    #pragma unroll
    for (int kk = 0; kk < 4; ++kk)
      af[kk] = *(const short8*)(arow + kk*32);
  }
  __syncthreads();
  if (!waveok) return;

  #pragma unroll
  for (int kk = 0; kk < 4; ++kk){
    #pragma unroll
    for (int nt = 0; nt < 8; ++nt){
      int colc = nt*16 + lrow;
      int g = kk*4 + kgrp;
      short8 bfv = *(const short8*)((const char*)Wl + colc*256 + ((g ^ (colc & 7))*16));
      acc[nt] = __builtin_amdgcn_mfma_f32_16x16x32_bf16(af[kk], bfv, acc[nt], 0, 0, 0);
    }
  }

  int r0 = mb + kgrp*4;
  float vv[8][4];
  float lw[8], lb[8];
  #pragma unroll
  for (int nt = 0; nt < 8; ++nt){
    int c = nt*16 + lrow;
    float bsum = bias[c];
    lw[nt] = lnw[c]; lb[nt] = lnb[c];
    #pragma unroll
    for (int i = 0; i < 4; ++i){
      int r = r0 + i;
      float v = 0.f;
      if (r < M){
        v = acc[nt][i] + bsum + feats[(size_t)r*128 + c];
        outp[(size_t)r*128 + c] = v;
      }
      vv[nt][i] = v;
    }
  }
  #pragma unroll
  for (int i = 0; i < 4; ++i){
    int r = r0 + i;
    float s = 0.f;
    #pragma unroll
    for (int nt = 0; nt < 8; ++nt) s += vv[nt][i];
    #pragma unroll
    for (int o = 1; o < 16; o <<= 1) s += __shfl_xor(s, o);
    float mu = s * (1.0f/128.0f);
    float ss = 0.f;
    float d[8];
    #pragma unroll
    for (int nt = 0; nt < 8; ++nt){ d[nt] = vv[nt][i] - mu; ss += d[nt]*d[nt]; }
    #pragma unroll
    for (int o = 1; o < 16; o <<= 1) ss += __shfl_xor(ss, o);
    float sd = sqrtf(ss * (1.0f/127.0f));
    float inv = 1.0f / (sd + LN_EPS);
    if (r < M){
      #pragma unroll
      for (int nt = 0; nt < 8; ++nt){
        int c = nt*16 + lrow;
        x2b[(size_t)r*128 + c] = f2bf(d[nt]*inv*lw[nt] + lb[nt]);
      }
    }
  }
}

// ---------- CSR build, atomic-free, bin-segmented ----------
__global__ __launch_bounds__(256) void hist_seg2(const int* __restrict__ ei,
    unsigned* __restrict__ copies, int E, int n, int nw, int chunk, int nsb){
  __shared__ unsigned hh[12544];
  int b = blockIdx.x, s = blockIdx.y, t = threadIdx.x;
  int bin0 = s * nsb;
  int bin1 = min(bin0 + nsb, n);
  int words = (bin1 - bin0 + 1) >> 1;
  for (int i = t; i < 2*words; i += 256) hh[i] = 0;
  __syncthreads();
  int lo = b*chunk, hi = min(lo + chunk, E);
  for (int e = lo + t; e < hi; e += 256){
    int2 rc = ((const int2*)ei)[e];
    if (rc.x >= bin0 && rc.x < bin1)
      atomicAdd(&hh[(rc.x - bin0) >> 1], 1u << ((rc.x & 1)*16));
    if (rc.y >= bin0 && rc.y < bin1)
      atomicAdd(&hh[words + ((rc.y - bin0) >> 1)], 1u << ((rc.y & 1)*16));
  }
  __syncthreads();
  unsigned* d0 = copies + (size_t)b*nw + (bin0 >> 1);
  unsigned* d1 = copies + (size_t)(NBCH + b)*nw + (bin0 >> 1);
  for (int i = t; i < words; i += 256){ d0[i] = hh[i]; d1[i] = hh[words + i]; }
}

// fold copies -> cnt2 + u16 choff, AND per-256-bin partial sums (merged reduce)
__global__ __launch_bounds__(256) void scan_fold2(const unsigned* __restrict__ copies,
    int* __restrict__ cnt2, ushort* __restrict__ choff, int* __restrict__ partial,
    int n, int nw, int npb){
  int y = blockIdx.y;
  int t = threadIdx.x;
  int bin = blockIdx.x*256 + t;
  int run = 0;
  if (bin < n){
    const unsigned* cp = copies + (size_t)y*NBCH*nw + (bin >> 1);
    int sh = (bin & 1)*16;
    for (int b = 0; b < NBCH; ++b){
      int c = (int)((cp[(size_t)b*nw] >> sh) & 0xffffu);
      choff[((size_t)y*NBCH + b)*n + bin] = (ushort)run;
      run += c;
    }
    cnt2[(size_t)y*n + bin] = run;
  }
  __shared__ int sm[256];
  sm[t] = (bin < n) ? run : 0;
  __syncthreads();
  for (int off = 128; off; off >>= 1){
    if (t < off) sm[t] += sm[t+off];
    __syncthreads();
  }
  if (t == 0) partial[y*npb + blockIdx.x] = sm[0];
}

__global__ __launch_bounds__(256) void scan_mid(int* __restrict__ partial, int nb,
                                                int* __restrict__ rptr, int* __restrict__ cptr, int n){
  int y = blockIdx.y;
  int* p = partial + y*nb;
  int t = threadIdx.x;
  __shared__ int sm[256];
  sm[t] = (t < nb) ? p[t] : 0;
  __syncthreads();
  for (int off = 1; off < 256; off <<= 1){
    int v = (t >= off) ? sm[t-off] : 0;
    __syncthreads();
    sm[t] += v;
    __syncthreads();
  }
  if (t < nb) p[t] = (t == 0) ? 0 : sm[t-1];
  if (t == 0) (y ? cptr : rptr)[n] = sm[255];
}

// 1 bin/thread scatter: ptr[bin] = partial[block] + exclusive-in-block
__global__ __launch_bounds__(256) void scan_scatter2(const int* __restrict__ cnt2,
    const int* __restrict__ partial, int* __restrict__ rptr, int* __restrict__ cptr,
    int n, int npb){
  int y = blockIdx.y;
  int* ptr = y ? cptr : rptr;
  int t = threadIdx.x;
  int bin = blockIdx.x*256 + t;
  int v = (bin < n) ? cnt2[(size_t)y*n + bin] : 0;
  __shared__ int sm[256];
  sm[t] = v;
  __syncthreads();
  for (int off = 1; off < 256; off <<= 1){
    int x = (t >= off) ? sm[t-off] : 0;
    __syncthreads();
    sm[t] += x;
    __syncthreads();
  }
  if (bin < n) ptr[bin] = partial[y*npb + blockIdx.x] + sm[t] - v;
}

// fill via in-chunk LDS rank within bin segment; no global atomics
__global__ __launch_bounds__(256) void fill_r_seg(const int* __restrict__ ei,
    const int* __restrict__ rptr, const ushort* __restrict__ choffR,
    int* __restrict__ rcol, int* __restrict__ pose, int E, int n, int chunk, int nsb){
  __shared__ unsigned hh[8192];
  int b = blockIdx.x, s = blockIdx.y, t = threadIdx.x;
  int bin0 = s * nsb;
  int bin1 = min(bin0 + nsb, n);
  int words = (bin1 - bin0 + 1) >> 1;
  for (int i = t; i < words; i += 256) hh[i] = 0;
  __syncthreads();
  const ushort* chb = choffR + (size_t)b*n;
  int lo = b*chunk, hi = min(lo + chunk, E);
  for (int e = lo + t; e < hi; e += 256){
    int2 rc = ((const int2*)ei)[e];
    int bin = rc.x;
    if (bin < bin0 || bin >= bin1) continue;
    int sh = (bin & 1)*16;
    unsigned old = atomicAdd(&hh[(bin - bin0) >> 1], 1u << sh);
    int rank = (int)((old >> sh) & 0xffffu);
    int pos = rptr[bin] + (int)chb[bin] + rank;
    rcol[pos] = rc.y;
    pose[e] = pos;
  }
}

__global__ __launch_bounds__(256) void fill_c_seg(const int* __restrict__ ei,
    const int* __restrict__ cptr, const ushort* __restrict__ choffC,
    const int* __restrict__ pose, int* __restrict__ crow, int* __restrict__ cposr,
    int E, int n, int chunk, int nsb){
  __shared__ unsigned hh[8192];
  int b = blockIdx.x, s = blockIdx.y, t = threadIdx.x;
  int bin0 = s * nsb;
  int bin1 = min(bin0 + nsb, n);
  int words = (bin1 - bin0 + 1) >> 1;
  for (int i = t; i < words; i += 256) hh[i] = 0;
  __syncthreads();
  const ushort* chb = choffC + (size_t)b*n;
  int lo = b*chunk, hi = min(lo + chunk, E);
  for (int e = lo + t; e < hi; e += 256){
    int2 rc = ((const int2*)ei)[e];
    int bin = rc.y;
    if (bin < bin0 || bin >= bin1) continue;
    int sh = (bin & 1)*16;
    unsigned old = atomicAdd(&hh[(bin - bin0) >> 1], 1u << sh);
    int rank = (int)((old >> sh) & 0xffffu);
    int pos = cptr[bin] + (int)chb[bin] + rank;
    crow[pos] = rc.x;
    cposr[pose[e]] = pos;
  }
}

// ---------- q.k dot for one head (16 dims): q fp8, k as f32 regs ----------
__device__ __forceinline__ float qdot16q8(const unsigned char* __restrict__ qb8, int c, int h,
                                          const float* kf){
  const uint4* qp = (const uint4*)(qb8 + (size_t)c*128 + h*16);
  uint4 q = *qp;
  unsigned w[4] = {q.x, q.y, q.z, q.w};
  float s = 0.f;
  #pragma unroll
  for (int i = 0; i < 4; ++i){
#if HAS_CVT_FP8
    f32x2 lo = __builtin_amdgcn_cvt_pk_f32_fp8(w[i], false);
    f32x2 hi = __builtin_amdgcn_cvt_pk_f32_fp8(w[i], true);
    s = fmaf(lo[0], kf[4*i+0], s);
    s = fmaf(lo[1], kf[4*i+1], s);
    s = fmaf(hi[0], kf[4*i+2], s);
    s = fmaf(hi[1], kf[4*i+3], s);
#else
    #pragma unroll
    for (int j = 0; j < 4; ++j)
      s = fmaf(fp8_to_f32((w[i] >> (8*j)) & 0xffu), kf[4*i+j], s);
#endif
  }
  return s * 0.25f;   // 1/sqrt(16)
}

// degree-templated softmax body; __shfl UNCONDITIONAL (round-17 lesson)
template<int NS>
__device__ __forceinline__ void softmax_rows(const unsigned char* __restrict__ qb8,
    const int* __restrict__ rcol, const int* __restrict__ cposr,
    ushort* __restrict__ cbuf, const float* kf, int lo, int hi, int h, int el,
    int rl, int cpl){
  float sreg[NS];
  float m = -1e30f;
  #pragma unroll
  for (int ts = 0; ts < NS; ++ts){
    int c = __shfl(rl, el + ts*8);        // all 64 lanes active here
    int j = lo + el + ts*8;
    float s = -1e30f;
    if (j < hi) s = qdot16q8(qb8, c, h, kf);
    sreg[ts] = s;
    m = fmaxf(m, s);
  }
  if (NS == 8)
    for (int j = lo + el + 64; j < hi; j += 8)
      m = fmaxf(m, qdot16q8(qb8, rcol[j], h, kf));
  #pragma unroll
  for (int o = 8; o < 64; o <<= 1) m = fmaxf(m, __shfl_xor(m, o));

  float d = 0.f;
  #pragma unroll
  for (int ts = 0; ts < NS; ++ts){
    int j = lo + el + ts*8;
    if (j < hi){ float e = __expf(sreg[ts] - m); sreg[ts] = e; d += e; }
  }
  if (NS == 8)
    for (int j = lo + el + 64; j < hi; j += 8)
      d += __expf(qdot16q8(qb8, rcol[j], h, kf) - m);
  #pragma unroll
  for (int o = 8; o < 64; o <<= 1) d += __shfl_xor(d, o);
  float invd = 1.0f / d;

  #pragma unroll
  for (int ts = 0; ts < NS; ++ts){
    int cp = __shfl(cpl, el + ts*8);      // unconditional
    int j = lo + el + ts*8;
    if (j < hi) cbuf[(size_t)cp*8 + h] = f2bf(sreg[ts] * invd);
  }
  if (NS == 8)
    for (int j = lo + el + 64; j < hi; j += 8){
      float s = qdot16q8(qb8, rcol[j], h, kf);
      cbuf[(size_t)cposr[j]*8 + h] = f2bf(__expf(s - m) * invd);
    }
}

// ---------- fused segmented softmax over row-CSR (fp8 q, fp16 k) ----------
__global__ void row_softmax_kernel(const unsigned char* __restrict__ qb8,
                                   const ushort* __restrict__ kb,
                                   const int* __restrict__ rptr, const int* __restrict__ rcol,
                                   const int* __restrict__ cposr,
                                   ushort* __restrict__ cbuf, int n){
  int wid = threadIdx.x >> 6, lane = threadIdx.x & 63;
  int r = blockIdx.x * (blockDim.x >> 6) + wid;
  if (r >= n) return;
  int lo = rptr[r], hi = rptr[r+1];
  if (lo >= hi) return;
  int h = lane & 7, el = lane >> 3;

  int jl = lo + lane;
  bool jok = jl < hi;
  int rl  = rcol [jok ? jl : lo];
  int cpl = cposr[jok ? jl : lo];

  float kf[16];
  {
    const int4* kp = (const int4*)(kb + (size_t)r*128 + h*16);
    int4 k0 = kp[0], k1 = kp[1];
    int kw[8] = {k0.x,k0.y,k0.z,k0.w,k1.x,k1.y,k1.z,k1.w};
    #pragma unroll
    for (int i = 0; i < 8; ++i){
      half2v k2 = __builtin_bit_cast(half2v, kw[i]);
      kf[2*i]   = (float)k2.x;
      kf[2*i+1] = (float)k2.y;
    }
  }

  int deg = hi - lo;   // wave-uniform
  if (deg <= 16)      softmax_rows<2>(qb8, rcol, cposr, cbuf, kf, lo, hi, h, el, rl, cpl);
  else if (deg <= 32) softmax_rows<4>(qb8, rcol, cposr, cbuf, kf, lo, hi, h, el, rl, cpl);
  else                softmax_rows<8>(qb8, rcol, cposr, cbuf, kf, lo, hi, h, el, rl, cpl);
}

// ---------- gather aggregation over col-CSR -> bf16 agg ----------
__global__ void agg_kernel(const ushort* __restrict__ vb, const ushort* __restrict__ cbuf,
                           const int* __restrict__ cptr, const int* __restrict__ crow,
                           ushort* __restrict__ aggb, int n){
  int wid = threadIdx.x >> 6, lane = threadIdx.x & 63;
  int node = blockIdx.x * (blockDim.x >> 6) + wid;
  if (node >= n) return;
  int lo = cptr[node], hi = cptr[node+1];
  int deg = hi - lo;                    // wave-uniform
  int oct = lane >> 3, l8 = lane & 7;

  int jl = lo + lane;
  int crl = crow[jl < hi ? jl : lo];

  float acc[16] = {};
  int tmax = (deg + 7) >> 3;
  for (int ts = 0; ts < tmax; ++ts){
    int li = oct + ts*8;
    int row = __shfl(crl, li & 63);     // all 64 lanes active
    if (li < deg){
      if (li >= 64) row = crow[lo + li];
      float a = bf2f(cbuf[(size_t)(lo + li)*8 + l8]);
      const short8* vp = (const short8*)(vb + (size_t)row*128 + l8*16);
      short8 v0 = vp[0], v1 = vp[1];
      #pragma unroll
      for (int i = 0; i < 8; ++i){
        acc[i]   = fmaf(a, bf2f((ushort)v0[i]), acc[i]);
        acc[8+i] = fmaf(a, bf2f((ushort)v1[i]), acc[8+i]);
      }
    }
  }
  #pragma unroll
  for (int i = 0; i < 16; ++i){
    acc[i] += __shfl_xor(acc[i], 8);
    acc[i] += __shfl_xor(acc[i], 16);
    acc[i] += __shfl_xor(acc[i], 32);
  }
  if (oct == 0){
    short8 o0, o1;
    #pragma unroll
    for (int i = 0; i < 8; ++i){ o0[i] = (short)f2bf(acc[i]); o1[i] = (short)f2bf(acc[8+i]); }
    short8* op = (short8*)(aggb + (size_t)node*128 + l8*16);
    op[0] = o0; op[1] = o1;
  }
}

extern "C" void kernel_launch(void* const* d_in, const int* in_sizes, int n_in,
                              void* d_out, int out_size, void* d_ws, size_t ws_size,
                              hipStream_t stream){
  const float* feats = (const float*)d_in[0];
  const int*   ei    = (const int*)  d_in[1];
  const float* Wq = (const float*)d_in[2];
  const float* bq = (const float*)d_in[3];
  const float* Wk = (const float*)d_in[4];
  const float* bk = (const float*)d_in[5];
  const float* Wv = (const float*)d_in[6];
  const float* bv = (const float*)d_in[7];
  const float* Wo = (const float*)d_in[8];
  const float* bo = (const float*)d_in[9];
  const float* ln1w = (const float*)d_in[10];
  const float* ln1b = (const float*)d_in[11];
  const float* ln2w = (const float*)d_in[12];
  const float* ln2b = (const float*)d_in[13];
  const float* W1 = (const float*)d_in[14];
  const float* b1 = (const float*)d_in[15];
  const float* W2 = (const float*)d_in[16];
  const float* b2 = (const float*)d_in[17];
  float* outp = (float*)d_out;

  int n = in_sizes[0] / 128;      // 50000 nodes
  int E = in_sizes[1] / 2;        // 800000 edges
  int nw = (n + 1) >> 1;          // packed u16 words per full histogram
  int chunk = (E + NBCH - 1) / NBCH;
  int nsb = (((n + NSEG - 1) / NSEG) + 1) & ~1;   // bins per segment (even)
  int npb = (n + 255) / 256;      // partial blocks (<= 256)

  const size_t ND  = (size_t)n * 128;
  const size_t ND2 = ND / 2;
  const size_t EH  = (size_t)E * H_HEADS;

  float* ws = (float*)d_ws;
  ushort* x2b  = (ushort*)ws;                      // ND bf16 (LN2 out)
  unsigned char* qb8 = (unsigned char*)(ws + ND2); // ND fp8
  ushort* kb   = (ushort*)(ws + 2*ND2);            // ND fp16
  ushort* vb   = (ushort*)(ws + 3*ND2);            // ND bf16
  ushort* cbuf = (ushort*)(ws + 4*ND2);            // EH bf16 (alpha, col order)
  ushort* aggb = (ushort*)(ws + 4*ND2 + EH/2);     // ND bf16
  int* crow    = (int*)(ws + 5*ND2 + EH/2);
  int* cposr   = crow + E;
  int* rcol    = cposr + E;
  int* pose    = rcol + E;
  int* rptr    = pose + E;
  int* cptr    = rptr + (n + 4);
  int* cnt2    = cptr + (n + 4);                   // [2][n]
  ushort* choff = (ushort*)(cnt2 + 2*n);           // [2][NBCH][n] u16
  unsigned* copies = (unsigned*)(choff + (size_t)2*NBCH*n);  // [2][NBCH][nw]
  int* partial = (int*)(copies + (size_t)2*NBCH*nw);         // 2*npb ints
  ushort* wbuf = (ushort*)(partial + 512);
  ushort* Wqb = wbuf;                              // Wq,Wk,Wv contiguous for qkv
  ushort* Wkb = Wqb + 16384;
  ushort* Wvb = Wkb + 16384;
  ushort* Wob = Wvb + 16384;
  ushort* W1b = Wob + 16384;
  ushort* W2b = W1b + 65536;
  ushort* h1  = (ushort*)qb8;                      // n*512 bf16 == qb8..cbuf slots

  // weight conversion (independent)
  CvtArgs ca;
  ca.s[0]=Wq; ca.s[1]=Wk; ca.s[2]=Wv; ca.s[3]=Wo; ca.s[4]=W1; ca.s[5]=W2;
  ca.d[0]=Wqb; ca.d[1]=Wkb; ca.d[2]=Wvb; ca.d[3]=Wob; ca.d[4]=W1b; ca.d[5]=W2b;
  ca.cnt[0]=ca.cnt[1]=ca.cnt[2]=ca.cnt[3]=16384; ca.cnt[4]=ca.cnt[5]=65536;
  cvt6_kernel<<<dim3(65536/256, 6), 256, 0, stream>>>(ca);

  // atomic-free CSR build (bin-segmented LDS histograms; fold+reduce merged)
  hist_seg2   <<<dim3(NBCH,NSEG), 256, 0, stream>>>(ei, copies, E, n, nw, chunk, nsb);
  scan_fold2  <<<dim3(npb,2), 256, 0, stream>>>(copies, cnt2, choff, partial, n, nw, npb);
  scan_mid    <<<dim3(1,2),   256, 0, stream>>>(partial, npb, rptr, cptr, n);
  scan_scatter2<<<dim3(npb,2),256, 0, stream>>>(cnt2, partial, rptr, cptr, n, npb);
  fill_r_seg<<<dim3(NBCH,NSEG), 256, 0, stream>>>(ei, rptr, choff,                  rcol, pose, E, n, chunk, nsb);
  fill_c_seg<<<dim3(NBCH,NSEG), 256, 0, stream>>>(ei, cptr, choff + (size_t)NBCH*n, pose, crow, cposr, E, n, chunk, nsb);

  // fused LN1 + QKV (feats read once; q fp8 / k fp16 / v bf16)
  int gm = (n + 127)/128;
  qkv_fused<<<gm, 512, 0, stream>>>(feats, Wqb, ln1w, ln1b, bq, bk, bv, qb8, kb, vb, n);

  // fused segmented softmax (fp8 q gathers, degree-branched, preloaded indices)
  row_softmax_kernel<<<(n+3)/4, 256, 0, stream>>>(qb8, kb, rptr, rcol, cposr, cbuf, n);

  // gather aggregation (8 chains in flight, preloaded crow) -> bf16
  agg_kernel<<<(n+3)/4, 256, 0, stream>>>(vb, cbuf, cptr, crow, aggb, n);

  // attention out projection + residual + fused LN2 -> outp (f32) + x2b (bf16)
  gemm_wo_ln2<<<gm, 512, 0, stream>>>(aggb, Wob, bo, feats, ln2w, ln2b, outp, x2b, n);

  // FFN
  gemm_lds<128,1,0,1><<<dim3(gm,4), 512, 0, stream>>>(x2b, W1b, b1, nullptr, h1,  n, 512);
  gemm_lds<512,1,1,0><<<dim3(gm,1), 512, 0, stream>>>(h1,  W2b, b2, outp,    outp, n, 128);
}